// Round 1
// baseline (1731.644 us; speedup 1.0000x reference)
//
#include <hip/hip_runtime.h>
#include <math.h>

#define HW 4096
#define EPSV 1e-5f

// ---------------------------------------------------------------------------
// 3x3 conv + BN + PReLU.  ROWS output rows per block, 64 co x 64 w tile.
// Thread micro-tile: 4co x 4pix (x ROWS).  Inner: ds_read_b128 weights.
// ---------------------------------------------------------------------------
template<int CIN, int COUT, int DIL, int ROWS>
__global__ __launch_bounds__(256) void conv3x3_bn_prelu(
    const float* __restrict__ in, const float* __restrict__ wgt,
    const float* __restrict__ bias, const float* __restrict__ bng,
    const float* __restrict__ bnb, const float* __restrict__ bnm,
    const float* __restrict__ bnv, const float* __restrict__ al,
    float* __restrict__ out)
{
    constexpr int NW  = 64 + 2 * DIL;            // staged row width
    constexpr int SR  = (ROWS == 1) ? 3 : (ROWS + 2); // staged rows (ROWS>1 => DIL==1)
    constexpr int NIN = 4 + 2 * DIL;             // per-thread input regs per row

    const int tid = threadIdx.x;
    const int b   = blockIdx.z;
    const int co0 = blockIdx.y * 64;
    const int h0  = blockIdx.x * ROWS;
    const int cg  = tid >> 4, pg = tid & 15;
    const int c0l = cg * 4,  w0 = pg * 4;

    __shared__ __align__(16) float sIn[16 * SR * NW];
    __shared__ __align__(16) float sW[16 * 9 * 68];

    float acc[ROWS][4][4] = {};

    for (int cc = 0; cc < CIN; cc += 16) {
        // ---- stage input tile (zero-padded) ----
        for (int i = tid; i < 16 * SR * NW; i += 256) {
            const int col = i % NW;
            const int rest = i / NW;
            const int r  = rest % SR;
            const int ci = rest / SR;
            const int irow = (ROWS == 1) ? (h0 + (r - 1) * DIL) : (h0 - 1 + r);
            const int icol = col - DIL;
            float vv = 0.f;
            if (irow >= 0 && irow < 64 && icol >= 0 && icol < 64)
                vv = in[((b * CIN + cc + ci) * 64 + irow) * 64 + icol];
            sIn[i] = vv;
        }
        // ---- stage weights transposed: sW[ci][tap][co], stride 68 ----
        for (int i = tid; i < 16 * 9 * 64; i += 256) {
            const int co  = i / 144;
            const int rem = i - co * 144;
            const int ci  = rem / 9;
            const int tap = rem - ci * 9;
            sW[(ci * 9 + tap) * 68 + co] =
                wgt[((co0 + co) * CIN + cc + ci) * 9 + tap];
        }
        __syncthreads();

        #pragma unroll 1
        for (int ci = 0; ci < 16; ++ci) {
            float vin[SR][NIN];
            #pragma unroll
            for (int r = 0; r < SR; ++r)
                #pragma unroll
                for (int j = 0; j < NIN; ++j)
                    vin[r][j] = sIn[(ci * SR + r) * NW + w0 + j];
            #pragma unroll
            for (int dy = 0; dy < 3; ++dy)
                #pragma unroll
                for (int dx = 0; dx < 3; ++dx) {
                    const float4 wv = *(const float4*)&sW[(ci * 9 + dy * 3 + dx) * 68 + c0l];
                    const float wa[4] = {wv.x, wv.y, wv.z, wv.w};
                    #pragma unroll
                    for (int ro = 0; ro < ROWS; ++ro) {
                        const int r = (ROWS == 1) ? dy : (ro + dy);
                        #pragma unroll
                        for (int p = 0; p < 4; ++p) {
                            const float iv = vin[r][p + dx * DIL];
                            #pragma unroll
                            for (int i2 = 0; i2 < 4; ++i2)
                                acc[ro][i2][p] = fmaf(wa[i2], iv, acc[ro][i2][p]);
                        }
                    }
                }
        }
        __syncthreads();
    }

    const float a = al[0];
    #pragma unroll
    for (int i2 = 0; i2 < 4; ++i2) {
        const int co = co0 + c0l + i2;
        const float scale = bng[co] * rsqrtf(bnv[co] + EPSV);
        const float shift = bnb[co] - bnm[co] * scale;
        const float bb = bias[co];
        #pragma unroll
        for (int ro = 0; ro < ROWS; ++ro) {
            float4 o;
            float t;
            t = (acc[ro][i2][0] + bb) * scale + shift; o.x = t >= 0.f ? t : a * t;
            t = (acc[ro][i2][1] + bb) * scale + shift; o.y = t >= 0.f ? t : a * t;
            t = (acc[ro][i2][2] + bb) * scale + shift; o.z = t >= 0.f ? t : a * t;
            t = (acc[ro][i2][3] + bb) * scale + shift; o.w = t >= 0.f ? t : a * t;
            *(float4*)&out[((b * COUT + co) * 64 + h0 + ro) * 64 + w0] = o;
        }
    }
}

// ---------------------------------------------------------------------------
// Generic 1x1 conv (+optional BN/PReLU, optional dual-source concat input,
// optional extra per-(b,co) bias).  64co x 64pix tile, 4x4 micro.
// ---------------------------------------------------------------------------
template<int CIN, bool BNACT, bool DUAL>
__global__ __launch_bounds__(256) void conv1x1_kernel(
    const float* __restrict__ in0, const float* __restrict__ in1,
    const float* __restrict__ wgt, int wstride, int COUT,
    const float* __restrict__ bias, const float* __restrict__ bng,
    const float* __restrict__ bnb, const float* __restrict__ bnm,
    const float* __restrict__ bnv, const float* __restrict__ al,
    const float* __restrict__ ebias, float* __restrict__ out)
{
    const int tid = threadIdx.x;
    const int b = blockIdx.z, co0 = blockIdx.y * 64, p0 = blockIdx.x * 64;
    const int cg = tid >> 4, pg = tid & 15;
    const int c0l = cg * 4, w0 = pg * 4;

    __shared__ __align__(16) float sIn[16 * 64];
    __shared__ __align__(16) float sW[16 * 68];

    float acc[4][4] = {};

    for (int cc = 0; cc < CIN; cc += 16) {
        {
            int i = tid;
            #pragma unroll
            for (int it = 0; it < 4; ++it, i += 256) {
                const int px = i & 63, ci = i >> 6;
                const int ch = cc + ci;
                const float* src;
                if (DUAL)
                    src = (ch < 128) ? (in0 + (size_t)(b * 128 + ch) * HW)
                                     : (in1 + (size_t)(b * 128 + ch - 128) * HW);
                else
                    src = in0 + (size_t)(b * CIN + ch) * HW;
                sIn[ci * 64 + px] = src[p0 + px];
            }
            i = tid;
            #pragma unroll
            for (int it = 0; it < 4; ++it, i += 256) {
                const int ci = i & 15, co = i >> 4;
                sW[ci * 68 + co] = wgt[(co0 + co) * wstride + cc + ci];
            }
        }
        __syncthreads();
        #pragma unroll
        for (int ci = 0; ci < 16; ++ci) {
            const float4 iv = *(const float4*)&sIn[ci * 64 + w0];
            const float4 wv = *(const float4*)&sW[ci * 68 + c0l];
            const float ia[4] = {iv.x, iv.y, iv.z, iv.w};
            const float wa[4] = {wv.x, wv.y, wv.z, wv.w};
            #pragma unroll
            for (int i2 = 0; i2 < 4; ++i2)
                #pragma unroll
                for (int j = 0; j < 4; ++j)
                    acc[i2][j] = fmaf(wa[i2], ia[j], acc[i2][j]);
        }
        __syncthreads();
    }

    const float a = BNACT ? al[0] : 0.f;
    #pragma unroll
    for (int i2 = 0; i2 < 4; ++i2) {
        const int co = co0 + c0l + i2;
        float bb = bias[co];
        if (ebias) bb += ebias[b * COUT + co];
        float scale = 1.f, shift = bb;
        if (BNACT) {
            scale = bng[co] * rsqrtf(bnv[co] + EPSV);
            shift = bb * scale + (bnb[co] - bnm[co] * scale);
        }
        float4 o;
        float t;
        t = acc[i2][0] * scale + shift; o.x = (BNACT && t < 0.f) ? a * t : t;
        t = acc[i2][1] * scale + shift; o.y = (BNACT && t < 0.f) ? a * t : t;
        t = acc[i2][2] * scale + shift; o.z = (BNACT && t < 0.f) ? a * t : t;
        t = acc[i2][3] * scale + shift; o.w = (BNACT && t < 0.f) ? a * t : t;
        *(float4*)&out[(size_t)(b * COUT + co) * HW + p0 + w0] = o;
    }
}

// ---------------------------------------------------------------------------
// q & k 1x1 convs (128 -> 16 each) from c2.
// ---------------------------------------------------------------------------
__global__ __launch_bounds__(256) void qk_kernel(
    const float* __restrict__ c2g, const float* __restrict__ qw,
    const float* __restrict__ qb2, const float* __restrict__ kw,
    const float* __restrict__ kb2, float* __restrict__ qo, float* __restrict__ ko)
{
    const int b = blockIdx.y, p0 = blockIdx.x * 64, tid = threadIdx.x;
    __shared__ float sC[128][64];
    __shared__ float sWq[16][128];
    __shared__ float sWk[16][128];
    for (int i = tid; i < 8192; i += 256) {
        const int px = i & 63, ci = i >> 6;
        sC[ci][px] = c2g[(size_t)(b * 128 + ci) * HW + p0 + px];
    }
    for (int i = tid; i < 2048; i += 256) {
        const int ci = i & 127, co = i >> 7;
        sWq[co][ci] = qw[co * 128 + ci];
        sWk[co][ci] = kw[co * 128 + ci];
    }
    __syncthreads();
    const int px = tid & 63, grp = tid >> 6;  // 0..3
    const int co0 = (grp & 1) * 8;
    const bool isK = grp >= 2;
    const float* sWp = isK ? &sWk[0][0] : &sWq[0][0];
    float acc[8] = {};
    for (int ci = 0; ci < 128; ++ci) {
        const float xv = sC[ci][px];
        #pragma unroll
        for (int j = 0; j < 8; ++j)
            acc[j] = fmaf(sWp[(co0 + j) * 128 + ci], xv, acc[j]);
    }
    const float* bsrc = isK ? kb2 : qb2;
    float* osrc = isK ? ko : qo;
    #pragma unroll
    for (int j = 0; j < 8; ++j)
        osrc[(size_t)(b * 16 + co0 + j) * HW + p0 + px] = acc[j] + bsrc[co0 + j];
}

// ---------------------------------------------------------------------------
// Flash-style attention over HW=4096: block = (b, 32-query tile).
// Phase A: online max/sumexp.  Phase B: PV accumulate.  Fuses gamma2*out+c2.
// ---------------------------------------------------------------------------
__global__ __launch_bounds__(256) void attn_kernel(
    const float* __restrict__ qg, const float* __restrict__ kg,
    const float* __restrict__ vg, const float* __restrict__ c2g,
    const float* __restrict__ gamma2, float* __restrict__ o2)
{
    const int tid = threadIdx.x;
    const int b  = blockIdx.y;
    const int n0 = blockIdx.x * 32;
    const int cg = tid >> 3, c0 = cg * 4;   // c: 0..124
    const int ng = tid & 7,  nn0 = ng * 4;  // n: 0..28
    const int sn = tid >> 3;                // score thread: n 0..31
    const int sm0 = (tid & 7) * 4;          // score thread: 4 m's

    __shared__ __align__(16) float sQ[16][32];
    __shared__ __align__(16) float sK[16][36];
    __shared__ __align__(16) float sV[32][132];
    __shared__ __align__(16) float sPT[32][36];
    __shared__ float sRedM[32][9];
    __shared__ float sRedS[32][9];
    __shared__ float sMax[32];
    __shared__ float sInv[32];

    for (int i = tid; i < 512; i += 256) {
        const int c = i >> 5, n = i & 31;
        sQ[c][n] = qg[(size_t)(b * 16 + c) * HW + n0 + n];
    }
    __syncthreads();

    // ---- phase A: per-thread online logsumexp over a strided m subset ----
    float runM = -3e38f, runS = 0.f;
    for (int m0 = 0; m0 < HW; m0 += 32) {
        for (int i = tid; i < 512; i += 256) {
            const int c = i >> 5, m = i & 31;
            sK[c][m] = kg[(size_t)(b * 16 + c) * HW + m0 + m];
        }
        __syncthreads();
        float s0 = 0, s1 = 0, s2 = 0, s3 = 0;
        #pragma unroll
        for (int c = 0; c < 16; ++c) {
            const float qv = sQ[c][sn];
            const float4 kv = *(const float4*)&sK[c][sm0];
            s0 = fmaf(qv, kv.x, s0); s1 = fmaf(qv, kv.y, s1);
            s2 = fmaf(qv, kv.z, s2); s3 = fmaf(qv, kv.w, s3);
        }
        const float mx = fmaxf(fmaxf(s0, s1), fmaxf(s2, s3));
        const float nm = fmaxf(runM, mx);
        runS = runS * __expf(runM - nm)
             + __expf(s0 - nm) + __expf(s1 - nm) + __expf(s2 - nm) + __expf(s3 - nm);
        runM = nm;
        __syncthreads();
    }
    sRedM[sn][ng] = runM; sRedS[sn][ng] = runS;
    __syncthreads();
    if (tid < 32) {
        float M = -3e38f;
        for (int j = 0; j < 8; ++j) M = fmaxf(M, sRedM[tid][j]);
        float S = 0.f;
        for (int j = 0; j < 8; ++j) S += sRedS[tid][j] * __expf(sRedM[tid][j] - M);
        sMax[tid] = M; sInv[tid] = 1.0f / S;
    }
    __syncthreads();
    const float myM = sMax[sn], myI = sInv[sn];

    // ---- phase B: PV ----
    float acc[4][4] = {};
    for (int m0 = 0; m0 < HW; m0 += 32) {
        for (int i = tid; i < 512; i += 256) {
            const int c = i >> 5, m = i & 31;
            sK[c][m] = kg[(size_t)(b * 16 + c) * HW + m0 + m];
        }
        for (int i = tid; i < 4096; i += 256) {
            const int c = i >> 5, m = i & 31;
            sV[m][c] = vg[(size_t)(b * 128 + c) * HW + m0 + m];
        }
        __syncthreads();
        float s0 = 0, s1 = 0, s2 = 0, s3 = 0;
        #pragma unroll
        for (int c = 0; c < 16; ++c) {
            const float qv = sQ[c][sn];
            const float4 kv = *(const float4*)&sK[c][sm0];
            s0 = fmaf(qv, kv.x, s0); s1 = fmaf(qv, kv.y, s1);
            s2 = fmaf(qv, kv.z, s2); s3 = fmaf(qv, kv.w, s3);
        }
        sPT[sm0 + 0][sn] = __expf(s0 - myM) * myI;
        sPT[sm0 + 1][sn] = __expf(s1 - myM) * myI;
        sPT[sm0 + 2][sn] = __expf(s2 - myM) * myI;
        sPT[sm0 + 3][sn] = __expf(s3 - myM) * myI;
        __syncthreads();
        #pragma unroll 4
        for (int m = 0; m < 32; ++m) {
            const float4 vv = *(const float4*)&sV[m][c0];
            const float4 pp = *(const float4*)&sPT[m][nn0];
            const float va[4] = {vv.x, vv.y, vv.z, vv.w};
            const float pa[4] = {pp.x, pp.y, pp.z, pp.w};
            #pragma unroll
            for (int i2 = 0; i2 < 4; ++i2)
                #pragma unroll
                for (int j = 0; j < 4; ++j)
                    acc[i2][j] = fmaf(va[i2], pa[j], acc[i2][j]);
        }
        __syncthreads();
    }

    const float g2 = gamma2[0];
    #pragma unroll
    for (int i2 = 0; i2 < 4; ++i2) {
        const int c = c0 + i2;
        const size_t base = (size_t)(b * 128 + c) * HW + n0 + nn0;
        const float4 cv = *(const float4*)&c2g[base];
        float4 o;
        o.x = fmaf(g2, acc[i2][0], cv.x);
        o.y = fmaf(g2, acc[i2][1], cv.y);
        o.z = fmaf(g2, acc[i2][2], cv.z);
        o.w = fmaf(g2, acc[i2][3], cv.w);
        *(float4*)&o2[base] = o;
    }
}

// ---------------------------------------------------------------------------
// Global average pool over HW for each (b, c) of xp [4,256,64,64].
// ---------------------------------------------------------------------------
__global__ __launch_bounds__(256) void pool_kernel(
    const float* __restrict__ xp, float* __restrict__ pool)
{
    const int c = blockIdx.x, b = blockIdx.y, tid = threadIdx.x;
    const float4* row = (const float4*)(xp + (size_t)(b * 256 + c) * HW);
    float s = 0.f;
    #pragma unroll 4
    for (int i = tid; i < 1024; i += 256) {
        const float4 t = row[i];
        s += t.x + t.y + t.z + t.w;
    }
    __shared__ float red[256];
    red[tid] = s; __syncthreads();
    for (int st = 128; st > 0; st >>= 1) {
        if (tid < st) red[tid] += red[tid + st];
        __syncthreads();
    }
    if (tid == 0) pool[b * 256 + c] = red[0] * (1.0f / 4096.0f);
}

// ---------------------------------------------------------------------------
// c3 head (1x1 on pooled vector, BN+PReLU) and fold it into the fuse-conv as
// a per-(b,co) bias: fbias[b,co] = sum_j f_w[co][256+j] * c3[b][j].
// ---------------------------------------------------------------------------
__global__ __launch_bounds__(256) void c3_fbias_kernel(
    const float* __restrict__ pool, const float* __restrict__ c3w,
    const float* __restrict__ c3b, const float* __restrict__ bng,
    const float* __restrict__ bnb, const float* __restrict__ bnm,
    const float* __restrict__ bnv, const float* __restrict__ al,
    const float* __restrict__ fw, float* __restrict__ fbias)
{
    const int b = blockIdx.x, tid = threadIdx.x;
    __shared__ float sp[256];
    __shared__ float sc3[128];
    sp[tid] = pool[b * 256 + tid];
    __syncthreads();
    if (tid < 128) {
        float acc = c3b[tid];
        for (int ci = 0; ci < 256; ++ci) acc = fmaf(c3w[tid * 256 + ci], sp[ci], acc);
        const float scale = bng[tid] * rsqrtf(bnv[tid] + EPSV);
        float t = (acc - bnm[tid]) * scale + bnb[tid];
        const float a = al[0];
        sc3[tid] = t >= 0.f ? t : a * t;
    }
    __syncthreads();
    float f = 0.f;
    for (int j = 0; j < 128; ++j) f = fmaf(fw[tid * 384 + 256 + j], sc3[j], f);
    fbias[b * 256 + tid] = f;
}

// ---------------------------------------------------------------------------
extern "C" void kernel_launch(void* const* d_in, const int* in_sizes, int n_in,
                              void* d_out, int out_size, void* d_ws, size_t ws_size,
                              hipStream_t stream)
{
    const float* x     = (const float*)d_in[0];
    const float* dc_w  = (const float*)d_in[1];
    const float* dc_b  = (const float*)d_in[2];
    const float* dc_g  = (const float*)d_in[3];
    const float* dc_bt = (const float*)d_in[4];
    const float* dc_m  = (const float*)d_in[5];
    const float* dc_v  = (const float*)d_in[6];
    const float* dc_a  = (const float*)d_in[7];
    const float* c1_w  = (const float*)d_in[8];
    const float* c1_b  = (const float*)d_in[9];
    const float* c1_g  = (const float*)d_in[10];
    const float* c1_bt = (const float*)d_in[11];
    const float* c1_m  = (const float*)d_in[12];
    const float* c1_v  = (const float*)d_in[13];
    const float* c1_a  = (const float*)d_in[14];
    const float* c2_w  = (const float*)d_in[15];
    const float* c2_b  = (const float*)d_in[16];
    const float* c2_g  = (const float*)d_in[17];
    const float* c2_bt = (const float*)d_in[18];
    const float* c2_m  = (const float*)d_in[19];
    const float* c2_v  = (const float*)d_in[20];
    const float* c2_a  = (const float*)d_in[21];
    const float* q_w   = (const float*)d_in[22];
    const float* q_b   = (const float*)d_in[23];
    const float* k_w   = (const float*)d_in[24];
    const float* k_b   = (const float*)d_in[25];
    const float* v_w   = (const float*)d_in[26];
    const float* v_b   = (const float*)d_in[27];
    const float* gamma2= (const float*)d_in[28];
    const float* c3_w  = (const float*)d_in[29];
    const float* c3_b  = (const float*)d_in[30];
    const float* c3_g  = (const float*)d_in[31];
    const float* c3_bt = (const float*)d_in[32];
    const float* c3_m  = (const float*)d_in[33];
    const float* c3_v  = (const float*)d_in[34];
    const float* c3_a  = (const float*)d_in[35];
    const float* f_w   = (const float*)d_in[36];
    const float* f_b   = (const float*)d_in[37];
    const float* f_g   = (const float*)d_in[38];
    const float* f_bt  = (const float*)d_in[39];
    const float* f_m   = (const float*)d_in[40];
    const float* f_v   = (const float*)d_in[41];
    const float* f_a   = (const float*)d_in[42];

    float* ws   = (float*)d_ws;
    float* xp   = ws;                     // 4,194,304  [4,256,64,64]
    float* c1b  = xp   + 4194304;         // 2,097,152  [4,128,64,64]
    float* c2b  = c1b  + 2097152;         // 2,097,152
    float* qb   = c2b  + 2097152;         // 262,144    [4,16,4096]
    float* kb   = qb   + 262144;          // 262,144
    float* vb   = kb   + 262144;          // 2,097,152  [4,128,4096]
    float* o2b  = vb   + 2097152;         // 2,097,152
    float* poolb= o2b  + 2097152;         // 1,024
    float* fbb  = poolb+ 1024;            // 1,024

    // 1. down_conv 3x3 512->256 + BN + PReLU
    conv3x3_bn_prelu<512, 256, 1, 2><<<dim3(32, 4, 4), 256, 0, stream>>>(
        x, dc_w, dc_b, dc_g, dc_bt, dc_m, dc_v, dc_a, xp);
    // 2. branch1: 1x1 256->128 + BN + PReLU
    conv1x1_kernel<256, true, false><<<dim3(64, 2, 4), 256, 0, stream>>>(
        xp, nullptr, c1_w, 256, 128, c1_b, c1_g, c1_bt, c1_m, c1_v, c1_a, nullptr, c1b);
    // 3. branch2: dilated 3x3 256->128 + BN + PReLU
    conv3x3_bn_prelu<256, 128, 2, 1><<<dim3(64, 2, 4), 256, 0, stream>>>(
        xp, c2_w, c2_b, c2_g, c2_bt, c2_m, c2_v, c2_a, c2b);
    // 4. q,k 1x1 128->16
    qk_kernel<<<dim3(64, 4), 256, 0, stream>>>(c2b, q_w, q_b, k_w, k_b, qb, kb);
    // 5. v 1x1 128->128 (bias only)
    conv1x1_kernel<128, false, false><<<dim3(64, 2, 4), 256, 0, stream>>>(
        c2b, nullptr, v_w, 128, 128, v_b, nullptr, nullptr, nullptr, nullptr,
        nullptr, nullptr, vb);
    // 6. attention + gamma2*out + c2
    attn_kernel<<<dim3(128, 4), 256, 0, stream>>>(qb, kb, vb, c2b, gamma2, o2b);
    // 7. global average pool of xp
    pool_kernel<<<dim3(256, 4), 256, 0, stream>>>(xp, poolb);
    // 8. c3 head folded into fuse-conv bias
    c3_fbias_kernel<<<dim3(4), 256, 0, stream>>>(
        poolb, c3_w, c3_b, c3_g, c3_bt, c3_m, c3_v, c3_a, f_w, fbb);
    // 9. fuse conv 384->256 (c1 | o2 | c3-as-bias) + BN + PReLU -> out
    conv1x1_kernel<256, true, true><<<dim3(64, 4, 4), 256, 0, stream>>>(
        c1b, o2b, f_w, 384, 256, f_b, f_g, f_bt, f_m, f_v, f_a, fbb, (float*)d_out);
}

// Round 2
// 1252.998 us; speedup vs baseline: 1.3820x; 1.3820x over previous
//
#include <hip/hip_runtime.h>
#include <hip/hip_bf16.h>
#include <math.h>

#define HW 4096
#define EPSV 1e-5f

typedef __attribute__((ext_vector_type(8))) short bf16x8;
typedef __attribute__((ext_vector_type(4))) float f32x4;

// ---------------------------------------------------------------------------
// 3x3 conv + BN + PReLU.  ROWS output rows per block, 64 co x 64 w tile.
// ---------------------------------------------------------------------------
template<int CIN, int COUT, int DIL, int ROWS>
__global__ __launch_bounds__(256) void conv3x3_bn_prelu(
    const float* __restrict__ in, const float* __restrict__ wgt,
    const float* __restrict__ bias, const float* __restrict__ bng,
    const float* __restrict__ bnb, const float* __restrict__ bnm,
    const float* __restrict__ bnv, const float* __restrict__ al,
    float* __restrict__ out)
{
    constexpr int NW  = 64 + 2 * DIL;
    constexpr int SR  = (ROWS == 1) ? 3 : (ROWS + 2);
    constexpr int NIN = 4 + 2 * DIL;

    const int tid = threadIdx.x;
    const int b   = blockIdx.z;
    const int co0 = blockIdx.y * 64;
    const int h0  = blockIdx.x * ROWS;
    const int cg  = tid >> 4, pg = tid & 15;
    const int c0l = cg * 4,  w0 = pg * 4;

    __shared__ __align__(16) float sIn[16 * SR * NW];
    __shared__ __align__(16) float sW[16 * 9 * 68];

    float acc[ROWS][4][4] = {};

    for (int cc = 0; cc < CIN; cc += 16) {
        for (int i = tid; i < 16 * SR * NW; i += 256) {
            const int col = i % NW;
            const int rest = i / NW;
            const int r  = rest % SR;
            const int ci = rest / SR;
            const int irow = (ROWS == 1) ? (h0 + (r - 1) * DIL) : (h0 - 1 + r);
            const int icol = col - DIL;
            float vv = 0.f;
            if (irow >= 0 && irow < 64 && icol >= 0 && icol < 64)
                vv = in[((b * CIN + cc + ci) * 64 + irow) * 64 + icol];
            sIn[i] = vv;
        }
        for (int i = tid; i < 16 * 9 * 64; i += 256) {
            const int co  = i / 144;
            const int rem = i - co * 144;
            const int ci  = rem / 9;
            const int tap = rem - ci * 9;
            sW[(ci * 9 + tap) * 68 + co] =
                wgt[((co0 + co) * CIN + cc + ci) * 9 + tap];
        }
        __syncthreads();

        #pragma unroll 1
        for (int ci = 0; ci < 16; ++ci) {
            float vin[SR][NIN];
            #pragma unroll
            for (int r = 0; r < SR; ++r)
                #pragma unroll
                for (int j = 0; j < NIN; ++j)
                    vin[r][j] = sIn[(ci * SR + r) * NW + w0 + j];
            #pragma unroll
            for (int dy = 0; dy < 3; ++dy)
                #pragma unroll
                for (int dx = 0; dx < 3; ++dx) {
                    const float4 wv = *(const float4*)&sW[(ci * 9 + dy * 3 + dx) * 68 + c0l];
                    const float wa[4] = {wv.x, wv.y, wv.z, wv.w};
                    #pragma unroll
                    for (int ro = 0; ro < ROWS; ++ro) {
                        const int r = (ROWS == 1) ? dy : (ro + dy);
                        #pragma unroll
                        for (int p = 0; p < 4; ++p) {
                            const float iv = vin[r][p + dx * DIL];
                            #pragma unroll
                            for (int i2 = 0; i2 < 4; ++i2)
                                acc[ro][i2][p] = fmaf(wa[i2], iv, acc[ro][i2][p]);
                        }
                    }
                }
        }
        __syncthreads();
    }

    const float a = al[0];
    #pragma unroll
    for (int i2 = 0; i2 < 4; ++i2) {
        const int co = co0 + c0l + i2;
        const float scale = bng[co] * rsqrtf(bnv[co] + EPSV);
        const float shift = bnb[co] - bnm[co] * scale;
        const float bb = bias[co];
        #pragma unroll
        for (int ro = 0; ro < ROWS; ++ro) {
            float4 o;
            float t;
            t = (acc[ro][i2][0] + bb) * scale + shift; o.x = t >= 0.f ? t : a * t;
            t = (acc[ro][i2][1] + bb) * scale + shift; o.y = t >= 0.f ? t : a * t;
            t = (acc[ro][i2][2] + bb) * scale + shift; o.z = t >= 0.f ? t : a * t;
            t = (acc[ro][i2][3] + bb) * scale + shift; o.w = t >= 0.f ? t : a * t;
            *(float4*)&out[((b * COUT + co) * 64 + h0 + ro) * 64 + w0] = o;
        }
    }
}

// ---------------------------------------------------------------------------
// Generic 1x1 conv.  OUTBF16: write bf16 instead of fp32.
// ---------------------------------------------------------------------------
template<int CIN, bool BNACT, bool DUAL, bool OUTBF16>
__global__ __launch_bounds__(256) void conv1x1_kernel(
    const float* __restrict__ in0, const float* __restrict__ in1,
    const float* __restrict__ wgt, int wstride, int COUT,
    const float* __restrict__ bias, const float* __restrict__ bng,
    const float* __restrict__ bnb, const float* __restrict__ bnm,
    const float* __restrict__ bnv, const float* __restrict__ al,
    const float* __restrict__ ebias, void* __restrict__ outv)
{
    const int tid = threadIdx.x;
    const int b = blockIdx.z, co0 = blockIdx.y * 64, p0 = blockIdx.x * 64;
    const int cg = tid >> 4, pg = tid & 15;
    const int c0l = cg * 4, w0 = pg * 4;

    __shared__ __align__(16) float sIn[16 * 64];
    __shared__ __align__(16) float sW[16 * 68];

    float acc[4][4] = {};

    for (int cc = 0; cc < CIN; cc += 16) {
        {
            int i = tid;
            #pragma unroll
            for (int it = 0; it < 4; ++it, i += 256) {
                const int px = i & 63, ci = i >> 6;
                const int ch = cc + ci;
                const float* src;
                if (DUAL)
                    src = (ch < 128) ? (in0 + (size_t)(b * 128 + ch) * HW)
                                     : (in1 + (size_t)(b * 128 + ch - 128) * HW);
                else
                    src = in0 + (size_t)(b * CIN + ch) * HW;
                sIn[ci * 64 + px] = src[p0 + px];
            }
            i = tid;
            #pragma unroll
            for (int it = 0; it < 4; ++it, i += 256) {
                const int ci = i & 15, co = i >> 4;
                sW[ci * 68 + co] = wgt[(co0 + co) * wstride + cc + ci];
            }
        }
        __syncthreads();
        #pragma unroll
        for (int ci = 0; ci < 16; ++ci) {
            const float4 iv = *(const float4*)&sIn[ci * 64 + w0];
            const float4 wv = *(const float4*)&sW[ci * 68 + c0l];
            const float ia[4] = {iv.x, iv.y, iv.z, iv.w};
            const float wa[4] = {wv.x, wv.y, wv.z, wv.w};
            #pragma unroll
            for (int i2 = 0; i2 < 4; ++i2)
                #pragma unroll
                for (int j = 0; j < 4; ++j)
                    acc[i2][j] = fmaf(wa[i2], ia[j], acc[i2][j]);
        }
        __syncthreads();
    }

    const float a = BNACT ? al[0] : 0.f;
    #pragma unroll
    for (int i2 = 0; i2 < 4; ++i2) {
        const int co = co0 + c0l + i2;
        float bb = bias[co];
        if (ebias) bb += ebias[b * COUT + co];
        float scale = 1.f, shift = bb;
        if (BNACT) {
            scale = bng[co] * rsqrtf(bnv[co] + EPSV);
            shift = bb * scale + (bnb[co] - bnm[co] * scale);
        }
        float r[4];
        #pragma unroll
        for (int j = 0; j < 4; ++j) {
            float t = acc[i2][j] * scale + shift;
            r[j] = (BNACT && t < 0.f) ? a * t : t;
        }
        const size_t base = (size_t)(b * COUT + co) * HW + p0 + w0;
        if (OUTBF16) {
            __hip_bfloat16* out = (__hip_bfloat16*)outv;
            #pragma unroll
            for (int j = 0; j < 4; ++j) out[base + j] = __float2bfloat16(r[j]);
        } else {
            float* out = (float*)outv;
            *(float4*)&out[base] = make_float4(r[0], r[1], r[2], r[3]);
        }
    }
}

// ---------------------------------------------------------------------------
// q & k 1x1 convs (128 -> 16 each) -> packed bf16 [b][4096][32] (16 ch + 16 zero)
// ---------------------------------------------------------------------------
__global__ __launch_bounds__(256) void qk_kernel(
    const float* __restrict__ c2g, const float* __restrict__ qw,
    const float* __restrict__ qb2, const float* __restrict__ kw,
    const float* __restrict__ kb2, __hip_bfloat16* __restrict__ qpack,
    __hip_bfloat16* __restrict__ kpack)
{
    const int b = blockIdx.y, p0 = blockIdx.x * 64, tid = threadIdx.x;
    __shared__ float sC[128][64];
    __shared__ float sWq[16][128];
    __shared__ float sWk[16][128];
    for (int i = tid; i < 8192; i += 256) {
        const int px = i & 63, ci = i >> 6;
        sC[ci][px] = c2g[(size_t)(b * 128 + ci) * HW + p0 + px];
    }
    for (int i = tid; i < 2048; i += 256) {
        const int ci = i & 127, co = i >> 7;
        sWq[co][ci] = qw[co * 128 + ci];
        sWk[co][ci] = kw[co * 128 + ci];
    }
    __syncthreads();
    const int px = tid & 63, grp = tid >> 6;
    const int co0 = (grp & 1) * 8;
    const bool isK = grp >= 2;
    const float* sWp = isK ? &sWk[0][0] : &sWq[0][0];
    float acc[8] = {};
    for (int ci = 0; ci < 128; ++ci) {
        const float xv = sC[ci][px];
        #pragma unroll
        for (int j = 0; j < 8; ++j)
            acc[j] = fmaf(sWp[(co0 + j) * 128 + ci], xv, acc[j]);
    }
    const float* bsrc = isK ? kb2 : qb2;
    __hip_bfloat16* osrc = isK ? kpack : qpack;
    const size_t base = (size_t)(b * 4096 + p0 + px) * 32;
    #pragma unroll
    for (int j = 0; j < 8; ++j) {
        osrc[base + co0 + j] = __float2bfloat16(acc[j] + bsrc[co0 + j]);
        osrc[base + 16 + co0 + j] = __float2bfloat16(0.f);   // zero pad ch 16..31
    }
}

// ---------------------------------------------------------------------------
// MFMA flash attention.  Block = (b, 32 queries), 4 waves.
// Wave layout: grp = wave>>1 picks n-half (16 n), wbit = wave&1 picks
// score m-subtile pair {2*wbit, 2*wbit+1} and c-half (64 c) for PV.
// Phase A: row max only.  Phase B: p=exp(s-M) (unnormalized) -> bf16 sP
// (double-buffered) -> PV MFMA; final scale by 1/S.  Epilogue fuses
// gamma2*out + c2.
// ---------------------------------------------------------------------------
__global__ __launch_bounds__(256) void attn_mfma(
    const __hip_bfloat16* __restrict__ qpack,
    const __hip_bfloat16* __restrict__ kpack,
    const __hip_bfloat16* __restrict__ vpackT,
    const float* __restrict__ c2g,
    const float* __restrict__ gamma2,
    float* __restrict__ o2)
{
    const int tid = threadIdx.x;
    const int b = blockIdx.y;
    const int n0 = blockIdx.x * 32;
    const int wave = tid >> 6, lane = tid & 63;
    const int grp = wave >> 1, wbit = wave & 1;
    const int lane15 = lane & 15, quad = lane >> 4;
    const int msb = wbit * 2;
    const int cbase = wbit * 64;

    __shared__ __align__(16) __hip_bfloat16 sP[2][2][16][72];  // [buf][grp][n][m(64)+pad]
    __shared__ float sRed[2][2][2][16];                        // [M/S][grp][wbit][row]

    const int nrow = n0 + grp * 16 + lane15;
    const bf16x8 aq = *(const bf16x8*)(qpack + ((size_t)(b * 4096 + nrow) * 32 + quad * 8));

    // ---- phase A: global row max ----
    float runM[4] = {-3e30f, -3e30f, -3e30f, -3e30f};
    for (int m0 = 0; m0 < HW; m0 += 64) {
        const int mA = m0 + msb * 16 + lane15;
        const bf16x8 bk0 = *(const bf16x8*)(kpack + ((size_t)(b * 4096 + mA) * 32 + quad * 8));
        const bf16x8 bk1 = *(const bf16x8*)(kpack + ((size_t)(b * 4096 + mA + 16) * 32 + quad * 8));
        const f32x4 z = {0.f, 0.f, 0.f, 0.f};
        const f32x4 s0 = __builtin_amdgcn_mfma_f32_16x16x32_bf16(aq, bk0, z, 0, 0, 0);
        const f32x4 s1 = __builtin_amdgcn_mfma_f32_16x16x32_bf16(aq, bk1, z, 0, 0, 0);
        #pragma unroll
        for (int r = 0; r < 4; ++r)
            runM[r] = fmaxf(runM[r], fmaxf(s0[r], s1[r]));
    }
    #pragma unroll
    for (int mask = 1; mask < 16; mask <<= 1)
        #pragma unroll
        for (int r = 0; r < 4; ++r)
            runM[r] = fmaxf(runM[r], __shfl_xor(runM[r], mask));
    if (lane15 == 0)
        #pragma unroll
        for (int r = 0; r < 4; ++r) sRed[0][grp][wbit][quad * 4 + r] = runM[r];
    __syncthreads();
    float M[4];
    #pragma unroll
    for (int r = 0; r < 4; ++r)
        M[r] = fmaxf(sRed[0][grp][0][quad * 4 + r], sRed[0][grp][1][quad * 4 + r]);

    // ---- phase B: exp + PV ----
    float runS[4] = {0.f, 0.f, 0.f, 0.f};
    f32x4 oacc[4];
    #pragma unroll
    for (int cs = 0; cs < 4; ++cs) oacc[cs] = (f32x4){0.f, 0.f, 0.f, 0.f};

    for (int t = 0; t < 64; ++t) {
        const int m0 = t * 64;
        const int buf = t & 1;
        const int mA = m0 + msb * 16 + lane15;
        const bf16x8 bk0 = *(const bf16x8*)(kpack + ((size_t)(b * 4096 + mA) * 32 + quad * 8));
        const bf16x8 bk1 = *(const bf16x8*)(kpack + ((size_t)(b * 4096 + mA + 16) * 32 + quad * 8));
        const f32x4 z = {0.f, 0.f, 0.f, 0.f};
        const f32x4 s0 = __builtin_amdgcn_mfma_f32_16x16x32_bf16(aq, bk0, z, 0, 0, 0);
        const f32x4 s1 = __builtin_amdgcn_mfma_f32_16x16x32_bf16(aq, bk1, z, 0, 0, 0);
        #pragma unroll
        for (int r = 0; r < 4; ++r) {
            const float p0 = __expf(s0[r] - M[r]);
            const float p1 = __expf(s1[r] - M[r]);
            runS[r] += p0 + p1;
            sP[buf][grp][quad * 4 + r][lane15 + 16 * msb]      = __float2bfloat16(p0);
            sP[buf][grp][quad * 4 + r][lane15 + 16 * msb + 16] = __float2bfloat16(p1);
        }
        __syncthreads();
        #pragma unroll
        for (int ks = 0; ks < 2; ++ks) {
            const bf16x8 ap = *(const bf16x8*)&sP[buf][grp][lane15][ks * 32 + quad * 8];
            #pragma unroll
            for (int cs = 0; cs < 4; ++cs) {
                const int c = cbase + cs * 16 + lane15;
                const bf16x8 bv = *(const bf16x8*)(
                    vpackT + ((size_t)(b * 128 + c) * HW + m0 + ks * 32 + quad * 8));
                oacc[cs] = __builtin_amdgcn_mfma_f32_16x16x32_bf16(ap, bv, oacc[cs], 0, 0, 0);
            }
        }
    }

    // ---- S reduction + epilogue ----
    #pragma unroll
    for (int mask = 1; mask < 16; mask <<= 1)
        #pragma unroll
        for (int r = 0; r < 4; ++r)
            runS[r] += __shfl_xor(runS[r], mask);
    if (lane15 == 0)
        #pragma unroll
        for (int r = 0; r < 4; ++r) sRed[1][grp][wbit][quad * 4 + r] = runS[r];
    __syncthreads();
    float invS[4];
    #pragma unroll
    for (int r = 0; r < 4; ++r)
        invS[r] = 1.0f / (sRed[1][grp][0][quad * 4 + r] + sRed[1][grp][1][quad * 4 + r]);

    const float g2 = gamma2[0];
    #pragma unroll
    for (int cs = 0; cs < 4; ++cs) {
        const int c = cbase + cs * 16 + lane15;
        const size_t base = (size_t)(b * 128 + c) * HW + n0 + grp * 16 + quad * 4;
        #pragma unroll
        for (int r = 0; r < 4; ++r)
            o2[base + r] = fmaf(g2, oacc[cs][r] * invS[r], c2g[base + r]);
    }
}

// ---------------------------------------------------------------------------
__global__ __launch_bounds__(256) void pool_kernel(
    const float* __restrict__ xp, float* __restrict__ pool)
{
    const int c = blockIdx.x, b = blockIdx.y, tid = threadIdx.x;
    const float4* row = (const float4*)(xp + (size_t)(b * 256 + c) * HW);
    float s = 0.f;
    #pragma unroll 4
    for (int i = tid; i < 1024; i += 256) {
        const float4 t = row[i];
        s += t.x + t.y + t.z + t.w;
    }
    __shared__ float red[256];
    red[tid] = s; __syncthreads();
    for (int st = 128; st > 0; st >>= 1) {
        if (tid < st) red[tid] += red[tid + st];
        __syncthreads();
    }
    if (tid == 0) pool[b * 256 + c] = red[0] * (1.0f / 4096.0f);
}

// ---------------------------------------------------------------------------
__global__ __launch_bounds__(256) void c3_fbias_kernel(
    const float* __restrict__ pool, const float* __restrict__ c3w,
    const float* __restrict__ c3b, const float* __restrict__ bng,
    const float* __restrict__ bnb, const float* __restrict__ bnm,
    const float* __restrict__ bnv, const float* __restrict__ al,
    const float* __restrict__ fw, float* __restrict__ fbias)
{
    const int b = blockIdx.x, tid = threadIdx.x;
    __shared__ float sp[256];
    __shared__ float sc3[128];
    sp[tid] = pool[b * 256 + tid];
    __syncthreads();
    if (tid < 128) {
        float acc = c3b[tid];
        for (int ci = 0; ci < 256; ++ci) acc = fmaf(c3w[tid * 256 + ci], sp[ci], acc);
        const float scale = bng[tid] * rsqrtf(bnv[tid] + EPSV);
        float t = (acc - bnm[tid]) * scale + bnb[tid];
        const float a = al[0];
        sc3[tid] = t >= 0.f ? t : a * t;
    }
    __syncthreads();
    float f = 0.f;
    for (int j = 0; j < 128; ++j) f = fmaf(fw[tid * 384 + 256 + j], sc3[j], f);
    fbias[b * 256 + tid] = f;
}

// ---------------------------------------------------------------------------
extern "C" void kernel_launch(void* const* d_in, const int* in_sizes, int n_in,
                              void* d_out, int out_size, void* d_ws, size_t ws_size,
                              hipStream_t stream)
{
    const float* x     = (const float*)d_in[0];
    const float* dc_w  = (const float*)d_in[1];
    const float* dc_b  = (const float*)d_in[2];
    const float* dc_g  = (const float*)d_in[3];
    const float* dc_bt = (const float*)d_in[4];
    const float* dc_m  = (const float*)d_in[5];
    const float* dc_v  = (const float*)d_in[6];
    const float* dc_a  = (const float*)d_in[7];
    const float* c1_w  = (const float*)d_in[8];
    const float* c1_b  = (const float*)d_in[9];
    const float* c1_g  = (const float*)d_in[10];
    const float* c1_bt = (const float*)d_in[11];
    const float* c1_m  = (const float*)d_in[12];
    const float* c1_v  = (const float*)d_in[13];
    const float* c1_a  = (const float*)d_in[14];
    const float* c2_w  = (const float*)d_in[15];
    const float* c2_b  = (const float*)d_in[16];
    const float* c2_g  = (const float*)d_in[17];
    const float* c2_bt = (const float*)d_in[18];
    const float* c2_m  = (const float*)d_in[19];
    const float* c2_v  = (const float*)d_in[20];
    const float* c2_a  = (const float*)d_in[21];
    const float* q_w   = (const float*)d_in[22];
    const float* q_b   = (const float*)d_in[23];
    const float* k_w   = (const float*)d_in[24];
    const float* k_b   = (const float*)d_in[25];
    const float* v_w   = (const float*)d_in[26];
    const float* v_b   = (const float*)d_in[27];
    const float* gamma2= (const float*)d_in[28];
    const float* c3_w  = (const float*)d_in[29];
    const float* c3_b  = (const float*)d_in[30];
    const float* c3_g  = (const float*)d_in[31];
    const float* c3_bt = (const float*)d_in[32];
    const float* c3_m  = (const float*)d_in[33];
    const float* c3_v  = (const float*)d_in[34];
    const float* c3_a  = (const float*)d_in[35];
    const float* f_w   = (const float*)d_in[36];
    const float* f_b   = (const float*)d_in[37];
    const float* f_g   = (const float*)d_in[38];
    const float* f_bt  = (const float*)d_in[39];
    const float* f_m   = (const float*)d_in[40];
    const float* f_v   = (const float*)d_in[41];
    const float* f_a   = (const float*)d_in[42];

    float* ws   = (float*)d_ws;
    float* xp   = ws;                     // [4,256,64,64] fp32
    float* c1b  = xp   + 4194304;         // [4,128,64,64] fp32
    float* c2b  = c1b  + 2097152;         // [4,128,64,64] fp32
    float* o2b  = c2b  + 2097152;         // [4,128,64,64] fp32
    float* poolb= o2b  + 2097152;         // 1024
    float* fbb  = poolb+ 1024;            // 1024
    __hip_bfloat16* qpk = (__hip_bfloat16*)(fbb + 1024);     // [4,4096,32] bf16
    __hip_bfloat16* kpk = qpk + 4 * 4096 * 32;               // [4,4096,32] bf16
    __hip_bfloat16* vbh = kpk + 4 * 4096 * 32;               // [4,128,4096] bf16

    // 1. down_conv 3x3 512->256 + BN + PReLU
    conv3x3_bn_prelu<512, 256, 1, 2><<<dim3(32, 4, 4), 256, 0, stream>>>(
        x, dc_w, dc_b, dc_g, dc_bt, dc_m, dc_v, dc_a, xp);
    // 2. branch1: 1x1 256->128 + BN + PReLU
    conv1x1_kernel<256, true, false, false><<<dim3(64, 2, 4), 256, 0, stream>>>(
        xp, nullptr, c1_w, 256, 128, c1_b, c1_g, c1_bt, c1_m, c1_v, c1_a, nullptr, c1b);
    // 3. branch2: dilated 3x3 256->128 + BN + PReLU
    conv3x3_bn_prelu<256, 128, 2, 1><<<dim3(64, 2, 4), 256, 0, stream>>>(
        xp, c2_w, c2_b, c2_g, c2_bt, c2_m, c2_v, c2_a, c2b);
    // 4. q,k 1x1 128->16 -> packed bf16 (K=32 zero-padded)
    qk_kernel<<<dim3(64, 4), 256, 0, stream>>>(c2b, q_w, q_b, k_w, k_b, qpk, kpk);
    // 5. v 1x1 128->128 (bias only) -> bf16 [c][m]
    conv1x1_kernel<128, false, false, true><<<dim3(64, 2, 4), 256, 0, stream>>>(
        c2b, nullptr, v_w, 128, 128, v_b, nullptr, nullptr, nullptr, nullptr,
        nullptr, nullptr, vbh);
    // 6. MFMA attention + gamma2*out + c2
    attn_mfma<<<dim3(128, 4), 256, 0, stream>>>(qpk, kpk, vbh, c2b, gamma2, o2b);
    // 7. global average pool of xp
    pool_kernel<<<dim3(256, 4), 256, 0, stream>>>(xp, poolb);
    // 8. c3 head folded into fuse-conv bias
    c3_fbias_kernel<<<dim3(4), 256, 0, stream>>>(
        poolb, c3_w, c3_b, c3_g, c3_bt, c3_m, c3_v, c3_a, f_w, fbb);
    // 9. fuse conv 384->256 + BN + PReLU -> out
    conv1x1_kernel<256, true, true, false><<<dim3(64, 4, 4), 256, 0, stream>>>(
        c1b, o2b, f_w, 384, 256, f_b, f_g, f_bt, f_m, f_v, f_a, fbb, (float*)d_out);
}

// Round 3
// 604.836 us; speedup vs baseline: 2.8630x; 2.0716x over previous
//
#include <hip/hip_runtime.h>
#include <hip/hip_bf16.h>
#include <math.h>

#define HW 4096
#define EPSV 1e-5f

typedef unsigned short ushort;
typedef __attribute__((ext_vector_type(8))) short bf16x8;
typedef __attribute__((ext_vector_type(4))) float f32x4;

__device__ inline ushort f2bf(float f) {
    __hip_bfloat16 h = __float2bfloat16(f);
    return *reinterpret_cast<ushort*>(&h);
}

// ---------------------------------------------------------------------------
// fp32 [b][C][4096] -> bf16 channel-last [b][4096][C], LDS transpose.
// ---------------------------------------------------------------------------
template<int C>
__global__ __launch_bounds__(256) void to_chlast_bf16(
    const float* __restrict__ src, ushort* __restrict__ dst)
{
    const int b = blockIdx.z, c0 = blockIdx.y * 64, p0 = blockIdx.x * 64;
    const int tid = threadIdx.x;
    __shared__ float sT[64][65];
    for (int i = tid; i < 4096; i += 256) {
        const int ch = i >> 6, px = i & 63;
        sT[ch][px] = src[(size_t)(b * C + c0 + ch) * HW + p0 + px];
    }
    __syncthreads();
    const int px = tid >> 2, seg = tid & 3;
    ushort tmp[16];
    #pragma unroll
    for (int j = 0; j < 16; ++j) tmp[j] = f2bf(sT[seg * 16 + j][px]);
    ushort* d = dst + (size_t)(b * HW + p0 + px) * C + c0 + seg * 16;
    *(uint4*)d = *(uint4*)&tmp[0];
    *(uint4*)(d + 8) = *(uint4*)&tmp[8];
}

// ---------------------------------------------------------------------------
// Pack 3x3 weights [co][ci][3][3] fp32 -> [tap][ci/32][co][ci32] bf16.
// ---------------------------------------------------------------------------
template<int CIN, int COUT>
__global__ __launch_bounds__(256) void pack_w3x3(
    const float* __restrict__ w, ushort* __restrict__ wpk)
{
    const int idx = blockIdx.x * 256 + threadIdx.x;
    constexpr int total = 9 * (CIN / 32) * COUT * 32;
    if (idx >= total) return;
    const int ci_in = idx & 31;
    int rest = idx >> 5;
    const int co = rest % COUT; rest /= COUT;
    const int cc = rest % (CIN / 32);
    const int tap = rest / (CIN / 32);
    wpk[idx] = f2bf(w[((size_t)co * CIN + cc * 32 + ci_in) * 9 + tap]);
}

// ---------------------------------------------------------------------------
// MFMA implicit-GEMM 3x3 conv + BN + PReLU.
// Block: COTILE co x (4 rows x 64 cols).  4 waves; wave w owns row h0+w.
// K = CIN x 9 taps, processed as 32-ch chunks x 9 taps from LDS.
// A-operand = weights (m=co), B-operand = pixels (n=pix).
// ---------------------------------------------------------------------------
template<int CIN, int COUT, int COTILE, int DIL>
__global__ __launch_bounds__(256) void conv3x3_mfma(
    const ushort* __restrict__ xin,   // [b][64][64][CIN] bf16
    const ushort* __restrict__ wpk,   // [9][CIN/32][COUT][32] bf16
    const float* __restrict__ bias, const float* __restrict__ bng,
    const float* __restrict__ bnb, const float* __restrict__ bnm,
    const float* __restrict__ bnv, const float* __restrict__ al,
    float* __restrict__ out)
{
    constexpr int HR = 4 + 2 * DIL;
    constexpr int NC = 64 + 2 * DIL;
    constexpr int MT = COTILE / 16;

    const int tid = threadIdx.x;
    const int wave = tid >> 6, lane = tid & 63;
    const int l15 = lane & 15, quad = lane >> 4;
    const int b = blockIdx.z;
    const int co0 = blockIdx.y * COTILE;
    const int h0 = blockIdx.x * 4;

    __shared__ __align__(16) ushort sA[HR * NC * 32];
    __shared__ __align__(16) ushort sB[9 * COTILE * 32];
    __shared__ float sScale[COTILE], sShift[COTILE];

    if (tid < COTILE) {
        const int co = co0 + tid;
        const float sc = bng[co] * rsqrtf(bnv[co] + EPSV);
        sScale[tid] = sc;
        sShift[tid] = (bias[co] - bnm[co]) * sc + bnb[co];
    }

    f32x4 acc[MT][4];
    #pragma unroll
    for (int mt = 0; mt < MT; ++mt)
        #pragma unroll
        for (int nt = 0; nt < 4; ++nt) acc[mt][nt] = (f32x4){0.f, 0.f, 0.f, 0.f};

    #pragma unroll 1
    for (int cc = 0; cc < CIN / 32; ++cc) {
        __syncthreads();
        // ---- stage pixels [pix][32ch] ----
        constexpr int NA = HR * NC * 4;
        for (int i = tid; i < NA; i += 256) {
            const int p = i >> 2, seg = i & 3;
            const int r = p / NC, c = p - r * NC;
            const int grow = h0 - DIL + r, gcol = c - DIL;
            uint4 val = {0u, 0u, 0u, 0u};
            if (grow >= 0 && grow < 64 && gcol >= 0 && gcol < 64)
                val = *(const uint4*)&xin[((size_t)(b * 64 + grow) * 64 + gcol) * CIN
                                          + cc * 32 + seg * 8];
            *(uint4*)&sA[p * 32 + seg * 8] = val;
        }
        // ---- stage weights [tap][co][32ci] ----
        constexpr int NB = 9 * COTILE * 4;
        for (int i = tid; i < NB; i += 256) {
            const int tap = i / (COTILE * 4);
            const int rem = i - tap * (COTILE * 4);
            const int co = rem >> 2, seg = rem & 3;
            *(uint4*)&sB[(tap * COTILE + co) * 32 + seg * 8] =
                *(const uint4*)&wpk[((size_t)(tap * (CIN / 32) + cc) * COUT
                                     + co0 + co) * 32 + seg * 8];
        }
        __syncthreads();

        #pragma unroll
        for (int ty = 0; ty < 3; ++ty)
            #pragma unroll
            for (int tx = 0; tx < 3; ++tx) {
                const int tap = ty * 3 + tx;
                bf16x8 aw[MT];
                #pragma unroll
                for (int mt = 0; mt < MT; ++mt)
                    aw[mt] = *(const bf16x8*)&sB[(tap * COTILE + mt * 16 + l15) * 32 + quad * 8];
                const int rl = wave + ty * DIL;
                #pragma unroll
                for (int nt = 0; nt < 4; ++nt) {
                    const int cl = nt * 16 + l15 + tx * DIL;
                    const bf16x8 bp = *(const bf16x8*)&sA[(rl * NC + cl) * 32 + quad * 8];
                    #pragma unroll
                    for (int mt = 0; mt < MT; ++mt)
                        acc[mt][nt] = __builtin_amdgcn_mfma_f32_16x16x32_bf16(
                            aw[mt], bp, acc[mt][nt], 0, 0, 0);
                }
            }
    }

    const float a = al[0];
    #pragma unroll
    for (int mt = 0; mt < MT; ++mt)
        #pragma unroll
        for (int rr = 0; rr < 4; ++rr) {
            const int col = mt * 16 + quad * 4 + rr;
            const float sc = sScale[col], sh = sShift[col];
            const int co = co0 + col;
            #pragma unroll
            for (int nt = 0; nt < 4; ++nt) {
                float t = acc[mt][nt][rr] * sc + sh;
                t = t >= 0.f ? t : a * t;
                out[((size_t)(b * COUT + co) * 64 + h0 + wave) * 64 + nt * 16 + l15] = t;
            }
        }
}

// ---------------------------------------------------------------------------
// Generic 1x1 conv.  OUTBF16: write bf16 instead of fp32.
// ---------------------------------------------------------------------------
template<int CIN, bool BNACT, bool DUAL, bool OUTBF16>
__global__ __launch_bounds__(256) void conv1x1_kernel(
    const float* __restrict__ in0, const float* __restrict__ in1,
    const float* __restrict__ wgt, int wstride, int COUT,
    const float* __restrict__ bias, const float* __restrict__ bng,
    const float* __restrict__ bnb, const float* __restrict__ bnm,
    const float* __restrict__ bnv, const float* __restrict__ al,
    const float* __restrict__ ebias, void* __restrict__ outv)
{
    const int tid = threadIdx.x;
    const int b = blockIdx.z, co0 = blockIdx.y * 64, p0 = blockIdx.x * 64;
    const int cg = tid >> 4, pg = tid & 15;
    const int c0l = cg * 4, w0 = pg * 4;

    __shared__ __align__(16) float sIn[16 * 64];
    __shared__ __align__(16) float sW[16 * 68];

    float acc[4][4] = {};

    for (int cc = 0; cc < CIN; cc += 16) {
        {
            int i = tid;
            #pragma unroll
            for (int it = 0; it < 4; ++it, i += 256) {
                const int px = i & 63, ci = i >> 6;
                const int ch = cc + ci;
                const float* src;
                if (DUAL)
                    src = (ch < 128) ? (in0 + (size_t)(b * 128 + ch) * HW)
                                     : (in1 + (size_t)(b * 128 + ch - 128) * HW);
                else
                    src = in0 + (size_t)(b * CIN + ch) * HW;
                sIn[ci * 64 + px] = src[p0 + px];
            }
            i = tid;
            #pragma unroll
            for (int it = 0; it < 4; ++it, i += 256) {
                const int ci = i & 15, co = i >> 4;
                sW[ci * 68 + co] = wgt[(co0 + co) * wstride + cc + ci];
            }
        }
        __syncthreads();
        #pragma unroll
        for (int ci = 0; ci < 16; ++ci) {
            const float4 iv = *(const float4*)&sIn[ci * 64 + w0];
            const float4 wv = *(const float4*)&sW[ci * 68 + c0l];
            const float ia[4] = {iv.x, iv.y, iv.z, iv.w};
            const float wa[4] = {wv.x, wv.y, wv.z, wv.w};
            #pragma unroll
            for (int i2 = 0; i2 < 4; ++i2)
                #pragma unroll
                for (int j = 0; j < 4; ++j)
                    acc[i2][j] = fmaf(wa[i2], ia[j], acc[i2][j]);
        }
        __syncthreads();
    }

    const float a = BNACT ? al[0] : 0.f;
    #pragma unroll
    for (int i2 = 0; i2 < 4; ++i2) {
        const int co = co0 + c0l + i2;
        float bb = bias[co];
        if (ebias) bb += ebias[b * COUT + co];
        float scale = 1.f, shift = bb;
        if (BNACT) {
            scale = bng[co] * rsqrtf(bnv[co] + EPSV);
            shift = bb * scale + (bnb[co] - bnm[co] * scale);
        }
        float r[4];
        #pragma unroll
        for (int j = 0; j < 4; ++j) {
            float t = acc[i2][j] * scale + shift;
            r[j] = (BNACT && t < 0.f) ? a * t : t;
        }
        const size_t base = (size_t)(b * COUT + co) * HW + p0 + w0;
        if (OUTBF16) {
            ushort* out = (ushort*)outv;
            #pragma unroll
            for (int j = 0; j < 4; ++j) out[base + j] = f2bf(r[j]);
        } else {
            float* out = (float*)outv;
            *(float4*)&out[base] = make_float4(r[0], r[1], r[2], r[3]);
        }
    }
}

// ---------------------------------------------------------------------------
// q & k 1x1 convs (128 -> 16 each) -> packed bf16 [b][4096][32] (16 ch + 16 zero)
// ---------------------------------------------------------------------------
__global__ __launch_bounds__(256) void qk_kernel(
    const float* __restrict__ c2g, const float* __restrict__ qw,
    const float* __restrict__ qb2, const float* __restrict__ kw,
    const float* __restrict__ kb2, ushort* __restrict__ qpack,
    ushort* __restrict__ kpack)
{
    const int b = blockIdx.y, p0 = blockIdx.x * 64, tid = threadIdx.x;
    __shared__ float sC[128][64];
    __shared__ float sWq[16][128];
    __shared__ float sWk[16][128];
    for (int i = tid; i < 8192; i += 256) {
        const int px = i & 63, ci = i >> 6;
        sC[ci][px] = c2g[(size_t)(b * 128 + ci) * HW + p0 + px];
    }
    for (int i = tid; i < 2048; i += 256) {
        const int ci = i & 127, co = i >> 7;
        sWq[co][ci] = qw[co * 128 + ci];
        sWk[co][ci] = kw[co * 128 + ci];
    }
    __syncthreads();
    const int px = tid & 63, grp = tid >> 6;
    const int co0 = (grp & 1) * 8;
    const bool isK = grp >= 2;
    const float* sWp = isK ? &sWk[0][0] : &sWq[0][0];
    float acc[8] = {};
    for (int ci = 0; ci < 128; ++ci) {
        const float xv = sC[ci][px];
        #pragma unroll
        for (int j = 0; j < 8; ++j)
            acc[j] = fmaf(sWp[(co0 + j) * 128 + ci], xv, acc[j]);
    }
    const float* bsrc = isK ? kb2 : qb2;
    ushort* osrc = isK ? kpack : qpack;
    const size_t base = (size_t)(b * 4096 + p0 + px) * 32;
    #pragma unroll
    for (int j = 0; j < 8; ++j) {
        osrc[base + co0 + j] = f2bf(acc[j] + bsrc[co0 + j]);
        osrc[base + 16 + co0 + j] = 0;   // bf16 zero
    }
}

// ---------------------------------------------------------------------------
// MFMA flash attention (as round 2).
// ---------------------------------------------------------------------------
__global__ __launch_bounds__(256) void attn_mfma(
    const ushort* __restrict__ qpack,
    const ushort* __restrict__ kpack,
    const ushort* __restrict__ vpackT,
    const float* __restrict__ c2g,
    const float* __restrict__ gamma2,
    float* __restrict__ o2)
{
    const int tid = threadIdx.x;
    const int b = blockIdx.y;
    const int n0 = blockIdx.x * 32;
    const int wave = tid >> 6, lane = tid & 63;
    const int grp = wave >> 1, wbit = wave & 1;
    const int lane15 = lane & 15, quad = lane >> 4;
    const int msb = wbit * 2;
    const int cbase = wbit * 64;

    __shared__ __align__(16) ushort sP[2][2][16][72];
    __shared__ float sRed[2][2][2][16];

    const int nrow = n0 + grp * 16 + lane15;
    const bf16x8 aq = *(const bf16x8*)(qpack + ((size_t)(b * 4096 + nrow) * 32 + quad * 8));

    float runM[4] = {-3e30f, -3e30f, -3e30f, -3e30f};
    for (int m0 = 0; m0 < HW; m0 += 64) {
        const int mA = m0 + msb * 16 + lane15;
        const bf16x8 bk0 = *(const bf16x8*)(kpack + ((size_t)(b * 4096 + mA) * 32 + quad * 8));
        const bf16x8 bk1 = *(const bf16x8*)(kpack + ((size_t)(b * 4096 + mA + 16) * 32 + quad * 8));
        const f32x4 z = {0.f, 0.f, 0.f, 0.f};
        const f32x4 s0 = __builtin_amdgcn_mfma_f32_16x16x32_bf16(aq, bk0, z, 0, 0, 0);
        const f32x4 s1 = __builtin_amdgcn_mfma_f32_16x16x32_bf16(aq, bk1, z, 0, 0, 0);
        #pragma unroll
        for (int r = 0; r < 4; ++r)
            runM[r] = fmaxf(runM[r], fmaxf(s0[r], s1[r]));
    }
    #pragma unroll
    for (int mask = 1; mask < 16; mask <<= 1)
        #pragma unroll
        for (int r = 0; r < 4; ++r)
            runM[r] = fmaxf(runM[r], __shfl_xor(runM[r], mask));
    if (lane15 == 0)
        #pragma unroll
        for (int r = 0; r < 4; ++r) sRed[0][grp][wbit][quad * 4 + r] = runM[r];
    __syncthreads();
    float M[4];
    #pragma unroll
    for (int r = 0; r < 4; ++r)
        M[r] = fmaxf(sRed[0][grp][0][quad * 4 + r], sRed[0][grp][1][quad * 4 + r]);

    float runS[4] = {0.f, 0.f, 0.f, 0.f};
    f32x4 oacc[4];
    #pragma unroll
    for (int cs = 0; cs < 4; ++cs) oacc[cs] = (f32x4){0.f, 0.f, 0.f, 0.f};

    for (int t = 0; t < 64; ++t) {
        const int m0 = t * 64;
        const int buf = t & 1;
        const int mA = m0 + msb * 16 + lane15;
        const bf16x8 bk0 = *(const bf16x8*)(kpack + ((size_t)(b * 4096 + mA) * 32 + quad * 8));
        const bf16x8 bk1 = *(const bf16x8*)(kpack + ((size_t)(b * 4096 + mA + 16) * 32 + quad * 8));
        const f32x4 z = {0.f, 0.f, 0.f, 0.f};
        const f32x4 s0 = __builtin_amdgcn_mfma_f32_16x16x32_bf16(aq, bk0, z, 0, 0, 0);
        const f32x4 s1 = __builtin_amdgcn_mfma_f32_16x16x32_bf16(aq, bk1, z, 0, 0, 0);
        #pragma unroll
        for (int r = 0; r < 4; ++r) {
            const float p0 = __expf(s0[r] - M[r]);
            const float p1 = __expf(s1[r] - M[r]);
            runS[r] += p0 + p1;
            sP[buf][grp][quad * 4 + r][lane15 + 16 * msb]      = f2bf(p0);
            sP[buf][grp][quad * 4 + r][lane15 + 16 * msb + 16] = f2bf(p1);
        }
        __syncthreads();
        #pragma unroll
        for (int ks = 0; ks < 2; ++ks) {
            const bf16x8 ap = *(const bf16x8*)&sP[buf][grp][lane15][ks * 32 + quad * 8];
            #pragma unroll
            for (int cs = 0; cs < 4; ++cs) {
                const int c = cbase + cs * 16 + lane15;
                const bf16x8 bv = *(const bf16x8*)(
                    vpackT + ((size_t)(b * 128 + c) * HW + m0 + ks * 32 + quad * 8));
                oacc[cs] = __builtin_amdgcn_mfma_f32_16x16x32_bf16(ap, bv, oacc[cs], 0, 0, 0);
            }
        }
    }

    #pragma unroll
    for (int mask = 1; mask < 16; mask <<= 1)
        #pragma unroll
        for (int r = 0; r < 4; ++r)
            runS[r] += __shfl_xor(runS[r], mask);
    if (lane15 == 0)
        #pragma unroll
        for (int r = 0; r < 4; ++r) sRed[1][grp][wbit][quad * 4 + r] = runS[r];
    __syncthreads();
    float invS[4];
    #pragma unroll
    for (int r = 0; r < 4; ++r)
        invS[r] = 1.0f / (sRed[1][grp][0][quad * 4 + r] + sRed[1][grp][1][quad * 4 + r]);

    const float g2 = gamma2[0];
    #pragma unroll
    for (int cs = 0; cs < 4; ++cs) {
        const int c = cbase + cs * 16 + lane15;
        const size_t base = (size_t)(b * 128 + c) * HW + n0 + grp * 16 + quad * 4;
        #pragma unroll
        for (int r = 0; r < 4; ++r)
            o2[base + r] = fmaf(g2, oacc[cs][r] * invS[r], c2g[base + r]);
    }
}

// ---------------------------------------------------------------------------
__global__ __launch_bounds__(256) void pool_kernel(
    const float* __restrict__ xp, float* __restrict__ pool)
{
    const int c = blockIdx.x, b = blockIdx.y, tid = threadIdx.x;
    const float4* row = (const float4*)(xp + (size_t)(b * 256 + c) * HW);
    float s = 0.f;
    #pragma unroll 4
    for (int i = tid; i < 1024; i += 256) {
        const float4 t = row[i];
        s += t.x + t.y + t.z + t.w;
    }
    __shared__ float red[256];
    red[tid] = s; __syncthreads();
    for (int st = 128; st > 0; st >>= 1) {
        if (tid < st) red[tid] += red[tid + st];
        __syncthreads();
    }
    if (tid == 0) pool[b * 256 + c] = red[0] * (1.0f / 4096.0f);
}

// ---------------------------------------------------------------------------
__global__ __launch_bounds__(256) void c3_fbias_kernel(
    const float* __restrict__ pool, const float* __restrict__ c3w,
    const float* __restrict__ c3b, const float* __restrict__ bng,
    const float* __restrict__ bnb, const float* __restrict__ bnm,
    const float* __restrict__ bnv, const float* __restrict__ al,
    const float* __restrict__ fw, float* __restrict__ fbias)
{
    const int b = blockIdx.x, tid = threadIdx.x;
    __shared__ float sp[256];
    __shared__ float sc3[128];
    sp[tid] = pool[b * 256 + tid];
    __syncthreads();
    if (tid < 128) {
        float acc = c3b[tid];
        for (int ci = 0; ci < 256; ++ci) acc = fmaf(c3w[tid * 256 + ci], sp[ci], acc);
        const float scale = bng[tid] * rsqrtf(bnv[tid] + EPSV);
        float t = (acc - bnm[tid]) * scale + bnb[tid];
        const float a = al[0];
        sc3[tid] = t >= 0.f ? t : a * t;
    }
    __syncthreads();
    float f = 0.f;
    for (int j = 0; j < 128; ++j) f = fmaf(fw[tid * 384 + 256 + j], sc3[j], f);
    fbias[b * 256 + tid] = f;
}

// ---------------------------------------------------------------------------
extern "C" void kernel_launch(void* const* d_in, const int* in_sizes, int n_in,
                              void* d_out, int out_size, void* d_ws, size_t ws_size,
                              hipStream_t stream)
{
    const float* x     = (const float*)d_in[0];
    const float* dc_w  = (const float*)d_in[1];
    const float* dc_b  = (const float*)d_in[2];
    const float* dc_g  = (const float*)d_in[3];
    const float* dc_bt = (const float*)d_in[4];
    const float* dc_m  = (const float*)d_in[5];
    const float* dc_v  = (const float*)d_in[6];
    const float* dc_a  = (const float*)d_in[7];
    const float* c1_w  = (const float*)d_in[8];
    const float* c1_b  = (const float*)d_in[9];
    const float* c1_g  = (const float*)d_in[10];
    const float* c1_bt = (const float*)d_in[11];
    const float* c1_m  = (const float*)d_in[12];
    const float* c1_v  = (const float*)d_in[13];
    const float* c1_a  = (const float*)d_in[14];
    const float* c2_w  = (const float*)d_in[15];
    const float* c2_b  = (const float*)d_in[16];
    const float* c2_g  = (const float*)d_in[17];
    const float* c2_bt = (const float*)d_in[18];
    const float* c2_m  = (const float*)d_in[19];
    const float* c2_v  = (const float*)d_in[20];
    const float* c2_a  = (const float*)d_in[21];
    const float* q_w   = (const float*)d_in[22];
    const float* q_b   = (const float*)d_in[23];
    const float* k_w   = (const float*)d_in[24];
    const float* k_b   = (const float*)d_in[25];
    const float* v_w   = (const float*)d_in[26];
    const float* v_b   = (const float*)d_in[27];
    const float* gamma2= (const float*)d_in[28];
    const float* c3_w  = (const float*)d_in[29];
    const float* c3_b  = (const float*)d_in[30];
    const float* c3_g  = (const float*)d_in[31];
    const float* c3_bt = (const float*)d_in[32];
    const float* c3_m  = (const float*)d_in[33];
    const float* c3_v  = (const float*)d_in[34];
    const float* c3_a  = (const float*)d_in[35];
    const float* f_w   = (const float*)d_in[36];
    const float* f_b   = (const float*)d_in[37];
    const float* f_g   = (const float*)d_in[38];
    const float* f_bt  = (const float*)d_in[39];
    const float* f_m   = (const float*)d_in[40];
    const float* f_v   = (const float*)d_in[41];
    const float* f_a   = (const float*)d_in[42];

    float* ws   = (float*)d_ws;
    float* xp   = ws;                     // [4,256,4096] fp32
    float* c1b  = xp   + 4194304;         // [4,128,4096] fp32
    float* c2b  = c1b  + 2097152;
    float* o2b  = c2b  + 2097152;
    float* poolb= o2b  + 2097152;         // 1024
    float* fbb  = poolb+ 1024;            // 1024
    ushort* qpk  = (ushort*)(fbb + 1024); // [4,4096,32] bf16
    ushort* kpk  = qpk + 4 * 4096 * 32;
    ushort* vbh  = kpk + 4 * 4096 * 32;   // [4,128,4096] bf16
    ushort* xbf  = vbh + 4 * 128 * 4096;  // [4,4096,512] bf16 channel-last
    ushort* xpbf = xbf + (size_t)4 * 4096 * 512;   // [4,4096,256] bf16
    ushort* wdcp = xpbf + (size_t)4 * 4096 * 256;  // [9,16,256,32] bf16
    ushort* wc2p = wdcp + 9 * 16 * 256 * 32;       // [9,8,128,32]  bf16

    // 0a. pack weights to bf16 MFMA layouts
    pack_w3x3<512, 256><<<dim3((9*16*256*32 + 255)/256), 256, 0, stream>>>(dc_w, wdcp);
    pack_w3x3<256, 128><<<dim3((9*8*128*32 + 255)/256), 256, 0, stream>>>(c2_w, wc2p);
    // 0b. x -> channel-last bf16
    to_chlast_bf16<512><<<dim3(64, 8, 4), 256, 0, stream>>>(x, xbf);
    // 1. down_conv 3x3 512->256 + BN + PReLU (MFMA)
    conv3x3_mfma<512, 256, 64, 1><<<dim3(16, 4, 4), 256, 0, stream>>>(
        xbf, wdcp, dc_b, dc_g, dc_bt, dc_m, dc_v, dc_a, xp);
    // 1b. xp -> channel-last bf16 for c2
    to_chlast_bf16<256><<<dim3(64, 4, 4), 256, 0, stream>>>(xp, xpbf);
    // 2. branch1: 1x1 256->128 + BN + PReLU
    conv1x1_kernel<256, true, false, false><<<dim3(64, 2, 4), 256, 0, stream>>>(
        xp, nullptr, c1_w, 256, 128, c1_b, c1_g, c1_bt, c1_m, c1_v, c1_a, nullptr, c1b);
    // 3. branch2: dilated 3x3 256->128 + BN + PReLU (MFMA)
    conv3x3_mfma<256, 128, 32, 2><<<dim3(16, 4, 4), 256, 0, stream>>>(
        xpbf, wc2p, c2_b, c2_g, c2_bt, c2_m, c2_v, c2_a, c2b);
    // 4. q,k 1x1 128->16 -> packed bf16
    qk_kernel<<<dim3(64, 4), 256, 0, stream>>>(c2b, q_w, q_b, k_w, k_b, qpk, kpk);
    // 5. v 1x1 128->128 (bias only) -> bf16 [c][m]
    conv1x1_kernel<128, false, false, true><<<dim3(64, 2, 4), 256, 0, stream>>>(
        c2b, nullptr, v_w, 128, 128, v_b, nullptr, nullptr, nullptr, nullptr,
        nullptr, nullptr, vbh);
    // 6. MFMA attention + gamma2*out + c2
    attn_mfma<<<dim3(128, 4), 256, 0, stream>>>(qpk, kpk, vbh, c2b, gamma2, o2b);
    // 7. global average pool of xp
    pool_kernel<<<dim3(256, 4), 256, 0, stream>>>(xp, poolb);
    // 8. c3 head folded into fuse-conv bias
    c3_fbias_kernel<<<dim3(4), 256, 0, stream>>>(
        poolb, c3_w, c3_b, c3_g, c3_bt, c3_m, c3_v, c3_a, f_w, fbb);
    // 9. fuse conv 384->256 + BN + PReLU -> out
    conv1x1_kernel<256, true, true, false><<<dim3(64, 4, 4), 256, 0, stream>>>(
        c1b, o2b, f_w, 384, 256, f_b, f_g, f_bt, f_m, f_v, f_a, fbb, (float*)d_out);
}

// Round 4
// 571.745 us; speedup vs baseline: 3.0287x; 1.0579x over previous
//
#include <hip/hip_runtime.h>
#include <hip/hip_bf16.h>
#include <math.h>

#define HW 4096
#define EPSV 1e-5f

typedef unsigned short ushort;
typedef __attribute__((ext_vector_type(8))) short bf16x8;
typedef __attribute__((ext_vector_type(4))) float f32x4;

__device__ inline ushort f2bf(float f) {
    __hip_bfloat16 h = __float2bfloat16(f);
    return *reinterpret_cast<ushort*>(&h);
}
__device__ inline float bf2f(ushort u) {
    unsigned int v = ((unsigned int)u) << 16;
    return __uint_as_float(v);
}

// ---------------------------------------------------------------------------
// fp32 [b][C][4096] -> bf16 channel-last [b][4096][C], LDS transpose.
// ---------------------------------------------------------------------------
template<int C>
__global__ __launch_bounds__(256) void to_chlast_bf16(
    const float* __restrict__ src, ushort* __restrict__ dst)
{
    const int b = blockIdx.z, c0 = blockIdx.y * 64, p0 = blockIdx.x * 64;
    const int tid = threadIdx.x;
    __shared__ float sT[64][65];
    for (int i = tid; i < 4096; i += 256) {
        const int ch = i >> 6, px = i & 63;
        sT[ch][px] = src[(size_t)(b * C + c0 + ch) * HW + p0 + px];
    }
    __syncthreads();
    const int px = tid >> 2, seg = tid & 3;
    ushort tmp[16];
    #pragma unroll
    for (int j = 0; j < 16; ++j) tmp[j] = f2bf(sT[seg * 16 + j][px]);
    ushort* d = dst + (size_t)(b * HW + p0 + px) * C + c0 + seg * 16;
    *(uint4*)d = *(uint4*)&tmp[0];
    *(uint4*)(d + 8) = *(uint4*)&tmp[8];
}

// ---------------------------------------------------------------------------
// Pack 3x3 weights [co][ci][3][3] fp32 -> [tap][ci/32][co][ci32] bf16.
// ---------------------------------------------------------------------------
template<int CIN, int COUT>
__global__ __launch_bounds__(256) void pack_w3x3(
    const float* __restrict__ w, ushort* __restrict__ wpk)
{
    const int idx = blockIdx.x * 256 + threadIdx.x;
    constexpr int total = 9 * (CIN / 32) * COUT * 32;
    if (idx >= total) return;
    const int ci_in = idx & 31;
    int rest = idx >> 5;
    const int co = rest % COUT; rest /= COUT;
    const int cc = rest % (CIN / 32);
    const int tap = rest / (CIN / 32);
    wpk[idx] = f2bf(w[((size_t)co * CIN + cc * 32 + ci_in) * 9 + tap]);
}

// ---------------------------------------------------------------------------
// MFMA implicit-GEMM 3x3 conv + BN + PReLU.
// ---------------------------------------------------------------------------
template<int CIN, int COUT, int COTILE, int DIL>
__global__ __launch_bounds__(256) void conv3x3_mfma(
    const ushort* __restrict__ xin,   // [b][64][64][CIN] bf16
    const ushort* __restrict__ wpk,   // [9][CIN/32][COUT][32] bf16
    const float* __restrict__ bias, const float* __restrict__ bng,
    const float* __restrict__ bnb, const float* __restrict__ bnm,
    const float* __restrict__ bnv, const float* __restrict__ al,
    float* __restrict__ out)
{
    constexpr int HR = 4 + 2 * DIL;
    constexpr int NC = 64 + 2 * DIL;
    constexpr int MT = COTILE / 16;

    const int tid = threadIdx.x;
    const int wave = tid >> 6, lane = tid & 63;
    const int l15 = lane & 15, quad = lane >> 4;
    const int b = blockIdx.z;
    const int co0 = blockIdx.y * COTILE;
    const int h0 = blockIdx.x * 4;

    __shared__ __align__(16) ushort sA[HR * NC * 32];
    __shared__ __align__(16) ushort sB[9 * COTILE * 32];
    __shared__ float sScale[COTILE], sShift[COTILE];

    if (tid < COTILE) {
        const int co = co0 + tid;
        const float sc = bng[co] * rsqrtf(bnv[co] + EPSV);
        sScale[tid] = sc;
        sShift[tid] = (bias[co] - bnm[co]) * sc + bnb[co];
    }

    f32x4 acc[MT][4];
    #pragma unroll
    for (int mt = 0; mt < MT; ++mt)
        #pragma unroll
        for (int nt = 0; nt < 4; ++nt) acc[mt][nt] = (f32x4){0.f, 0.f, 0.f, 0.f};

    #pragma unroll 1
    for (int cc = 0; cc < CIN / 32; ++cc) {
        __syncthreads();
        constexpr int NA = HR * NC * 4;
        for (int i = tid; i < NA; i += 256) {
            const int p = i >> 2, seg = i & 3;
            const int r = p / NC, c = p - r * NC;
            const int grow = h0 - DIL + r, gcol = c - DIL;
            uint4 val = {0u, 0u, 0u, 0u};
            if (grow >= 0 && grow < 64 && gcol >= 0 && gcol < 64)
                val = *(const uint4*)&xin[((size_t)(b * 64 + grow) * 64 + gcol) * CIN
                                          + cc * 32 + seg * 8];
            *(uint4*)&sA[p * 32 + seg * 8] = val;
        }
        constexpr int NB = 9 * COTILE * 4;
        for (int i = tid; i < NB; i += 256) {
            const int tap = i / (COTILE * 4);
            const int rem = i - tap * (COTILE * 4);
            const int co = rem >> 2, seg = rem & 3;
            *(uint4*)&sB[(tap * COTILE + co) * 32 + seg * 8] =
                *(const uint4*)&wpk[((size_t)(tap * (CIN / 32) + cc) * COUT
                                     + co0 + co) * 32 + seg * 8];
        }
        __syncthreads();

        #pragma unroll
        for (int ty = 0; ty < 3; ++ty)
            #pragma unroll
            for (int tx = 0; tx < 3; ++tx) {
                const int tap = ty * 3 + tx;
                bf16x8 aw[MT];
                #pragma unroll
                for (int mt = 0; mt < MT; ++mt)
                    aw[mt] = *(const bf16x8*)&sB[(tap * COTILE + mt * 16 + l15) * 32 + quad * 8];
                const int rl = wave + ty * DIL;
                #pragma unroll
                for (int nt = 0; nt < 4; ++nt) {
                    const int cl = nt * 16 + l15 + tx * DIL;
                    const bf16x8 bp = *(const bf16x8*)&sA[(rl * NC + cl) * 32 + quad * 8];
                    #pragma unroll
                    for (int mt = 0; mt < MT; ++mt)
                        acc[mt][nt] = __builtin_amdgcn_mfma_f32_16x16x32_bf16(
                            aw[mt], bp, acc[mt][nt], 0, 0, 0);
                }
            }
    }

    const float a = al[0];
    #pragma unroll
    for (int mt = 0; mt < MT; ++mt)
        #pragma unroll
        for (int rr = 0; rr < 4; ++rr) {
            const int col = mt * 16 + quad * 4 + rr;
            const float sc = sScale[col], sh = sShift[col];
            const int co = co0 + col;
            #pragma unroll
            for (int nt = 0; nt < 4; ++nt) {
                float t = acc[mt][nt][rr] * sc + sh;
                t = t >= 0.f ? t : a * t;
                out[((size_t)(b * COUT + co) * 64 + h0 + wave) * 64 + nt * 16 + l15] = t;
            }
        }
}

// ---------------------------------------------------------------------------
// Generic 1x1 conv.  OUTBF16: write bf16 instead of fp32.
// ---------------------------------------------------------------------------
template<int CIN, bool BNACT, bool DUAL, bool OUTBF16>
__global__ __launch_bounds__(256) void conv1x1_kernel(
    const float* __restrict__ in0, const float* __restrict__ in1,
    const float* __restrict__ wgt, int wstride, int COUT,
    const float* __restrict__ bias, const float* __restrict__ bng,
    const float* __restrict__ bnb, const float* __restrict__ bnm,
    const float* __restrict__ bnv, const float* __restrict__ al,
    const float* __restrict__ ebias, void* __restrict__ outv)
{
    const int tid = threadIdx.x;
    const int b = blockIdx.z, co0 = blockIdx.y * 64, p0 = blockIdx.x * 64;
    const int cg = tid >> 4, pg = tid & 15;
    const int c0l = cg * 4, w0 = pg * 4;

    __shared__ __align__(16) float sIn[16 * 64];
    __shared__ __align__(16) float sW[16 * 68];

    float acc[4][4] = {};

    for (int cc = 0; cc < CIN; cc += 16) {
        {
            int i = tid;
            #pragma unroll
            for (int it = 0; it < 4; ++it, i += 256) {
                const int px = i & 63, ci = i >> 6;
                const int ch = cc + ci;
                const float* src;
                if (DUAL)
                    src = (ch < 128) ? (in0 + (size_t)(b * 128 + ch) * HW)
                                     : (in1 + (size_t)(b * 128 + ch - 128) * HW);
                else
                    src = in0 + (size_t)(b * CIN + ch) * HW;
                sIn[ci * 64 + px] = src[p0 + px];
            }
            i = tid;
            #pragma unroll
            for (int it = 0; it < 4; ++it, i += 256) {
                const int ci = i & 15, co = i >> 4;
                sW[ci * 68 + co] = wgt[(co0 + co) * wstride + cc + ci];
            }
        }
        __syncthreads();
        #pragma unroll
        for (int ci = 0; ci < 16; ++ci) {
            const float4 iv = *(const float4*)&sIn[ci * 64 + w0];
            const float4 wv = *(const float4*)&sW[ci * 68 + c0l];
            const float ia[4] = {iv.x, iv.y, iv.z, iv.w};
            const float wa[4] = {wv.x, wv.y, wv.z, wv.w};
            #pragma unroll
            for (int i2 = 0; i2 < 4; ++i2)
                #pragma unroll
                for (int j = 0; j < 4; ++j)
                    acc[i2][j] = fmaf(wa[i2], ia[j], acc[i2][j]);
        }
        __syncthreads();
    }

    const float a = BNACT ? al[0] : 0.f;
    #pragma unroll
    for (int i2 = 0; i2 < 4; ++i2) {
        const int co = co0 + c0l + i2;
        float bb = bias[co];
        if (ebias) bb += ebias[b * COUT + co];
        float scale = 1.f, shift = bb;
        if (BNACT) {
            scale = bng[co] * rsqrtf(bnv[co] + EPSV);
            shift = bb * scale + (bnb[co] - bnm[co] * scale);
        }
        float r[4];
        #pragma unroll
        for (int j = 0; j < 4; ++j) {
            float t = acc[i2][j] * scale + shift;
            r[j] = (BNACT && t < 0.f) ? a * t : t;
        }
        const size_t base = (size_t)(b * COUT + co) * HW + p0 + w0;
        if (OUTBF16) {
            ushort* out = (ushort*)outv;
            #pragma unroll
            for (int j = 0; j < 4; ++j) out[base + j] = f2bf(r[j]);
        } else {
            float* out = (float*)outv;
            *(float4*)&out[base] = make_float4(r[0], r[1], r[2], r[3]);
        }
    }
}

// ---------------------------------------------------------------------------
// q & k 1x1 convs (128 -> 16 each) -> packed bf16 [b][4096][32] (16 ch + 16 zero)
// ---------------------------------------------------------------------------
__global__ __launch_bounds__(256) void qk_kernel(
    const float* __restrict__ c2g, const float* __restrict__ qw,
    const float* __restrict__ qb2, const float* __restrict__ kw,
    const float* __restrict__ kb2, ushort* __restrict__ qpack,
    ushort* __restrict__ kpack)
{
    const int b = blockIdx.y, p0 = blockIdx.x * 64, tid = threadIdx.x;
    __shared__ float sC[128][64];
    __shared__ float sWq[16][128];
    __shared__ float sWk[16][128];
    for (int i = tid; i < 8192; i += 256) {
        const int px = i & 63, ci = i >> 6;
        sC[ci][px] = c2g[(size_t)(b * 128 + ci) * HW + p0 + px];
    }
    for (int i = tid; i < 2048; i += 256) {
        const int ci = i & 127, co = i >> 7;
        sWq[co][ci] = qw[co * 128 + ci];
        sWk[co][ci] = kw[co * 128 + ci];
    }
    __syncthreads();
    const int px = tid & 63, grp = tid >> 6;
    const int co0 = (grp & 1) * 8;
    const bool isK = grp >= 2;
    const float* sWp = isK ? &sWk[0][0] : &sWq[0][0];
    float acc[8] = {};
    for (int ci = 0; ci < 128; ++ci) {
        const float xv = sC[ci][px];
        #pragma unroll
        for (int j = 0; j < 8; ++j)
            acc[j] = fmaf(sWp[(co0 + j) * 128 + ci], xv, acc[j]);
    }
    const float* bsrc = isK ? kb2 : qb2;
    ushort* osrc = isK ? kpack : qpack;
    const size_t base = (size_t)(b * 4096 + p0 + px) * 32;
    #pragma unroll
    for (int j = 0; j < 8; ++j) {
        osrc[base + co0 + j] = f2bf(acc[j] + bsrc[co0 + j]);
        osrc[base + 16 + co0 + j] = 0;
    }
}

// ---------------------------------------------------------------------------
// One-pass flash attention, wave-private (NO barriers in main loop).
// Block = 256 thr = 4 waves; wave owns 16 queries.  Grid: (64 nblk, 4 msplit,
// 4 batch).  Each block sweeps 1024 m with online softmax; writes unnormalized
// partial O (bf16), rowwise M and S to workspace.
// ---------------------------------------------------------------------------
__global__ __launch_bounds__(256) void attn_flash(
    const ushort* __restrict__ qpack,
    const ushort* __restrict__ kpack,
    const ushort* __restrict__ vpackT,
    ushort* __restrict__ opart,       // [b][4j][4096n][128c] bf16
    float* __restrict__ Mpart,        // [b][4j][4096n]
    float* __restrict__ Spart)
{
    const int tid = threadIdx.x;
    const int wave = tid >> 6, lane = tid & 63;
    const int l15 = lane & 15, quad = lane >> 4;
    const int b = blockIdx.z, j = blockIdx.y;
    const int n0w = blockIdx.x * 64 + wave * 16;
    const int m_begin = j * 1024;

    __shared__ __align__(16) ushort sP[4][16][68];   // wave-private P tiles

    const bf16x8 aq = *(const bf16x8*)(qpack + ((size_t)(b * 4096 + n0w + l15) * 32 + quad * 8));

    float runM[4] = {-3e30f, -3e30f, -3e30f, -3e30f};
    float runS[4] = {0.f, 0.f, 0.f, 0.f};
    f32x4 oacc[8];
    #pragma unroll
    for (int cs = 0; cs < 8; ++cs) oacc[cs] = (f32x4){0.f, 0.f, 0.f, 0.f};

    #pragma unroll 1
    for (int t = 0; t < 16; ++t) {
        const int m0 = m_begin + t * 64;
        // ---- scores: 4 MFMAs (16n x 64m), K=32 ----
        f32x4 s[4];
        const f32x4 z = {0.f, 0.f, 0.f, 0.f};
        #pragma unroll
        for (int ms = 0; ms < 4; ++ms) {
            const bf16x8 bk = *(const bf16x8*)(
                kpack + ((size_t)(b * 4096 + m0 + ms * 16 + l15) * 32 + quad * 8));
            s[ms] = __builtin_amdgcn_mfma_f32_16x16x32_bf16(aq, bk, z, 0, 0, 0);
        }
        // ---- tile row max (cross-lane over the 16 m-lanes) ----
        float tmax[4];
        #pragma unroll
        for (int r = 0; r < 4; ++r)
            tmax[r] = fmaxf(fmaxf(s[0][r], s[1][r]), fmaxf(s[2][r], s[3][r]));
        #pragma unroll
        for (int mask = 1; mask < 16; mask <<= 1)
            #pragma unroll
            for (int r = 0; r < 4; ++r)
                tmax[r] = fmaxf(tmax[r], __shfl_xor(tmax[r], mask));
        float alpha[4];
        #pragma unroll
        for (int r = 0; r < 4; ++r) {
            const float nM = fmaxf(runM[r], tmax[r]);
            alpha[r] = __expf(runM[r] - nM);
            runM[r] = nM;
        }
        // ---- p = exp(s - M), write wave-private LDS, update S ----
        float tileS[4] = {0.f, 0.f, 0.f, 0.f};
        #pragma unroll
        for (int ms = 0; ms < 4; ++ms)
            #pragma unroll
            for (int r = 0; r < 4; ++r) {
                const float p = __expf(s[ms][r] - runM[r]);
                tileS[r] += p;
                sP[wave][quad * 4 + r][ms * 16 + l15] = f2bf(p);
            }
        #pragma unroll
        for (int r = 0; r < 4; ++r) runS[r] = runS[r] * alpha[r] + tileS[r];
        #pragma unroll
        for (int cs = 0; cs < 8; ++cs)
            #pragma unroll
            for (int r = 0; r < 4; ++r) oacc[cs][r] *= alpha[r];
        // ---- PV: P(16n x 64m) x V(64m x 128c) ----
        #pragma unroll
        for (int ks = 0; ks < 2; ++ks) {
            const bf16x8 ap = *(const bf16x8*)&sP[wave][l15][ks * 32 + quad * 8];
            #pragma unroll
            for (int cs = 0; cs < 8; ++cs) {
                const int c = cs * 16 + l15;
                const bf16x8 bv = *(const bf16x8*)(
                    vpackT + ((size_t)(b * 128 + c) * HW + m0 + ks * 32 + quad * 8));
                oacc[cs] = __builtin_amdgcn_mfma_f32_16x16x32_bf16(ap, bv, oacc[cs], 0, 0, 0);
            }
        }
    }

    // ---- finalize: row S reduce, write partials ----
    #pragma unroll
    for (int mask = 1; mask < 16; mask <<= 1)
        #pragma unroll
        for (int r = 0; r < 4; ++r) runS[r] += __shfl_xor(runS[r], mask);
    if (l15 == 0) {
        #pragma unroll
        for (int r = 0; r < 4; ++r) {
            const int n = n0w + quad * 4 + r;
            Mpart[((size_t)b * 4 + j) * 4096 + n] = runM[r];
            Spart[((size_t)b * 4 + j) * 4096 + n] = runS[r];
        }
    }
    #pragma unroll
    for (int cs = 0; cs < 8; ++cs)
        #pragma unroll
        for (int r = 0; r < 4; ++r) {
            const int n = n0w + quad * 4 + r;
            opart[(((size_t)b * 4 + j) * 4096 + n) * 128 + cs * 16 + l15] =
                f2bf(oacc[cs][r]);
        }
}

// ---------------------------------------------------------------------------
// Combine 4 m-split partials, normalize, fuse gamma2*O + c2 -> o2 (fp32 [c][n]).
// ---------------------------------------------------------------------------
__global__ __launch_bounds__(256) void attn_combine(
    const ushort* __restrict__ opart, const float* __restrict__ Mpart,
    const float* __restrict__ Spart, const float* __restrict__ c2g,
    const float* __restrict__ gamma2, float* __restrict__ o2)
{
    const int b = blockIdx.y, n0 = blockIdx.x * 32, tid = threadIdx.x;
    __shared__ float sO[128][33];
    __shared__ float sWj[4][32];
    if (tid < 32) {
        const int n = n0 + tid;
        float Mj[4], Sj[4];
        #pragma unroll
        for (int j = 0; j < 4; ++j) {
            Mj[j] = Mpart[((size_t)b * 4 + j) * 4096 + n];
            Sj[j] = Spart[((size_t)b * 4 + j) * 4096 + n];
        }
        float M = fmaxf(fmaxf(Mj[0], Mj[1]), fmaxf(Mj[2], Mj[3]));
        float e[4], St = 0.f;
        #pragma unroll
        for (int j = 0; j < 4; ++j) { e[j] = __expf(Mj[j] - M); St += Sj[j] * e[j]; }
        const float inv = 1.0f / St;
        #pragma unroll
        for (int j = 0; j < 4; ++j) sWj[j][tid] = e[j] * inv;
    }
    __syncthreads();
    #pragma unroll
    for (int e = 0; e < 16; ++e) {
        const int idx = tid + e * 256;
        const int n = idx >> 7, c = idx & 127;
        float s = 0.f;
        #pragma unroll
        for (int j = 0; j < 4; ++j)
            s += bf2f(opart[(((size_t)b * 4 + j) * 4096 + n0 + n) * 128 + c]) * sWj[j][n];
        sO[c][n] = s;
    }
    __syncthreads();
    const float g2 = gamma2[0];
    #pragma unroll
    for (int e = 0; e < 16; ++e) {
        const int idx = tid + e * 256;
        const int c = idx >> 5, n = idx & 31;
        const size_t a = (size_t)(b * 128 + c) * HW + n0 + n;
        o2[a] = fmaf(g2, sO[c][n], c2g[a]);
    }
}

// ---------------------------------------------------------------------------
__global__ __launch_bounds__(256) void pool_kernel(
    const float* __restrict__ xp, float* __restrict__ pool)
{
    const int c = blockIdx.x, b = blockIdx.y, tid = threadIdx.x;
    const float4* row = (const float4*)(xp + (size_t)(b * 256 + c) * HW);
    float s = 0.f;
    #pragma unroll 4
    for (int i = tid; i < 1024; i += 256) {
        const float4 t = row[i];
        s += t.x + t.y + t.z + t.w;
    }
    __shared__ float red[256];
    red[tid] = s; __syncthreads();
    for (int st = 128; st > 0; st >>= 1) {
        if (tid < st) red[tid] += red[tid + st];
        __syncthreads();
    }
    if (tid == 0) pool[b * 256 + c] = red[0] * (1.0f / 4096.0f);
}

// ---------------------------------------------------------------------------
__global__ __launch_bounds__(256) void c3_fbias_kernel(
    const float* __restrict__ pool, const float* __restrict__ c3w,
    const float* __restrict__ c3b, const float* __restrict__ bng,
    const float* __restrict__ bnb, const float* __restrict__ bnm,
    const float* __restrict__ bnv, const float* __restrict__ al,
    const float* __restrict__ fw, float* __restrict__ fbias)
{
    const int b = blockIdx.x, tid = threadIdx.x;
    __shared__ float sp[256];
    __shared__ float sc3[128];
    sp[tid] = pool[b * 256 + tid];
    __syncthreads();
    if (tid < 128) {
        float acc = c3b[tid];
        for (int ci = 0; ci < 256; ++ci) acc = fmaf(c3w[tid * 256 + ci], sp[ci], acc);
        const float scale = bng[tid] * rsqrtf(bnv[tid] + EPSV);
        float t = (acc - bnm[tid]) * scale + bnb[tid];
        const float a = al[0];
        sc3[tid] = t >= 0.f ? t : a * t;
    }
    __syncthreads();
    float f = 0.f;
    for (int j = 0; j < 128; ++j) f = fmaf(fw[tid * 384 + 256 + j], sc3[j], f);
    fbias[b * 256 + tid] = f;
}

// ---------------------------------------------------------------------------
extern "C" void kernel_launch(void* const* d_in, const int* in_sizes, int n_in,
                              void* d_out, int out_size, void* d_ws, size_t ws_size,
                              hipStream_t stream)
{
    const float* x     = (const float*)d_in[0];
    const float* dc_w  = (const float*)d_in[1];
    const float* dc_b  = (const float*)d_in[2];
    const float* dc_g  = (const float*)d_in[3];
    const float* dc_bt = (const float*)d_in[4];
    const float* dc_m  = (const float*)d_in[5];
    const float* dc_v  = (const float*)d_in[6];
    const float* dc_a  = (const float*)d_in[7];
    const float* c1_w  = (const float*)d_in[8];
    const float* c1_b  = (const float*)d_in[9];
    const float* c1_g  = (const float*)d_in[10];
    const float* c1_bt = (const float*)d_in[11];
    const float* c1_m  = (const float*)d_in[12];
    const float* c1_v  = (const float*)d_in[13];
    const float* c1_a  = (const float*)d_in[14];
    const float* c2_w  = (const float*)d_in[15];
    const float* c2_b  = (const float*)d_in[16];
    const float* c2_g  = (const float*)d_in[17];
    const float* c2_bt = (const float*)d_in[18];
    const float* c2_m  = (const float*)d_in[19];
    const float* c2_v  = (const float*)d_in[20];
    const float* c2_a  = (const float*)d_in[21];
    const float* q_w   = (const float*)d_in[22];
    const float* q_b   = (const float*)d_in[23];
    const float* k_w   = (const float*)d_in[24];
    const float* k_b   = (const float*)d_in[25];
    const float* v_w   = (const float*)d_in[26];
    const float* v_b   = (const float*)d_in[27];
    const float* gamma2= (const float*)d_in[28];
    const float* c3_w  = (const float*)d_in[29];
    const float* c3_b  = (const float*)d_in[30];
    const float* c3_g  = (const float*)d_in[31];
    const float* c3_bt = (const float*)d_in[32];
    const float* c3_m  = (const float*)d_in[33];
    const float* c3_v  = (const float*)d_in[34];
    const float* c3_a  = (const float*)d_in[35];
    const float* f_w   = (const float*)d_in[36];
    const float* f_b   = (const float*)d_in[37];
    const float* f_g   = (const float*)d_in[38];
    const float* f_bt  = (const float*)d_in[39];
    const float* f_m   = (const float*)d_in[40];
    const float* f_v   = (const float*)d_in[41];
    const float* f_a   = (const float*)d_in[42];

    float* ws   = (float*)d_ws;
    float* xp   = ws;                     // [4,256,4096] fp32
    float* c1b  = xp   + 4194304;         // [4,128,4096] fp32
    float* c2b  = c1b  + 2097152;
    float* o2b  = c2b  + 2097152;
    float* poolb= o2b  + 2097152;         // 1024
    float* fbb  = poolb+ 1024;            // 1024
    ushort* qpk  = (ushort*)(fbb + 1024); // [4,4096,32] bf16
    ushort* kpk  = qpk + 4 * 4096 * 32;
    ushort* vbh  = kpk + 4 * 4096 * 32;   // [4,128,4096] bf16
    ushort* xbf  = vbh + 4 * 128 * 4096;  // [4,4096,512] bf16 (dead after dc; reused as opart)
    ushort* xpbf = xbf + (size_t)4 * 4096 * 512;   // [4,4096,256] bf16
    ushort* wdcp = xpbf + (size_t)4 * 4096 * 256;  // [9,16,256,32] bf16
    ushort* wc2p = wdcp + 9 * 16 * 256 * 32;       // [9,8,128,32]  bf16
    float* Mpart = (float*)(wc2p + 9 * 8 * 128 * 32);  // [4,4,4096]
    float* Spart = Mpart + 4 * 4 * 4096;
    ushort* opart = xbf;                  // [4,4,4096,128] bf16 == 8,388,608 elems

    // 0a. pack weights
    pack_w3x3<512, 256><<<dim3((9*16*256*32 + 255)/256), 256, 0, stream>>>(dc_w, wdcp);
    pack_w3x3<256, 128><<<dim3((9*8*128*32 + 255)/256), 256, 0, stream>>>(c2_w, wc2p);
    // 0b. x -> channel-last bf16
    to_chlast_bf16<512><<<dim3(64, 8, 4), 256, 0, stream>>>(x, xbf);
    // 1. down_conv 3x3 512->256 (MFMA)
    conv3x3_mfma<512, 256, 64, 1><<<dim3(16, 4, 4), 256, 0, stream>>>(
        xbf, wdcp, dc_b, dc_g, dc_bt, dc_m, dc_v, dc_a, xp);
    // 1b. xp -> channel-last bf16 for c2
    to_chlast_bf16<256><<<dim3(64, 4, 4), 256, 0, stream>>>(xp, xpbf);
    // 2. branch1 1x1
    conv1x1_kernel<256, true, false, false><<<dim3(64, 2, 4), 256, 0, stream>>>(
        xp, nullptr, c1_w, 256, 128, c1_b, c1_g, c1_bt, c1_m, c1_v, c1_a, nullptr, c1b);
    // 3. branch2 dilated 3x3 (MFMA)
    conv3x3_mfma<256, 128, 32, 2><<<dim3(16, 4, 4), 256, 0, stream>>>(
        xpbf, wc2p, c2_b, c2_g, c2_bt, c2_m, c2_v, c2_a, c2b);
    // 4. q,k
    qk_kernel<<<dim3(64, 4), 256, 0, stream>>>(c2b, q_w, q_b, k_w, k_b, qpk, kpk);
    // 5. v -> bf16 [c][m]
    conv1x1_kernel<128, false, false, true><<<dim3(64, 2, 4), 256, 0, stream>>>(
        c2b, nullptr, v_w, 128, 128, v_b, nullptr, nullptr, nullptr, nullptr,
        nullptr, nullptr, vbh);
    // 6. flash attention (one-pass, wave-private, m-split 4) + combine
    attn_flash<<<dim3(64, 4, 4), 256, 0, stream>>>(qpk, kpk, vbh, opart, Mpart, Spart);
    attn_combine<<<dim3(128, 4), 256, 0, stream>>>(opart, Mpart, Spart, c2b, gamma2, o2b);
    // 7. pool
    pool_kernel<<<dim3(256, 4), 256, 0, stream>>>(xp, poolb);
    // 8. c3 -> fuse bias
    c3_fbias_kernel<<<dim3(4), 256, 0, stream>>>(
        poolb, c3_w, c3_b, c3_g, c3_bt, c3_m, c3_v, c3_a, f_w, fbb);
    // 9. fuse conv 384->256 -> out
    conv1x1_kernel<256, true, true, false><<<dim3(64, 4, 4), 256, 0, stream>>>(
        c1b, o2b, f_w, 384, 256, f_b, f_g, f_bt, f_m, f_v, f_a, fbb, (float*)d_out);
}

// Round 6
// 548.619 us; speedup vs baseline: 3.1564x; 1.0422x over previous
//
#include <hip/hip_runtime.h>
#include <hip/hip_bf16.h>
#include <math.h>

#define HW 4096
#define EPSV 1e-5f

typedef unsigned short ushort;
typedef __attribute__((ext_vector_type(8))) short bf16x8;
typedef __attribute__((ext_vector_type(4))) float f32x4;

__device__ inline ushort f2bf(float f) {
    __hip_bfloat16 h = __float2bfloat16(f);
    return *reinterpret_cast<ushort*>(&h);
}
__device__ inline float bf2f(ushort u) {
    unsigned int v = ((unsigned int)u) << 16;
    return __uint_as_float(v);
}

// ---------------------------------------------------------------------------
// fp32 [b][C][4096] -> bf16 channel-last [b][4096][C], LDS transpose.
// ---------------------------------------------------------------------------
template<int C>
__global__ __launch_bounds__(256) void to_chlast_bf16(
    const float* __restrict__ src, ushort* __restrict__ dst)
{
    const int b = blockIdx.z, c0 = blockIdx.y * 64, p0 = blockIdx.x * 64;
    const int tid = threadIdx.x;
    __shared__ float sT[64][65];
    for (int i = tid; i < 4096; i += 256) {
        const int ch = i >> 6, px = i & 63;
        sT[ch][px] = src[(size_t)(b * C + c0 + ch) * HW + p0 + px];
    }
    __syncthreads();
    const int px = tid >> 2, seg = tid & 3;
    ushort tmp[16];
    #pragma unroll
    for (int j = 0; j < 16; ++j) tmp[j] = f2bf(sT[seg * 16 + j][px]);
    ushort* d = dst + (size_t)(b * HW + p0 + px) * C + c0 + seg * 16;
    *(uint4*)d = *(uint4*)&tmp[0];
    *(uint4*)(d + 8) = *(uint4*)&tmp[8];
}

// ---------------------------------------------------------------------------
// Pack 3x3 weights [co][ci][3][3] fp32 -> [tap][ci/32][co][ci32] bf16.
// ---------------------------------------------------------------------------
template<int CIN, int COUT>
__global__ __launch_bounds__(256) void pack_w3x3(
    const float* __restrict__ w, ushort* __restrict__ wpk)
{
    const int idx = blockIdx.x * 256 + threadIdx.x;
    constexpr int total = 9 * (CIN / 32) * COUT * 32;
    if (idx >= total) return;
    const int ci_in = idx & 31;
    int rest = idx >> 5;
    const int co = rest % COUT; rest /= COUT;
    const int cc = rest % (CIN / 32);
    const int tap = rest / (CIN / 32);
    wpk[idx] = f2bf(w[((size_t)co * CIN + cc * 32 + ci_in) * 9 + tap]);
}

// ---------------------------------------------------------------------------
// Pack 1x1 weights [co][stride] fp32 -> [co][K] bf16 (first K columns).
// ---------------------------------------------------------------------------
__global__ __launch_bounds__(256) void pack_w1x1(
    const float* __restrict__ w, ushort* __restrict__ o,
    int K, int stride, int total)
{
    const int idx = blockIdx.x * 256 + threadIdx.x;
    if (idx >= total) return;
    const int co = idx / K, k = idx - co * K;
    o[idx] = f2bf(w[(size_t)co * stride + k]);
}

// ---------------------------------------------------------------------------
// MFMA implicit-GEMM 3x3 conv + BN + PReLU.
// ---------------------------------------------------------------------------
template<int CIN, int COUT, int COTILE, int DIL>
__global__ __launch_bounds__(256) void conv3x3_mfma(
    const ushort* __restrict__ xin,   // [b][64][64][CIN] bf16
    const ushort* __restrict__ wpk,   // [9][CIN/32][COUT][32] bf16
    const float* __restrict__ bias, const float* __restrict__ bng,
    const float* __restrict__ bnb, const float* __restrict__ bnm,
    const float* __restrict__ bnv, const float* __restrict__ al,
    float* __restrict__ out)
{
    constexpr int HR = 4 + 2 * DIL;
    constexpr int NC = 64 + 2 * DIL;
    constexpr int MT = COTILE / 16;

    const int tid = threadIdx.x;
    const int wave = tid >> 6, lane = tid & 63;
    const int l15 = lane & 15, quad = lane >> 4;
    const int b = blockIdx.z;
    const int co0 = blockIdx.y * COTILE;
    const int h0 = blockIdx.x * 4;

    __shared__ __align__(16) ushort sA[HR * NC * 32];
    __shared__ __align__(16) ushort sB[9 * COTILE * 32];
    __shared__ float sScale[COTILE], sShift[COTILE];

    if (tid < COTILE) {
        const int co = co0 + tid;
        const float sc = bng[co] * rsqrtf(bnv[co] + EPSV);
        sScale[tid] = sc;
        sShift[tid] = (bias[co] - bnm[co]) * sc + bnb[co];
    }

    f32x4 acc[MT][4];
    #pragma unroll
    for (int mt = 0; mt < MT; ++mt)
        #pragma unroll
        for (int nt = 0; nt < 4; ++nt) acc[mt][nt] = (f32x4){0.f, 0.f, 0.f, 0.f};

    #pragma unroll 1
    for (int cc = 0; cc < CIN / 32; ++cc) {
        __syncthreads();
        constexpr int NA = HR * NC * 4;
        for (int i = tid; i < NA; i += 256) {
            const int p = i >> 2, seg = i & 3;
            const int r = p / NC, c = p - r * NC;
            const int grow = h0 - DIL + r, gcol = c - DIL;
            uint4 val = {0u, 0u, 0u, 0u};
            if (grow >= 0 && grow < 64 && gcol >= 0 && gcol < 64)
                val = *(const uint4*)&xin[((size_t)(b * 64 + grow) * 64 + gcol) * CIN
                                          + cc * 32 + seg * 8];
            *(uint4*)&sA[p * 32 + seg * 8] = val;
        }
        constexpr int NB = 9 * COTILE * 4;
        for (int i = tid; i < NB; i += 256) {
            const int tap = i / (COTILE * 4);
            const int rem = i - tap * (COTILE * 4);
            const int co = rem >> 2, seg = rem & 3;
            *(uint4*)&sB[(tap * COTILE + co) * 32 + seg * 8] =
                *(const uint4*)&wpk[((size_t)(tap * (CIN / 32) + cc) * COUT
                                     + co0 + co) * 32 + seg * 8];
        }
        __syncthreads();

        #pragma unroll
        for (int ty = 0; ty < 3; ++ty)
            #pragma unroll
            for (int tx = 0; tx < 3; ++tx) {
                const int tap = ty * 3 + tx;
                bf16x8 aw[MT];
                #pragma unroll
                for (int mt = 0; mt < MT; ++mt)
                    aw[mt] = *(const bf16x8*)&sB[(tap * COTILE + mt * 16 + l15) * 32 + quad * 8];
                const int rl = wave + ty * DIL;
                #pragma unroll
                for (int nt = 0; nt < 4; ++nt) {
                    const int cl = nt * 16 + l15 + tx * DIL;
                    const bf16x8 bp = *(const bf16x8*)&sA[(rl * NC + cl) * 32 + quad * 8];
                    #pragma unroll
                    for (int mt = 0; mt < MT; ++mt)
                        acc[mt][nt] = __builtin_amdgcn_mfma_f32_16x16x32_bf16(
                            aw[mt], bp, acc[mt][nt], 0, 0, 0);
                }
            }
    }

    const float a = al[0];
    #pragma unroll
    for (int mt = 0; mt < MT; ++mt)
        #pragma unroll
        for (int rr = 0; rr < 4; ++rr) {
            const int col = mt * 16 + quad * 4 + rr;
            const float sc = sScale[col], sh = sShift[col];
            const int co = co0 + col;
            #pragma unroll
            for (int nt = 0; nt < 4; ++nt) {
                float t = acc[mt][nt][rr] * sc + sh;
                t = t >= 0.f ? t : a * t;
                out[((size_t)(b * COUT + co) * 64 + h0 + wave) * 64 + nt * 16 + l15] = t;
            }
        }
}

// ---------------------------------------------------------------------------
// MFMA 1x1 conv on channel-last bf16 input, frags straight from global.
// Block = 4 waves; wave = 64co x 32pix.  Grid: (16384/128, COUT/64).
// OMODE 0: fp32 channel-first out + BN/PReLU (+ebias).
// OMODE 1: bf16 channel-last out at [pix][ostride] col ocol (+BN/PReLU).
// ---------------------------------------------------------------------------
template<int CIN, int COUT, bool BNACT, int OMODE>
__global__ __launch_bounds__(256) void gemm1x1_cl(
    const ushort* __restrict__ xin,   // [16384][CIN] bf16
    const ushort* __restrict__ wbf,   // [COUT][CIN] bf16
    const float* __restrict__ bias, const float* __restrict__ bng,
    const float* __restrict__ bnb, const float* __restrict__ bnm,
    const float* __restrict__ bnv, const float* __restrict__ al,
    const float* __restrict__ ebias, void* __restrict__ outv,
    int ostride, int ocol)
{
    const int tid = threadIdx.x;
    const int wave = tid >> 6, lane = tid & 63;
    const int l15 = lane & 15, quad = lane >> 4;
    const int pix0 = blockIdx.x * 128 + wave * 32;
    const int co0 = blockIdx.y * 64;

    f32x4 acc[4][2];
    #pragma unroll
    for (int mt = 0; mt < 4; ++mt)
        #pragma unroll
        for (int nt = 0; nt < 2; ++nt) acc[mt][nt] = (f32x4){0.f, 0.f, 0.f, 0.f};

    #pragma unroll 2
    for (int cc = 0; cc < CIN / 32; ++cc) {
        bf16x8 aw[4], bp[2];
        #pragma unroll
        for (int mt = 0; mt < 4; ++mt)
            aw[mt] = *(const bf16x8*)&wbf[(size_t)(co0 + mt * 16 + l15) * CIN + cc * 32 + quad * 8];
        #pragma unroll
        for (int nt = 0; nt < 2; ++nt)
            bp[nt] = *(const bf16x8*)&xin[(size_t)(pix0 + nt * 16 + l15) * CIN + cc * 32 + quad * 8];
        #pragma unroll
        for (int mt = 0; mt < 4; ++mt)
            #pragma unroll
            for (int nt = 0; nt < 2; ++nt)
                acc[mt][nt] = __builtin_amdgcn_mfma_f32_16x16x32_bf16(
                    aw[mt], bp[nt], acc[mt][nt], 0, 0, 0);
    }

    const int bI = pix0 >> 12;
    const float a = BNACT ? al[0] : 0.f;

    if (OMODE == 0) {
        float* out = (float*)outv;
        #pragma unroll
        for (int mt = 0; mt < 4; ++mt)
            #pragma unroll
            for (int r = 0; r < 4; ++r) {
                const int co = co0 + mt * 16 + quad * 4 + r;
                float bb = bias[co];
                if (ebias) bb += ebias[bI * COUT + co];
                float scale = 1.f, shift = bb;
                if (BNACT) {
                    scale = bng[co] * rsqrtf(bnv[co] + EPSV);
                    shift = bb * scale + (bnb[co] - bnm[co] * scale);
                }
                #pragma unroll
                for (int nt = 0; nt < 2; ++nt) {
                    float t = acc[mt][nt][r] * scale + shift;
                    if (BNACT) t = t >= 0.f ? t : a * t;
                    out[((size_t)(bI * COUT + co)) * HW + (pix0 & 4095) + nt * 16 + l15] = t;
                }
            }
    } else {
        __shared__ ushort sT[4][32][68];
        #pragma unroll
        for (int mt = 0; mt < 4; ++mt)
            #pragma unroll
            for (int r = 0; r < 4; ++r) {
                const int co = co0 + mt * 16 + quad * 4 + r;
                float bb = bias[co];
                float scale = 1.f, shift = bb;
                if (BNACT) {
                    scale = bng[co] * rsqrtf(bnv[co] + EPSV);
                    shift = bb * scale + (bnb[co] - bnm[co] * scale);
                }
                #pragma unroll
                for (int nt = 0; nt < 2; ++nt) {
                    float t = acc[mt][nt][r] * scale + shift;
                    if (BNACT) t = t >= 0.f ? t : a * t;
                    sT[wave][nt * 16 + l15][mt * 16 + quad * 4 + r] = f2bf(t);
                }
            }
        __syncthreads();
        const int p = lane >> 1, half = lane & 1;
        ushort* out = (ushort*)outv;
        #pragma unroll
        for (int seg = 0; seg < 4; ++seg) {
            uint2 a0 = *(uint2*)&sT[wave][p][half * 32 + seg * 8];
            uint2 a1 = *(uint2*)&sT[wave][p][half * 32 + seg * 8 + 4];
            uint4 vv = {a0.x, a0.y, a1.x, a1.y};
            *(uint4*)&out[(size_t)(pix0 + p) * ostride + ocol + co0 + half * 32 + seg * 8] = vv;
        }
    }
}

// ---------------------------------------------------------------------------
// Generic fp32 1x1 conv (kept for v).  OUTBF16: write bf16.
// ---------------------------------------------------------------------------
template<int CIN, bool BNACT, bool OUTBF16>
__global__ __launch_bounds__(256) void conv1x1_kernel(
    const float* __restrict__ in0,
    const float* __restrict__ wgt, int wstride, int COUT,
    const float* __restrict__ bias, const float* __restrict__ al,
    void* __restrict__ outv)
{
    const int tid = threadIdx.x;
    const int b = blockIdx.z, co0 = blockIdx.y * 64, p0 = blockIdx.x * 64;
    const int cg = tid >> 4, pg = tid & 15;
    const int c0l = cg * 4, w0 = pg * 4;

    __shared__ __align__(16) float sIn[16 * 64];
    __shared__ __align__(16) float sW[16 * 68];

    float acc[4][4] = {};

    for (int cc = 0; cc < CIN; cc += 16) {
        {
            int i = tid;
            #pragma unroll
            for (int it = 0; it < 4; ++it, i += 256) {
                const int px = i & 63, ci = i >> 6;
                sIn[ci * 64 + px] = in0[(size_t)(b * CIN + cc + ci) * HW + p0 + px];
            }
            i = tid;
            #pragma unroll
            for (int it = 0; it < 4; ++it, i += 256) {
                const int ci = i & 15, co = i >> 4;
                sW[ci * 68 + co] = wgt[(co0 + co) * wstride + cc + ci];
            }
        }
        __syncthreads();
        #pragma unroll
        for (int ci = 0; ci < 16; ++ci) {
            const float4 iv = *(const float4*)&sIn[ci * 64 + w0];
            const float4 wv = *(const float4*)&sW[ci * 68 + c0l];
            const float ia[4] = {iv.x, iv.y, iv.z, iv.w};
            const float wa[4] = {wv.x, wv.y, wv.z, wv.w};
            #pragma unroll
            for (int i2 = 0; i2 < 4; ++i2)
                #pragma unroll
                for (int j = 0; j < 4; ++j)
                    acc[i2][j] = fmaf(wa[i2], ia[j], acc[i2][j]);
        }
        __syncthreads();
    }

    const float a = BNACT ? al[0] : 0.f;
    #pragma unroll
    for (int i2 = 0; i2 < 4; ++i2) {
        const int co = co0 + c0l + i2;
        const float shift = bias[co];
        float r[4];
        #pragma unroll
        for (int j = 0; j < 4; ++j) {
            float t = acc[i2][j] + shift;
            r[j] = (BNACT && t < 0.f) ? a * t : t;
        }
        const size_t base = (size_t)(b * COUT + co) * HW + p0 + w0;
        if (OUTBF16) {
            ushort* out = (ushort*)outv;
            #pragma unroll
            for (int j = 0; j < 4; ++j) out[base + j] = f2bf(r[j]);
        } else {
            float* out = (float*)outv;
            *(float4*)&out[base] = make_float4(r[0], r[1], r[2], r[3]);
        }
    }
}

// ---------------------------------------------------------------------------
// q & k 1x1 convs (128 -> 16 each) -> packed bf16 [b][4096][32] (16 ch + 16 zero)
// ---------------------------------------------------------------------------
__global__ __launch_bounds__(256) void qk_kernel(
    const float* __restrict__ c2g, const float* __restrict__ qw,
    const float* __restrict__ qb2, const float* __restrict__ kw,
    const float* __restrict__ kb2, ushort* __restrict__ qpack,
    ushort* __restrict__ kpack)
{
    const int b = blockIdx.y, p0 = blockIdx.x * 64, tid = threadIdx.x;
    __shared__ float sC[128][64];
    __shared__ float sWq[16][128];
    __shared__ float sWk[16][128];
    for (int i = tid; i < 8192; i += 256) {
        const int px = i & 63, ci = i >> 6;
        sC[ci][px] = c2g[(size_t)(b * 128 + ci) * HW + p0 + px];
    }
    for (int i = tid; i < 2048; i += 256) {
        const int ci = i & 127, co = i >> 7;
        sWq[co][ci] = qw[co * 128 + ci];
        sWk[co][ci] = kw[co * 128 + ci];
    }
    __syncthreads();
    const int px = tid & 63, grp = tid >> 6;
    const int co0 = (grp & 1) * 8;
    const bool isK = grp >= 2;
    const float* sWp = isK ? &sWk[0][0] : &sWq[0][0];
    float acc[8] = {};
    for (int ci = 0; ci < 128; ++ci) {
        const float xv = sC[ci][px];
        #pragma unroll
        for (int j = 0; j < 8; ++j)
            acc[j] = fmaf(sWp[(co0 + j) * 128 + ci], xv, acc[j]);
    }
    const float* bsrc = isK ? kb2 : qb2;
    ushort* osrc = isK ? kpack : qpack;
    const size_t base = (size_t)(b * 4096 + p0 + px) * 32;
    #pragma unroll
    for (int j = 0; j < 8; ++j) {
        osrc[base + co0 + j] = f2bf(acc[j] + bsrc[co0 + j]);
        osrc[base + 16 + co0 + j] = 0;
    }
}

// ---------------------------------------------------------------------------
// Two-pass flash attention, operand-swapped (lane owns ONE query column).
// NO cross-lane ops inside either loop; no alpha rescales.
// Block = 4 waves; wave = 16 queries.  Grid: (64 nblk, 4 msplit, 4 batch).
// ---------------------------------------------------------------------------
__global__ __launch_bounds__(256) void attn_flash(
    const ushort* __restrict__ qpack,
    const ushort* __restrict__ kpack,
    const ushort* __restrict__ vpackT,
    ushort* __restrict__ opart,       // [b][4j][4096n][128c] bf16
    float* __restrict__ Mpart,        // [b][4j][4096n]
    float* __restrict__ Spart)
{
    const int tid = threadIdx.x;
    const int wave = tid >> 6, lane = tid & 63;
    const int l15 = lane & 15, quad = lane >> 4;
    const int b = blockIdx.z, j = blockIdx.y;
    const int n0w = blockIdx.x * 64 + wave * 16;
    const int m_begin = j * 1024;

    __shared__ __align__(16) ushort sP[4][16][72];   // wave-private [n][64m]+pad

    // B-frag: Q (cols = n), lane owns query n = l15
    const bf16x8 bq = *(const bf16x8*)(qpack + ((size_t)(b * 4096 + n0w + l15) * 32 + quad * 8));
    const f32x4 z = {0.f, 0.f, 0.f, 0.f};

    // ---- pass 1: exact row max, in-register only ----
    float runM = -3e30f;
    #pragma unroll 4
    for (int t = 0; t < 16; ++t) {
        const int m0 = m_begin + t * 64;
        #pragma unroll
        for (int ms = 0; ms < 4; ++ms) {
            const bf16x8 ak = *(const bf16x8*)(
                kpack + ((size_t)(b * 4096 + m0 + ms * 16 + l15) * 32 + quad * 8));
            const f32x4 s = __builtin_amdgcn_mfma_f32_16x16x32_bf16(ak, bq, z, 0, 0, 0);
            runM = fmaxf(runM, fmaxf(fmaxf(s[0], s[1]), fmaxf(s[2], s[3])));
        }
    }
    runM = fmaxf(runM, __shfl_xor(runM, 16));
    runM = fmaxf(runM, __shfl_xor(runM, 32));
    const float Ms = runM * 1.44269504f;     // exp2 domain

    // ---- pass 2: p = exp(s - M), PV accumulate ----
    float runS = 0.f;
    f32x4 oacc[8];
    #pragma unroll
    for (int cs = 0; cs < 8; ++cs) oacc[cs] = (f32x4){0.f, 0.f, 0.f, 0.f};

    #pragma unroll 2
    for (int t = 0; t < 16; ++t) {
        const int m0 = m_begin + t * 64;
        f32x4 s[4];
        #pragma unroll
        for (int ms = 0; ms < 4; ++ms) {
            const bf16x8 ak = *(const bf16x8*)(
                kpack + ((size_t)(b * 4096 + m0 + ms * 16 + l15) * 32 + quad * 8));
            s[ms] = __builtin_amdgcn_mfma_f32_16x16x32_bf16(ak, bq, z, 0, 0, 0);
        }
        #pragma unroll
        for (int ms = 0; ms < 4; ++ms) {
            float p[4];
            #pragma unroll
            for (int r = 0; r < 4; ++r) {
                p[r] = __builtin_amdgcn_exp2f(fmaf(s[ms][r], 1.44269504f, -Ms));
                runS += p[r];
            }
            ushort4 u;
            u.x = f2bf(p[0]); u.y = f2bf(p[1]); u.z = f2bf(p[2]); u.w = f2bf(p[3]);
            *(uint2*)&sP[wave][l15][ms * 16 + quad * 4] = *(uint2*)&u;
        }
        __builtin_amdgcn_s_waitcnt(0);   // in-wave LDS ordering
        #pragma unroll
        for (int ks = 0; ks < 2; ++ks) {
            const bf16x8 ap = *(const bf16x8*)&sP[wave][l15][ks * 32 + quad * 8];
            #pragma unroll
            for (int cs = 0; cs < 8; ++cs) {
                const bf16x8 bv = *(const bf16x8*)(
                    vpackT + ((size_t)(b * 128 + cs * 16 + l15) * HW + m0 + ks * 32 + quad * 8));
                oacc[cs] = __builtin_amdgcn_mfma_f32_16x16x32_bf16(ap, bv, oacc[cs], 0, 0, 0);
            }
        }
    }

    runS += __shfl_xor(runS, 16);
    runS += __shfl_xor(runS, 32);
    if (lane < 16) {
        Mpart[((size_t)b * 4 + j) * 4096 + n0w + l15] = runM;
        Spart[((size_t)b * 4 + j) * 4096 + n0w + l15] = runS;
    }
    #pragma unroll
    for (int cs = 0; cs < 8; ++cs)
        #pragma unroll
        for (int r = 0; r < 4; ++r) {
            const int n = n0w + quad * 4 + r;
            opart[(((size_t)b * 4 + j) * 4096 + n) * 128 + cs * 16 + l15] = f2bf(oacc[cs][r]);
        }
}

// ---------------------------------------------------------------------------
// Combine 4 m-split partials, normalize, fuse gamma2*O + c2 -> catb[:,128:256]
// (bf16 channel-last).
// ---------------------------------------------------------------------------
__global__ __launch_bounds__(256) void attn_combine(
    const ushort* __restrict__ opart, const float* __restrict__ Mpart,
    const float* __restrict__ Spart, const float* __restrict__ c2g,
    const float* __restrict__ gamma2, ushort* __restrict__ catb)
{
    const int b = blockIdx.y, n0 = blockIdx.x * 32, tid = threadIdx.x;
    __shared__ float sC2[128][33];
    __shared__ float sWj[4][32];
    if (tid < 32) {
        const int n = n0 + tid;
        float Mj[4], Sj[4];
        #pragma unroll
        for (int j = 0; j < 4; ++j) {
            Mj[j] = Mpart[((size_t)b * 4 + j) * 4096 + n];
            Sj[j] = Spart[((size_t)b * 4 + j) * 4096 + n];
        }
        float M = fmaxf(fmaxf(Mj[0], Mj[1]), fmaxf(Mj[2], Mj[3]));
        float e[4], St = 0.f;
        #pragma unroll
        for (int j = 0; j < 4; ++j) { e[j] = __expf(Mj[j] - M); St += Sj[j] * e[j]; }
        const float inv = 1.0f / St;
        #pragma unroll
        for (int j = 0; j < 4; ++j) sWj[j][tid] = e[j] * inv;
    }
    #pragma unroll
    for (int e = 0; e < 16; ++e) {
        const int idx = tid + e * 256;
        const int c = idx >> 5, n = idx & 31;
        sC2[c][n] = c2g[(size_t)(b * 128 + c) * HW + n0 + n];
    }
    __syncthreads();
    const float g2 = gamma2[0];
    #pragma unroll
    for (int e = 0; e < 16; ++e) {
        const int idx = tid + e * 256;
        const int n = idx >> 7, c = idx & 127;
        float s = 0.f;
        #pragma unroll
        for (int j = 0; j < 4; ++j)
            s += bf2f(opart[(((size_t)b * 4 + j) * 4096 + n0 + n) * 128 + c]) * sWj[j][n];
        catb[(size_t)(b * 4096 + n0 + n) * 256 + 128 + c] = f2bf(fmaf(g2, s, sC2[c][n]));
    }
}

// ---------------------------------------------------------------------------
__global__ __launch_bounds__(256) void pool_kernel(
    const float* __restrict__ xp, float* __restrict__ pool)
{
    const int c = blockIdx.x, b = blockIdx.y, tid = threadIdx.x;
    const float4* row = (const float4*)(xp + (size_t)(b * 256 + c) * HW);
    float s = 0.f;
    #pragma unroll 4
    for (int i = tid; i < 1024; i += 256) {
        const float4 t = row[i];
        s += t.x + t.y + t.z + t.w;
    }
    __shared__ float red[256];
    red[tid] = s; __syncthreads();
    for (int st = 128; st > 0; st >>= 1) {
        if (tid < st) red[tid] += red[tid + st];
        __syncthreads();
    }
    if (tid == 0) pool[b * 256 + c] = red[0] * (1.0f / 4096.0f);
}

// ---------------------------------------------------------------------------
__global__ __launch_bounds__(256) void c3_fbias_kernel(
    const float* __restrict__ pool, const float* __restrict__ c3w,
    const float* __restrict__ c3b, const float* __restrict__ bng,
    const float* __restrict__ bnb, const float* __restrict__ bnm,
    const float* __restrict__ bnv, const float* __restrict__ al,
    const float* __restrict__ fw, float* __restrict__ fbias)
{
    const int b = blockIdx.x, tid = threadIdx.x;
    __shared__ float sp[256];
    __shared__ float sc3[128];
    sp[tid] = pool[b * 256 + tid];
    __syncthreads();
    if (tid < 128) {
        float acc = c3b[tid];
        for (int ci = 0; ci < 256; ++ci) acc = fmaf(c3w[tid * 256 + ci], sp[ci], acc);
        const float scale = bng[tid] * rsqrtf(bnv[tid] + EPSV);
        float t = (acc - bnm[tid]) * scale + bnb[tid];
        const float a = al[0];
        sc3[tid] = t >= 0.f ? t : a * t;
    }
    __syncthreads();
    float f = 0.f;
    for (int j = 0; j < 128; ++j) f = fmaf(fw[tid * 384 + 256 + j], sc3[j], f);
    fbias[b * 256 + tid] = f;
}

// ---------------------------------------------------------------------------
extern "C" void kernel_launch(void* const* d_in, const int* in_sizes, int n_in,
                              void* d_out, int out_size, void* d_ws, size_t ws_size,
                              hipStream_t stream)
{
    const float* x     = (const float*)d_in[0];
    const float* dc_w  = (const float*)d_in[1];
    const float* dc_b  = (const float*)d_in[2];
    const float* dc_g  = (const float*)d_in[3];
    const float* dc_bt = (const float*)d_in[4];
    const float* dc_m  = (const float*)d_in[5];
    const float* dc_v  = (const float*)d_in[6];
    const float* dc_a  = (const float*)d_in[7];
    const float* c1_w  = (const float*)d_in[8];
    const float* c1_b  = (const float*)d_in[9];
    const float* c1_g  = (const float*)d_in[10];
    const float* c1_bt = (const float*)d_in[11];
    const float* c1_m  = (const float*)d_in[12];
    const float* c1_v  = (const float*)d_in[13];
    const float* c1_a  = (const float*)d_in[14];
    const float* c2_w  = (const float*)d_in[15];
    const float* c2_b  = (const float*)d_in[16];
    const float* c2_g  = (const float*)d_in[17];
    const float* c2_bt = (const float*)d_in[18];
    const float* c2_m  = (const float*)d_in[19];
    const float* c2_v  = (const float*)d_in[20];
    const float* c2_a  = (const float*)d_in[21];
    const float* q_w   = (const float*)d_in[22];
    const float* q_b   = (const float*)d_in[23];
    const float* k_w   = (const float*)d_in[24];
    const float* k_b   = (const float*)d_in[25];
    const float* v_w   = (const float*)d_in[26];
    const float* v_b   = (const float*)d_in[27];
    const float* gamma2= (const float*)d_in[28];
    const float* c3_w  = (const float*)d_in[29];
    const float* c3_b  = (const float*)d_in[30];
    const float* c3_g  = (const float*)d_in[31];
    const float* c3_bt = (const float*)d_in[32];
    const float* c3_m  = (const float*)d_in[33];
    const float* c3_v  = (const float*)d_in[34];
    const float* c3_a  = (const float*)d_in[35];
    const float* f_w   = (const float*)d_in[36];
    const float* f_b   = (const float*)d_in[37];
    const float* f_g   = (const float*)d_in[38];
    const float* f_bt  = (const float*)d_in[39];
    const float* f_m   = (const float*)d_in[40];
    const float* f_v   = (const float*)d_in[41];
    const float* f_a   = (const float*)d_in[42];

    float* ws    = (float*)d_ws;
    float* xp    = ws;                         // [4,256,4096] fp32
    float* c2b   = xp + 4194304;               // [4,128,4096] fp32
    ushort* catb = (ushort*)(c2b + 2097152);   // [4,4096,256] bf16
    float* poolb = (float*)(catb + 8388608);   // 1024
    float* fbb   = poolb + 1024;               // 1024
    ushort* qpk  = (ushort*)(fbb + 1024);      // [4,4096,32] bf16
    ushort* kpk  = qpk + 524288;
    ushort* vbh  = kpk + 524288;               // [4,128,4096] bf16
    ushort* xbf  = vbh + 2097152;              // [4,4096,512] bf16 (reused as opart)
    ushort* xpbf = xbf + 8388608;              // [4,4096,256] bf16
    ushort* wdcp = xpbf + 4194304;             // [9,16,256,32]
    ushort* wc2p = wdcp + 1179648;             // [9,8,128,32]
    ushort* wc1b = wc2p + 294912;              // [128,256]
    ushort* wfb  = wc1b + 32768;               // [256,256]
    float* Mpart = (float*)(wfb + 65536);      // [4,4,4096]
    float* Spart = Mpart + 65536;
    ushort* opart = xbf;                       // [4,4,4096,128] bf16

    // 0. packs + x -> channel-last bf16
    pack_w3x3<512, 256><<<dim3((9*16*256*32 + 255)/256), 256, 0, stream>>>(dc_w, wdcp);
    pack_w3x3<256, 128><<<dim3((9*8*128*32 + 255)/256), 256, 0, stream>>>(c2_w, wc2p);
    pack_w1x1<<<dim3((32768 + 255)/256), 256, 0, stream>>>(c1_w, wc1b, 256, 256, 32768);
    pack_w1x1<<<dim3((65536 + 255)/256), 256, 0, stream>>>(f_w, wfb, 256, 384, 65536);
    to_chlast_bf16<512><<<dim3(64, 8, 4), 256, 0, stream>>>(x, xbf);
    // 1. down_conv 3x3 512->256 (MFMA)
    conv3x3_mfma<512, 256, 64, 1><<<dim3(16, 4, 4), 256, 0, stream>>>(
        xbf, wdcp, dc_b, dc_g, dc_bt, dc_m, dc_v, dc_a, xp);
    // 1b. xp -> channel-last bf16
    to_chlast_bf16<256><<<dim3(64, 4, 4), 256, 0, stream>>>(xp, xpbf);
    // 2. branch1 1x1 (MFMA) -> catb cols 0..127
    gemm1x1_cl<256, 128, true, 1><<<dim3(128, 2), 256, 0, stream>>>(
        xpbf, wc1b, c1_b, c1_g, c1_bt, c1_m, c1_v, c1_a, nullptr, catb, 256, 0);
    // 3. branch2 dilated 3x3 (MFMA)
    conv3x3_mfma<256, 128, 32, 2><<<dim3(16, 4, 4), 256, 0, stream>>>(
        xpbf, wc2p, c2_b, c2_g, c2_bt, c2_m, c2_v, c2_a, c2b);
    // 4. q,k
    qk_kernel<<<dim3(64, 4), 256, 0, stream>>>(c2b, q_w, q_b, k_w, k_b, qpk, kpk);
    // 5. v -> bf16 [c][m]
    conv1x1_kernel<128, false, true><<<dim3(64, 2, 4), 256, 0, stream>>>(
        c2b, v_w, 128, 128, v_b, nullptr, vbh);
    // 6. flash attention + combine -> catb cols 128..255
    attn_flash<<<dim3(64, 4, 4), 256, 0, stream>>>(qpk, kpk, vbh, opart, Mpart, Spart);
    attn_combine<<<dim3(128, 4), 256, 0, stream>>>(opart, Mpart, Spart, c2b, gamma2, catb);
    // 7. pool + c3 -> fuse bias
    pool_kernel<<<dim3(256, 4), 256, 0, stream>>>(xp, poolb);
    c3_fbias_kernel<<<dim3(4), 256, 0, stream>>>(
        poolb, c3_w, c3_b, c3_g, c3_bt, c3_m, c3_v, c3_a, f_w, fbb);
    // 8. fuse conv (MFMA, K=256) -> d_out
    gemm1x1_cl<256, 256, true, 0><<<dim3(128, 4), 256, 0, stream>>>(
        catb, wfb, f_b, f_g, f_bt, f_m, f_v, f_a, fbb, (float*)d_out, 0, 0);
}

// Round 7
// 502.610 us; speedup vs baseline: 3.4453x; 1.0915x over previous
//
#include <hip/hip_runtime.h>
#include <hip/hip_bf16.h>
#include <math.h>

#define HW 4096
#define EPSV 1e-5f

typedef unsigned short ushort;
typedef __attribute__((ext_vector_type(8))) short bf16x8;
typedef __attribute__((ext_vector_type(4))) float f32x4;

__device__ inline ushort f2bf(float f) {
    __hip_bfloat16 h = __float2bfloat16(f);
    return *reinterpret_cast<ushort*>(&h);
}
__device__ inline float bf2f(ushort u) {
    unsigned int v = ((unsigned int)u) << 16;
    return __uint_as_float(v);
}

// ---------------------------------------------------------------------------
// fp32 [b][C][4096] -> bf16 channel-last [b][4096][C], LDS transpose.
// ---------------------------------------------------------------------------
template<int C>
__global__ __launch_bounds__(256) void to_chlast_bf16(
    const float* __restrict__ src, ushort* __restrict__ dst)
{
    const int b = blockIdx.z, c0 = blockIdx.y * 64, p0 = blockIdx.x * 64;
    const int tid = threadIdx.x;
    __shared__ float sT[64][65];
    for (int i = tid; i < 4096; i += 256) {
        const int ch = i >> 6, px = i & 63;
        sT[ch][px] = src[(size_t)(b * C + c0 + ch) * HW + p0 + px];
    }
    __syncthreads();
    const int px = tid >> 2, seg = tid & 3;
    ushort tmp[16];
    #pragma unroll
    for (int j = 0; j < 16; ++j) tmp[j] = f2bf(sT[seg * 16 + j][px]);
    ushort* d = dst + (size_t)(b * HW + p0 + px) * C + c0 + seg * 16;
    *(uint4*)d = *(uint4*)&tmp[0];
    *(uint4*)(d + 8) = *(uint4*)&tmp[8];
}

// ---------------------------------------------------------------------------
// Pack 3x3 weights [co][ci][3][3] fp32 -> [tap][ci/32][co][ci32] bf16.
// ---------------------------------------------------------------------------
template<int CIN, int COUT>
__global__ __launch_bounds__(256) void pack_w3x3(
    const float* __restrict__ w, ushort* __restrict__ wpk)
{
    const int idx = blockIdx.x * 256 + threadIdx.x;
    constexpr int total = 9 * (CIN / 32) * COUT * 32;
    if (idx >= total) return;
    const int ci_in = idx & 31;
    int rest = idx >> 5;
    const int co = rest % COUT; rest /= COUT;
    const int cc = rest % (CIN / 32);
    const int tap = rest / (CIN / 32);
    wpk[idx] = f2bf(w[((size_t)co * CIN + cc * 32 + ci_in) * 9 + tap]);
}

// ---------------------------------------------------------------------------
// Pack 1x1 weights [co][stride] fp32 -> [co][K] bf16 (first K columns).
// ---------------------------------------------------------------------------
__global__ __launch_bounds__(256) void pack_w1x1(
    const float* __restrict__ w, ushort* __restrict__ o,
    int K, int stride, int total)
{
    const int idx = blockIdx.x * 256 + threadIdx.x;
    if (idx >= total) return;
    const int co = idx / K, k = idx - co * K;
    o[idx] = f2bf(w[(size_t)co * stride + k]);
}

// ---------------------------------------------------------------------------
// MFMA implicit-GEMM 3x3 conv + BN + PReLU.
// ---------------------------------------------------------------------------
template<int CIN, int COUT, int COTILE, int DIL>
__global__ __launch_bounds__(256) void conv3x3_mfma(
    const ushort* __restrict__ xin,   // [b][64][64][CIN] bf16
    const ushort* __restrict__ wpk,   // [9][CIN/32][COUT][32] bf16
    const float* __restrict__ bias, const float* __restrict__ bng,
    const float* __restrict__ bnb, const float* __restrict__ bnm,
    const float* __restrict__ bnv, const float* __restrict__ al,
    float* __restrict__ out)
{
    constexpr int HR = 4 + 2 * DIL;
    constexpr int NC = 64 + 2 * DIL;
    constexpr int MT = COTILE / 16;

    const int tid = threadIdx.x;
    const int wave = tid >> 6, lane = tid & 63;
    const int l15 = lane & 15, quad = lane >> 4;
    const int b = blockIdx.z;
    const int co0 = blockIdx.y * COTILE;
    const int h0 = blockIdx.x * 4;

    __shared__ __align__(16) ushort sA[HR * NC * 32];
    __shared__ __align__(16) ushort sB[9 * COTILE * 32];
    __shared__ float sScale[COTILE], sShift[COTILE];

    if (tid < COTILE) {
        const int co = co0 + tid;
        const float sc = bng[co] * rsqrtf(bnv[co] + EPSV);
        sScale[tid] = sc;
        sShift[tid] = (bias[co] - bnm[co]) * sc + bnb[co];
    }

    f32x4 acc[MT][4];
    #pragma unroll
    for (int mt = 0; mt < MT; ++mt)
        #pragma unroll
        for (int nt = 0; nt < 4; ++nt) acc[mt][nt] = (f32x4){0.f, 0.f, 0.f, 0.f};

    #pragma unroll 1
    for (int cc = 0; cc < CIN / 32; ++cc) {
        __syncthreads();
        constexpr int NA = HR * NC * 4;
        for (int i = tid; i < NA; i += 256) {
            const int p = i >> 2, seg = i & 3;
            const int r = p / NC, c = p - r * NC;
            const int grow = h0 - DIL + r, gcol = c - DIL;
            uint4 val = {0u, 0u, 0u, 0u};
            if (grow >= 0 && grow < 64 && gcol >= 0 && gcol < 64)
                val = *(const uint4*)&xin[((size_t)(b * 64 + grow) * 64 + gcol) * CIN
                                          + cc * 32 + seg * 8];
            *(uint4*)&sA[p * 32 + seg * 8] = val;
        }
        constexpr int NB = 9 * COTILE * 4;
        for (int i = tid; i < NB; i += 256) {
            const int tap = i / (COTILE * 4);
            const int rem = i - tap * (COTILE * 4);
            const int co = rem >> 2, seg = rem & 3;
            *(uint4*)&sB[(tap * COTILE + co) * 32 + seg * 8] =
                *(const uint4*)&wpk[((size_t)(tap * (CIN / 32) + cc) * COUT
                                     + co0 + co) * 32 + seg * 8];
        }
        __syncthreads();

        #pragma unroll
        for (int ty = 0; ty < 3; ++ty)
            #pragma unroll
            for (int tx = 0; tx < 3; ++tx) {
                const int tap = ty * 3 + tx;
                bf16x8 aw[MT];
                #pragma unroll
                for (int mt = 0; mt < MT; ++mt)
                    aw[mt] = *(const bf16x8*)&sB[(tap * COTILE + mt * 16 + l15) * 32 + quad * 8];
                const int rl = wave + ty * DIL;
                #pragma unroll
                for (int nt = 0; nt < 4; ++nt) {
                    const int cl = nt * 16 + l15 + tx * DIL;
                    const bf16x8 bp = *(const bf16x8*)&sA[(rl * NC + cl) * 32 + quad * 8];
                    #pragma unroll
                    for (int mt = 0; mt < MT; ++mt)
                        acc[mt][nt] = __builtin_amdgcn_mfma_f32_16x16x32_bf16(
                            aw[mt], bp, acc[mt][nt], 0, 0, 0);
                }
            }
    }

    const float a = al[0];
    #pragma unroll
    for (int mt = 0; mt < MT; ++mt)
        #pragma unroll
        for (int rr = 0; rr < 4; ++rr) {
            const int col = mt * 16 + quad * 4 + rr;
            const float sc = sScale[col], sh = sShift[col];
            const int co = co0 + col;
            #pragma unroll
            for (int nt = 0; nt < 4; ++nt) {
                float t = acc[mt][nt][rr] * sc + sh;
                t = t >= 0.f ? t : a * t;
                out[((size_t)(b * COUT + co) * 64 + h0 + wave) * 64 + nt * 16 + l15] = t;
            }
        }
}

// ---------------------------------------------------------------------------
// MFMA 1x1 conv on channel-last bf16 input, frags straight from global.
// ---------------------------------------------------------------------------
template<int CIN, int COUT, bool BNACT, int OMODE>
__global__ __launch_bounds__(256) void gemm1x1_cl(
    const ushort* __restrict__ xin,   // [16384][CIN] bf16
    const ushort* __restrict__ wbf,   // [COUT][CIN] bf16
    const float* __restrict__ bias, const float* __restrict__ bng,
    const float* __restrict__ bnb, const float* __restrict__ bnm,
    const float* __restrict__ bnv, const float* __restrict__ al,
    const float* __restrict__ ebias, void* __restrict__ outv,
    int ostride, int ocol)
{
    const int tid = threadIdx.x;
    const int wave = tid >> 6, lane = tid & 63;
    const int l15 = lane & 15, quad = lane >> 4;
    const int pix0 = blockIdx.x * 128 + wave * 32;
    const int co0 = blockIdx.y * 64;

    f32x4 acc[4][2];
    #pragma unroll
    for (int mt = 0; mt < 4; ++mt)
        #pragma unroll
        for (int nt = 0; nt < 2; ++nt) acc[mt][nt] = (f32x4){0.f, 0.f, 0.f, 0.f};

    #pragma unroll 2
    for (int cc = 0; cc < CIN / 32; ++cc) {
        bf16x8 aw[4], bp[2];
        #pragma unroll
        for (int mt = 0; mt < 4; ++mt)
            aw[mt] = *(const bf16x8*)&wbf[(size_t)(co0 + mt * 16 + l15) * CIN + cc * 32 + quad * 8];
        #pragma unroll
        for (int nt = 0; nt < 2; ++nt)
            bp[nt] = *(const bf16x8*)&xin[(size_t)(pix0 + nt * 16 + l15) * CIN + cc * 32 + quad * 8];
        #pragma unroll
        for (int mt = 0; mt < 4; ++mt)
            #pragma unroll
            for (int nt = 0; nt < 2; ++nt)
                acc[mt][nt] = __builtin_amdgcn_mfma_f32_16x16x32_bf16(
                    aw[mt], bp[nt], acc[mt][nt], 0, 0, 0);
    }

    const int bI = pix0 >> 12;
    const float a = BNACT ? al[0] : 0.f;

    if (OMODE == 0) {
        float* out = (float*)outv;
        #pragma unroll
        for (int mt = 0; mt < 4; ++mt)
            #pragma unroll
            for (int r = 0; r < 4; ++r) {
                const int co = co0 + mt * 16 + quad * 4 + r;
                float bb = bias[co];
                if (ebias) bb += ebias[bI * COUT + co];
                float scale = 1.f, shift = bb;
                if (BNACT) {
                    scale = bng[co] * rsqrtf(bnv[co] + EPSV);
                    shift = bb * scale + (bnb[co] - bnm[co] * scale);
                }
                #pragma unroll
                for (int nt = 0; nt < 2; ++nt) {
                    float t = acc[mt][nt][r] * scale + shift;
                    if (BNACT) t = t >= 0.f ? t : a * t;
                    out[((size_t)(bI * COUT + co)) * HW + (pix0 & 4095) + nt * 16 + l15] = t;
                }
            }
    } else {
        __shared__ ushort sT[4][32][68];
        #pragma unroll
        for (int mt = 0; mt < 4; ++mt)
            #pragma unroll
            for (int r = 0; r < 4; ++r) {
                const int co = co0 + mt * 16 + quad * 4 + r;
                float bb = bias[co];
                float scale = 1.f, shift = bb;
                if (BNACT) {
                    scale = bng[co] * rsqrtf(bnv[co] + EPSV);
                    shift = bb * scale + (bnb[co] - bnm[co] * scale);
                }
                #pragma unroll
                for (int nt = 0; nt < 2; ++nt) {
                    float t = acc[mt][nt][r] * scale + shift;
                    if (BNACT) t = t >= 0.f ? t : a * t;
                    sT[wave][nt * 16 + l15][mt * 16 + quad * 4 + r] = f2bf(t);
                }
            }
        __syncthreads();
        const int p = lane >> 1, half = lane & 1;
        ushort* out = (ushort*)outv;
        #pragma unroll
        for (int seg = 0; seg < 4; ++seg) {
            uint2 a0 = *(uint2*)&sT[wave][p][half * 32 + seg * 8];
            uint2 a1 = *(uint2*)&sT[wave][p][half * 32 + seg * 8 + 4];
            uint4 vv = {a0.x, a0.y, a1.x, a1.y};
            *(uint4*)&out[(size_t)(pix0 + p) * ostride + ocol + co0 + half * 32 + seg * 8] = vv;
        }
    }
}

// ---------------------------------------------------------------------------
// Generic fp32 1x1 conv (kept for v).  OUTBF16: write bf16.
// ---------------------------------------------------------------------------
template<int CIN, bool BNACT, bool OUTBF16>
__global__ __launch_bounds__(256) void conv1x1_kernel(
    const float* __restrict__ in0,
    const float* __restrict__ wgt, int wstride, int COUT,
    const float* __restrict__ bias, const float* __restrict__ al,
    void* __restrict__ outv)
{
    const int tid = threadIdx.x;
    const int b = blockIdx.z, co0 = blockIdx.y * 64, p0 = blockIdx.x * 64;
    const int cg = tid >> 4, pg = tid & 15;
    const int c0l = cg * 4, w0 = pg * 4;

    __shared__ __align__(16) float sIn[16 * 64];
    __shared__ __align__(16) float sW[16 * 68];

    float acc[4][4] = {};

    for (int cc = 0; cc < CIN; cc += 16) {
        {
            int i = tid;
            #pragma unroll
            for (int it = 0; it < 4; ++it, i += 256) {
                const int px = i & 63, ci = i >> 6;
                sIn[ci * 64 + px] = in0[(size_t)(b * CIN + cc + ci) * HW + p0 + px];
            }
            i = tid;
            #pragma unroll
            for (int it = 0; it < 4; ++it, i += 256) {
                const int ci = i & 15, co = i >> 4;
                sW[ci * 68 + co] = wgt[(co0 + co) * wstride + cc + ci];
            }
        }
        __syncthreads();
        #pragma unroll
        for (int ci = 0; ci < 16; ++ci) {
            const float4 iv = *(const float4*)&sIn[ci * 64 + w0];
            const float4 wv = *(const float4*)&sW[ci * 68 + c0l];
            const float ia[4] = {iv.x, iv.y, iv.z, iv.w};
            const float wa[4] = {wv.x, wv.y, wv.z, wv.w};
            #pragma unroll
            for (int i2 = 0; i2 < 4; ++i2)
                #pragma unroll
                for (int j = 0; j < 4; ++j)
                    acc[i2][j] = fmaf(wa[i2], ia[j], acc[i2][j]);
        }
        __syncthreads();
    }

    const float a = BNACT ? al[0] : 0.f;
    #pragma unroll
    for (int i2 = 0; i2 < 4; ++i2) {
        const int co = co0 + c0l + i2;
        const float shift = bias[co];
        float r[4];
        #pragma unroll
        for (int j = 0; j < 4; ++j) {
            float t = acc[i2][j] + shift;
            r[j] = (BNACT && t < 0.f) ? a * t : t;
        }
        const size_t base = (size_t)(b * COUT + co) * HW + p0 + w0;
        if (OUTBF16) {
            ushort* out = (ushort*)outv;
            #pragma unroll
            for (int j = 0; j < 4; ++j) out[base + j] = f2bf(r[j]);
        } else {
            float* out = (float*)outv;
            *(float4*)&out[base] = make_float4(r[0], r[1], r[2], r[3]);
        }
    }
}

// ---------------------------------------------------------------------------
// q & k 1x1 convs (128 -> 16 each) -> packed bf16 [b][4096][32] (16 ch + 16 zero)
// ---------------------------------------------------------------------------
__global__ __launch_bounds__(256) void qk_kernel(
    const float* __restrict__ c2g, const float* __restrict__ qw,
    const float* __restrict__ qb2, const float* __restrict__ kw,
    const float* __restrict__ kb2, ushort* __restrict__ qpack,
    ushort* __restrict__ kpack)
{
    const int b = blockIdx.y, p0 = blockIdx.x * 64, tid = threadIdx.x;
    __shared__ float sC[128][64];
    __shared__ float sWq[16][128];
    __shared__ float sWk[16][128];
    for (int i = tid; i < 8192; i += 256) {
        const int px = i & 63, ci = i >> 6;
        sC[ci][px] = c2g[(size_t)(b * 128 + ci) * HW + p0 + px];
    }
    for (int i = tid; i < 2048; i += 256) {
        const int ci = i & 127, co = i >> 7;
        sWq[co][ci] = qw[co * 128 + ci];
        sWk[co][ci] = kw[co * 128 + ci];
    }
    __syncthreads();
    const int px = tid & 63, grp = tid >> 6;
    const int co0 = (grp & 1) * 8;
    const bool isK = grp >= 2;
    const float* sWp = isK ? &sWk[0][0] : &sWq[0][0];
    float acc[8] = {};
    for (int ci = 0; ci < 128; ++ci) {
        const float xv = sC[ci][px];
        #pragma unroll
        for (int j = 0; j < 8; ++j)
            acc[j] = fmaf(sWp[(co0 + j) * 128 + ci], xv, acc[j]);
    }
    const float* bsrc = isK ? kb2 : qb2;
    ushort* osrc = isK ? kpack : qpack;
    const size_t base = (size_t)(b * 4096 + p0 + px) * 32;
    #pragma unroll
    for (int j = 0; j < 8; ++j) {
        osrc[base + co0 + j] = f2bf(acc[j] + bsrc[co0 + j]);
        osrc[base + 16 + co0 + j] = 0;
    }
}

// ---------------------------------------------------------------------------
// Two-pass flash attention.  Wave owns 32 queries (two Q B-frags) so every
// K / V fragment load feeds two MFMAs.  No vmcnt drains in the loops — only
// an lgkmcnt(0) between the in-wave LDS write and read (same-wave DS ops are
// processed in order, so this suffices for RAW ordering).
// Block = 4 waves = 128 queries.  Grid: (32 nblk, 4 msplit, 4 batch).
// ---------------------------------------------------------------------------
__global__ __launch_bounds__(256) void attn_flash(
    const ushort* __restrict__ qpack,
    const ushort* __restrict__ kpack,
    const ushort* __restrict__ vpackT,
    ushort* __restrict__ opart,       // [b][4j][4096n][128c] bf16
    float* __restrict__ Mpart,        // [b][4j][4096n]
    float* __restrict__ Spart)
{
    const int tid = threadIdx.x;
    const int wave = tid >> 6, lane = tid & 63;
    const int l15 = lane & 15, quad = lane >> 4;
    const int b = blockIdx.z, j = blockIdx.y;
    const int n0w = blockIdx.x * 128 + wave * 32;
    const int m_begin = j * 1024;

    __shared__ __align__(16) ushort sP[4][2][16][72];   // wave-private [g][n][64m]+pad

    const bf16x8 bq0 = *(const bf16x8*)(qpack + ((size_t)(b * 4096 + n0w + l15) * 32 + quad * 8));
    const bf16x8 bq1 = *(const bf16x8*)(qpack + ((size_t)(b * 4096 + n0w + 16 + l15) * 32 + quad * 8));
    const f32x4 z = {0.f, 0.f, 0.f, 0.f};

    // ---- pass 1: exact row max, in-register only ----
    float runM0 = -3e30f, runM1 = -3e30f;
    #pragma unroll 2
    for (int t = 0; t < 16; ++t) {
        const int m0 = m_begin + t * 64;
        #pragma unroll
        for (int ms = 0; ms < 4; ++ms) {
            const bf16x8 ak = *(const bf16x8*)(
                kpack + ((size_t)(b * 4096 + m0 + ms * 16 + l15) * 32 + quad * 8));
            const f32x4 s0 = __builtin_amdgcn_mfma_f32_16x16x32_bf16(ak, bq0, z, 0, 0, 0);
            const f32x4 s1 = __builtin_amdgcn_mfma_f32_16x16x32_bf16(ak, bq1, z, 0, 0, 0);
            runM0 = fmaxf(runM0, fmaxf(fmaxf(s0[0], s0[1]), fmaxf(s0[2], s0[3])));
            runM1 = fmaxf(runM1, fmaxf(fmaxf(s1[0], s1[1]), fmaxf(s1[2], s1[3])));
        }
    }
    runM0 = fmaxf(runM0, __shfl_xor(runM0, 16));
    runM0 = fmaxf(runM0, __shfl_xor(runM0, 32));
    runM1 = fmaxf(runM1, __shfl_xor(runM1, 16));
    runM1 = fmaxf(runM1, __shfl_xor(runM1, 32));
    const float Ms0 = runM0 * 1.44269504f;
    const float Ms1 = runM1 * 1.44269504f;

    // ---- pass 2: p = exp2(s*log2e - Ms), PV accumulate ----
    float runS0 = 0.f, runS1 = 0.f;
    f32x4 oacc0[8], oacc1[8];
    #pragma unroll
    for (int cs = 0; cs < 8; ++cs) {
        oacc0[cs] = (f32x4){0.f, 0.f, 0.f, 0.f};
        oacc1[cs] = (f32x4){0.f, 0.f, 0.f, 0.f};
    }

    #pragma unroll 1
    for (int t = 0; t < 16; ++t) {
        const int m0 = m_begin + t * 64;
        f32x4 s0[4], s1[4];
        #pragma unroll
        for (int ms = 0; ms < 4; ++ms) {
            const bf16x8 ak = *(const bf16x8*)(
                kpack + ((size_t)(b * 4096 + m0 + ms * 16 + l15) * 32 + quad * 8));
            s0[ms] = __builtin_amdgcn_mfma_f32_16x16x32_bf16(ak, bq0, z, 0, 0, 0);
            s1[ms] = __builtin_amdgcn_mfma_f32_16x16x32_bf16(ak, bq1, z, 0, 0, 0);
        }
        #pragma unroll
        for (int ms = 0; ms < 4; ++ms) {
            float p0[4], p1[4];
            #pragma unroll
            for (int r = 0; r < 4; ++r) {
                p0[r] = __builtin_amdgcn_exp2f(fmaf(s0[ms][r], 1.44269504f, -Ms0));
                p1[r] = __builtin_amdgcn_exp2f(fmaf(s1[ms][r], 1.44269504f, -Ms1));
                runS0 += p0[r];
                runS1 += p1[r];
            }
            ushort4 u0, u1;
            u0.x = f2bf(p0[0]); u0.y = f2bf(p0[1]); u0.z = f2bf(p0[2]); u0.w = f2bf(p0[3]);
            u1.x = f2bf(p1[0]); u1.y = f2bf(p1[1]); u1.z = f2bf(p1[2]); u1.w = f2bf(p1[3]);
            *(uint2*)&sP[wave][0][l15][ms * 16 + quad * 4] = *(uint2*)&u0;
            *(uint2*)&sP[wave][1][l15][ms * 16 + quad * 4] = *(uint2*)&u1;
        }
        asm volatile("s_waitcnt lgkmcnt(0)" ::: "memory");   // LDS RAW only; vmem stays in flight
        #pragma unroll
        for (int ks = 0; ks < 2; ++ks) {
            const bf16x8 ap0 = *(const bf16x8*)&sP[wave][0][l15][ks * 32 + quad * 8];
            const bf16x8 ap1 = *(const bf16x8*)&sP[wave][1][l15][ks * 32 + quad * 8];
            #pragma unroll
            for (int cs = 0; cs < 8; ++cs) {
                const bf16x8 bv = *(const bf16x8*)(
                    vpackT + ((size_t)(b * 128 + cs * 16 + l15) * HW + m0 + ks * 32 + quad * 8));
                oacc0[cs] = __builtin_amdgcn_mfma_f32_16x16x32_bf16(ap0, bv, oacc0[cs], 0, 0, 0);
                oacc1[cs] = __builtin_amdgcn_mfma_f32_16x16x32_bf16(ap1, bv, oacc1[cs], 0, 0, 0);
            }
        }
    }

    runS0 += __shfl_xor(runS0, 16);
    runS0 += __shfl_xor(runS0, 32);
    runS1 += __shfl_xor(runS1, 16);
    runS1 += __shfl_xor(runS1, 32);
    if (lane < 32) {
        const float Mv = (lane < 16) ? runM0 : runM1;
        const float Sv = (lane < 16) ? runS0 : runS1;
        const int n = n0w + ((lane < 16) ? 0 : 16) + l15;
        Mpart[((size_t)b * 4 + j) * 4096 + n] = Mv;
        Spart[((size_t)b * 4 + j) * 4096 + n] = Sv;
    }
    #pragma unroll
    for (int cs = 0; cs < 8; ++cs)
        #pragma unroll
        for (int r = 0; r < 4; ++r) {
            const int n = n0w + quad * 4 + r;
            opart[(((size_t)b * 4 + j) * 4096 + n) * 128 + cs * 16 + l15] = f2bf(oacc0[cs][r]);
            opart[(((size_t)b * 4 + j) * 4096 + n + 16) * 128 + cs * 16 + l15] = f2bf(oacc1[cs][r]);
        }
}

// ---------------------------------------------------------------------------
// Combine 4 m-split partials, normalize, fuse gamma2*O + c2 -> catb[:,128:256]
// ---------------------------------------------------------------------------
__global__ __launch_bounds__(256) void attn_combine(
    const ushort* __restrict__ opart, const float* __restrict__ Mpart,
    const float* __restrict__ Spart, const float* __restrict__ c2g,
    const float* __restrict__ gamma2, ushort* __restrict__ catb)
{
    const int b = blockIdx.y, n0 = blockIdx.x * 32, tid = threadIdx.x;
    __shared__ float sC2[128][33];
    __shared__ float sWj[4][32];
    if (tid < 32) {
        const int n = n0 + tid;
        float Mj[4], Sj[4];
        #pragma unroll
        for (int j = 0; j < 4; ++j) {
            Mj[j] = Mpart[((size_t)b * 4 + j) * 4096 + n];
            Sj[j] = Spart[((size_t)b * 4 + j) * 4096 + n];
        }
        float M = fmaxf(fmaxf(Mj[0], Mj[1]), fmaxf(Mj[2], Mj[3]));
        float e[4], St = 0.f;
        #pragma unroll
        for (int j = 0; j < 4; ++j) { e[j] = __expf(Mj[j] - M); St += Sj[j] * e[j]; }
        const float inv = 1.0f / St;
        #pragma unroll
        for (int j = 0; j < 4; ++j) sWj[j][tid] = e[j] * inv;
    }
    #pragma unroll
    for (int e = 0; e < 16; ++e) {
        const int idx = tid + e * 256;
        const int c = idx >> 5, n = idx & 31;
        sC2[c][n] = c2g[(size_t)(b * 128 + c) * HW + n0 + n];
    }
    __syncthreads();
    const float g2 = gamma2[0];
    #pragma unroll
    for (int e = 0; e < 16; ++e) {
        const int idx = tid + e * 256;
        const int n = idx >> 7, c = idx & 127;
        float s = 0.f;
        #pragma unroll
        for (int j = 0; j < 4; ++j)
            s += bf2f(opart[(((size_t)b * 4 + j) * 4096 + n0 + n) * 128 + c]) * sWj[j][n];
        catb[(size_t)(b * 4096 + n0 + n) * 256 + 128 + c] = f2bf(fmaf(g2, s, sC2[c][n]));
    }
}

// ---------------------------------------------------------------------------
__global__ __launch_bounds__(256) void pool_kernel(
    const float* __restrict__ xp, float* __restrict__ pool)
{
    const int c = blockIdx.x, b = blockIdx.y, tid = threadIdx.x;
    const float4* row = (const float4*)(xp + (size_t)(b * 256 + c) * HW);
    float s = 0.f;
    #pragma unroll 4
    for (int i = tid; i < 1024; i += 256) {
        const float4 t = row[i];
        s += t.x + t.y + t.z + t.w;
    }
    __shared__ float red[256];
    red[tid] = s; __syncthreads();
    for (int st = 128; st > 0; st >>= 1) {
        if (tid < st) red[tid] += red[tid + st];
        __syncthreads();
    }
    if (tid == 0) pool[b * 256 + c] = red[0] * (1.0f / 4096.0f);
}

// ---------------------------------------------------------------------------
__global__ __launch_bounds__(256) void c3_fbias_kernel(
    const float* __restrict__ pool, const float* __restrict__ c3w,
    const float* __restrict__ c3b, const float* __restrict__ bng,
    const float* __restrict__ bnb, const float* __restrict__ bnm,
    const float* __restrict__ bnv, const float* __restrict__ al,
    const float* __restrict__ fw, float* __restrict__ fbias)
{
    const int b = blockIdx.x, tid = threadIdx.x;
    __shared__ float sp[256];
    __shared__ float sc3[128];
    sp[tid] = pool[b * 256 + tid];
    __syncthreads();
    if (tid < 128) {
        float acc = c3b[tid];
        for (int ci = 0; ci < 256; ++ci) acc = fmaf(c3w[tid * 256 + ci], sp[ci], acc);
        const float scale = bng[tid] * rsqrtf(bnv[tid] + EPSV);
        float t = (acc - bnm[tid]) * scale + bnb[tid];
        const float a = al[0];
        sc3[tid] = t >= 0.f ? t : a * t;
    }
    __syncthreads();
    float f = 0.f;
    for (int j = 0; j < 128; ++j) f = fmaf(fw[tid * 384 + 256 + j], sc3[j], f);
    fbias[b * 256 + tid] = f;
}

// ---------------------------------------------------------------------------
extern "C" void kernel_launch(void* const* d_in, const int* in_sizes, int n_in,
                              void* d_out, int out_size, void* d_ws, size_t ws_size,
                              hipStream_t stream)
{
    const float* x     = (const float*)d_in[0];
    const float* dc_w  = (const float*)d_in[1];
    const float* dc_b  = (const float*)d_in[2];
    const float* dc_g  = (const float*)d_in[3];
    const float* dc_bt = (const float*)d_in[4];
    const float* dc_m  = (const float*)d_in[5];
    const float* dc_v  = (const float*)d_in[6];
    const float* dc_a  = (const float*)d_in[7];
    const float* c1_w  = (const float*)d_in[8];
    const float* c1_b  = (const float*)d_in[9];
    const float* c1_g  = (const float*)d_in[10];
    const float* c1_bt = (const float*)d_in[11];
    const float* c1_m  = (const float*)d_in[12];
    const float* c1_v  = (const float*)d_in[13];
    const float* c1_a  = (const float*)d_in[14];
    const float* c2_w  = (const float*)d_in[15];
    const float* c2_b  = (const float*)d_in[16];
    const float* c2_g  = (const float*)d_in[17];
    const float* c2_bt = (const float*)d_in[18];
    const float* c2_m  = (const float*)d_in[19];
    const float* c2_v  = (const float*)d_in[20];
    const float* c2_a  = (const float*)d_in[21];
    const float* q_w   = (const float*)d_in[22];
    const float* q_b   = (const float*)d_in[23];
    const float* k_w   = (const float*)d_in[24];
    const float* k_b   = (const float*)d_in[25];
    const float* v_w   = (const float*)d_in[26];
    const float* v_b   = (const float*)d_in[27];
    const float* gamma2= (const float*)d_in[28];
    const float* c3_w  = (const float*)d_in[29];
    const float* c3_b  = (const float*)d_in[30];
    const float* c3_g  = (const float*)d_in[31];
    const float* c3_bt = (const float*)d_in[32];
    const float* c3_m  = (const float*)d_in[33];
    const float* c3_v  = (const float*)d_in[34];
    const float* c3_a  = (const float*)d_in[35];
    const float* f_w   = (const float*)d_in[36];
    const float* f_b   = (const float*)d_in[37];
    const float* f_g   = (const float*)d_in[38];
    const float* f_bt  = (const float*)d_in[39];
    const float* f_m   = (const float*)d_in[40];
    const float* f_v   = (const float*)d_in[41];
    const float* f_a   = (const float*)d_in[42];

    float* ws    = (float*)d_ws;
    float* xp    = ws;                         // [4,256,4096] fp32
    float* c2b   = xp + 4194304;               // [4,128,4096] fp32
    ushort* catb = (ushort*)(c2b + 2097152);   // [4,4096,256] bf16
    float* poolb = (float*)(catb + 8388608);   // 1024
    float* fbb   = poolb + 1024;               // 1024
    ushort* qpk  = (ushort*)(fbb + 1024);      // [4,4096,32] bf16
    ushort* kpk  = qpk + 524288;
    ushort* vbh  = kpk + 524288;               // [4,128,4096] bf16
    ushort* xbf  = vbh + 2097152;              // [4,4096,512] bf16 (reused as opart)
    ushort* xpbf = xbf + 8388608;              // [4,4096,256] bf16
    ushort* wdcp = xpbf + 4194304;             // [9,16,256,32]
    ushort* wc2p = wdcp + 1179648;             // [9,8,128,32]
    ushort* wc1b = wc2p + 294912;              // [128,256]
    ushort* wfb  = wc1b + 32768;               // [256,256]
    float* Mpart = (float*)(wfb + 65536);      // [4,4,4096]
    float* Spart = Mpart + 65536;
    ushort* opart = xbf;                       // [4,4,4096,128] bf16

    // 0. packs + x -> channel-last bf16
    pack_w3x3<512, 256><<<dim3((9*16*256*32 + 255)/256), 256, 0, stream>>>(dc_w, wdcp);
    pack_w3x3<256, 128><<<dim3((9*8*128*32 + 255)/256), 256, 0, stream>>>(c2_w, wc2p);
    pack_w1x1<<<dim3((32768 + 255)/256), 256, 0, stream>>>(c1_w, wc1b, 256, 256, 32768);
    pack_w1x1<<<dim3((65536 + 255)/256), 256, 0, stream>>>(f_w, wfb, 256, 384, 65536);
    to_chlast_bf16<512><<<dim3(64, 8, 4), 256, 0, stream>>>(x, xbf);
    // 1. down_conv 3x3 512->256 (MFMA)
    conv3x3_mfma<512, 256, 64, 1><<<dim3(16, 4, 4), 256, 0, stream>>>(
        xbf, wdcp, dc_b, dc_g, dc_bt, dc_m, dc_v, dc_a, xp);
    // 1b. xp -> channel-last bf16
    to_chlast_bf16<256><<<dim3(64, 4, 4), 256, 0, stream>>>(xp, xpbf);
    // 2. branch1 1x1 (MFMA) -> catb cols 0..127
    gemm1x1_cl<256, 128, true, 1><<<dim3(128, 2), 256, 0, stream>>>(
        xpbf, wc1b, c1_b, c1_g, c1_bt, c1_m, c1_v, c1_a, nullptr, catb, 256, 0);
    // 3. branch2 dilated 3x3 (MFMA)
    conv3x3_mfma<256, 128, 32, 2><<<dim3(16, 4, 4), 256, 0, stream>>>(
        xpbf, wc2p, c2_b, c2_g, c2_bt, c2_m, c2_v, c2_a, c2b);
    // 4. q,k
    qk_kernel<<<dim3(64, 4), 256, 0, stream>>>(c2b, q_w, q_b, k_w, k_b, qpk, kpk);
    // 5. v -> bf16 [c][m]
    conv1x1_kernel<128, false, true><<<dim3(64, 2, 4), 256, 0, stream>>>(
        c2b, v_w, 128, 128, v_b, nullptr, vbh);
    // 6. flash attention (32 q/wave, no vmcnt drains) + combine
    attn_flash<<<dim3(32, 4, 4), 256, 0, stream>>>(qpk, kpk, vbh, opart, Mpart, Spart);
    attn_combine<<<dim3(128, 4), 256, 0, stream>>>(opart, Mpart, Spart, c2b, gamma2, catb);
    // 7. pool + c3 -> fuse bias
    pool_kernel<<<dim3(256, 4), 256, 0, stream>>>(xp, poolb);
    c3_fbias_kernel<<<dim3(4), 256, 0, stream>>>(
        poolb, c3_w, c3_b, c3_g, c3_bt, c3_m, c3_v, c3_a, f_w, fbb);
    // 8. fuse conv (MFMA, K=256) -> d_out
    gemm1x1_cl<256, 256, true, 0><<<dim3(128, 4), 256, 0, stream>>>(
        catb, wfb, f_b, f_g, f_bt, f_m, f_v, f_a, fbb, (float*)d_out, 0, 0);
}

// Round 8
// 494.902 us; speedup vs baseline: 3.4990x; 1.0156x over previous
//
#include <hip/hip_runtime.h>
#include <hip/hip_bf16.h>
#include <math.h>

#define HW 4096
#define EPSV 1e-5f

typedef unsigned short ushort;
typedef __attribute__((ext_vector_type(8))) short bf16x8;
typedef __attribute__((ext_vector_type(4))) float f32x4;

__device__ inline ushort f2bf(float f) {
    __hip_bfloat16 h = __float2bfloat16(f);
    return *reinterpret_cast<ushort*>(&h);
}
__device__ inline float bf2f(ushort u) {
    unsigned int v = ((unsigned int)u) << 16;
    return __uint_as_float(v);
}

// ---------------------------------------------------------------------------
// fp32 [b][C][4096] -> bf16 channel-last [b][4096][C], LDS transpose.
// ---------------------------------------------------------------------------
template<int C>
__global__ __launch_bounds__(256) void to_chlast_bf16(
    const float* __restrict__ src, ushort* __restrict__ dst)
{
    const int b = blockIdx.z, c0 = blockIdx.y * 64, p0 = blockIdx.x * 64;
    const int tid = threadIdx.x;
    __shared__ float sT[64][65];
    for (int i = tid; i < 4096; i += 256) {
        const int ch = i >> 6, px = i & 63;
        sT[ch][px] = src[(size_t)(b * C + c0 + ch) * HW + p0 + px];
    }
    __syncthreads();
    const int px = tid >> 2, seg = tid & 3;
    ushort tmp[16];
    #pragma unroll
    for (int j = 0; j < 16; ++j) tmp[j] = f2bf(sT[seg * 16 + j][px]);
    ushort* d = dst + (size_t)(b * HW + p0 + px) * C + c0 + seg * 16;
    *(uint4*)d = *(uint4*)&tmp[0];
    *(uint4*)(d + 8) = *(uint4*)&tmp[8];
}

// ---------------------------------------------------------------------------
// Pack 3x3 weights [co][ci][3][3] fp32 -> [tap][ci/32][co][ci32] bf16.
// ---------------------------------------------------------------------------
template<int CIN, int COUT>
__global__ __launch_bounds__(256) void pack_w3x3(
    const float* __restrict__ w, ushort* __restrict__ wpk)
{
    const int idx = blockIdx.x * 256 + threadIdx.x;
    constexpr int total = 9 * (CIN / 32) * COUT * 32;
    if (idx >= total) return;
    const int ci_in = idx & 31;
    int rest = idx >> 5;
    const int co = rest % COUT; rest /= COUT;
    const int cc = rest % (CIN / 32);
    const int tap = rest / (CIN / 32);
    wpk[idx] = f2bf(w[((size_t)co * CIN + cc * 32 + ci_in) * 9 + tap]);
}

// ---------------------------------------------------------------------------
// Pack 1x1 weights [co][stride] fp32 -> [co][K] bf16 (first K columns).
// ---------------------------------------------------------------------------
__global__ __launch_bounds__(256) void pack_w1x1(
    const float* __restrict__ w, ushort* __restrict__ o,
    int K, int stride, int total)
{
    const int idx = blockIdx.x * 256 + threadIdx.x;
    if (idx >= total) return;
    const int co = idx / K, k = idx - co * K;
    o[idx] = f2bf(w[(size_t)co * stride + k]);
}

// ---------------------------------------------------------------------------
// MFMA implicit-GEMM 3x3 conv + BN + PReLU.
// ROWS output rows per block; 4 waves arranged as (row, col-group).
// Grid: (64/ROWS, COUT/COTILE, 4).
// ---------------------------------------------------------------------------
template<int CIN, int COUT, int COTILE, int DIL, int ROWS>
__global__ __launch_bounds__(256) void conv3x3_mfma(
    const ushort* __restrict__ xin,   // [b][64][64][CIN] bf16
    const ushort* __restrict__ wpk,   // [9][CIN/32][COUT][32] bf16
    const float* __restrict__ bias, const float* __restrict__ bng,
    const float* __restrict__ bnb, const float* __restrict__ bnm,
    const float* __restrict__ bnv, const float* __restrict__ al,
    float* __restrict__ out)
{
    constexpr int HR = ROWS + 2 * DIL;
    constexpr int NC = 64 + 2 * DIL;
    constexpr int MT = COTILE / 16;
    constexpr int WPR = 4 / ROWS;       // waves per row
    constexpr int NT = ROWS;            // col tiles per wave (4/WPR)

    const int tid = threadIdx.x;
    const int wave = tid >> 6, lane = tid & 63;
    const int l15 = lane & 15, quad = lane >> 4;
    const int b = blockIdx.z;
    const int co0 = blockIdx.y * COTILE;
    const int h0 = blockIdx.x * ROWS;
    const int row = wave / WPR;
    const int ntbase = (wave % WPR) * NT;

    __shared__ __align__(16) ushort sA[HR * NC * 32];
    __shared__ __align__(16) ushort sB[9 * COTILE * 32];
    __shared__ float sScale[COTILE], sShift[COTILE];

    if (tid < COTILE) {
        const int co = co0 + tid;
        const float sc = bng[co] * rsqrtf(bnv[co] + EPSV);
        sScale[tid] = sc;
        sShift[tid] = (bias[co] - bnm[co]) * sc + bnb[co];
    }

    f32x4 acc[MT][NT];
    #pragma unroll
    for (int mt = 0; mt < MT; ++mt)
        #pragma unroll
        for (int nt = 0; nt < NT; ++nt) acc[mt][nt] = (f32x4){0.f, 0.f, 0.f, 0.f};

    #pragma unroll 1
    for (int cc = 0; cc < CIN / 32; ++cc) {
        __syncthreads();
        constexpr int NA = HR * NC * 4;
        for (int i = tid; i < NA; i += 256) {
            const int p = i >> 2, seg = i & 3;
            const int r = p / NC, c = p - r * NC;
            const int grow = h0 - DIL + r, gcol = c - DIL;
            uint4 val = {0u, 0u, 0u, 0u};
            if (grow >= 0 && grow < 64 && gcol >= 0 && gcol < 64)
                val = *(const uint4*)&xin[((size_t)(b * 64 + grow) * 64 + gcol) * CIN
                                          + cc * 32 + seg * 8];
            *(uint4*)&sA[p * 32 + seg * 8] = val;
        }
        constexpr int NB = 9 * COTILE * 4;
        for (int i = tid; i < NB; i += 256) {
            const int tap = i / (COTILE * 4);
            const int rem = i - tap * (COTILE * 4);
            const int co = rem >> 2, seg = rem & 3;
            *(uint4*)&sB[(tap * COTILE + co) * 32 + seg * 8] =
                *(const uint4*)&wpk[((size_t)(tap * (CIN / 32) + cc) * COUT
                                     + co0 + co) * 32 + seg * 8];
        }
        __syncthreads();

        #pragma unroll
        for (int ty = 0; ty < 3; ++ty)
            #pragma unroll
            for (int tx = 0; tx < 3; ++tx) {
                const int tap = ty * 3 + tx;
                bf16x8 aw[MT];
                #pragma unroll
                for (int mt = 0; mt < MT; ++mt)
                    aw[mt] = *(const bf16x8*)&sB[(tap * COTILE + mt * 16 + l15) * 32 + quad * 8];
                const int rl = row + ty * DIL;
                #pragma unroll
                for (int nt = 0; nt < NT; ++nt) {
                    const int cl = (ntbase + nt) * 16 + l15 + tx * DIL;
                    const bf16x8 bp = *(const bf16x8*)&sA[(rl * NC + cl) * 32 + quad * 8];
                    #pragma unroll
                    for (int mt = 0; mt < MT; ++mt)
                        acc[mt][nt] = __builtin_amdgcn_mfma_f32_16x16x32_bf16(
                            aw[mt], bp, acc[mt][nt], 0, 0, 0);
                }
            }
    }

    const float a = al[0];
    #pragma unroll
    for (int mt = 0; mt < MT; ++mt)
        #pragma unroll
        for (int rr = 0; rr < 4; ++rr) {
            const int col = mt * 16 + quad * 4 + rr;
            const float sc = sScale[col], sh = sShift[col];
            const int co = co0 + col;
            #pragma unroll
            for (int nt = 0; nt < NT; ++nt) {
                float t = acc[mt][nt][rr] * sc + sh;
                t = t >= 0.f ? t : a * t;
                out[((size_t)(b * COUT + co) * 64 + h0 + row) * 64
                    + (ntbase + nt) * 16 + l15] = t;
            }
        }
}

// ---------------------------------------------------------------------------
// MFMA 1x1 conv on channel-last bf16 input, frags straight from global.
// ---------------------------------------------------------------------------
template<int CIN, int COUT, bool BNACT, int OMODE>
__global__ __launch_bounds__(256) void gemm1x1_cl(
    const ushort* __restrict__ xin,   // [16384][CIN] bf16
    const ushort* __restrict__ wbf,   // [COUT][CIN] bf16
    const float* __restrict__ bias, const float* __restrict__ bng,
    const float* __restrict__ bnb, const float* __restrict__ bnm,
    const float* __restrict__ bnv, const float* __restrict__ al,
    const float* __restrict__ ebias, void* __restrict__ outv,
    int ostride, int ocol)
{
    const int tid = threadIdx.x;
    const int wave = tid >> 6, lane = tid & 63;
    const int l15 = lane & 15, quad = lane >> 4;
    const int pix0 = blockIdx.x * 128 + wave * 32;
    const int co0 = blockIdx.y * 64;

    f32x4 acc[4][2];
    #pragma unroll
    for (int mt = 0; mt < 4; ++mt)
        #pragma unroll
        for (int nt = 0; nt < 2; ++nt) acc[mt][nt] = (f32x4){0.f, 0.f, 0.f, 0.f};

    #pragma unroll 2
    for (int cc = 0; cc < CIN / 32; ++cc) {
        bf16x8 aw[4], bp[2];
        #pragma unroll
        for (int mt = 0; mt < 4; ++mt)
            aw[mt] = *(const bf16x8*)&wbf[(size_t)(co0 + mt * 16 + l15) * CIN + cc * 32 + quad * 8];
        #pragma unroll
        for (int nt = 0; nt < 2; ++nt)
            bp[nt] = *(const bf16x8*)&xin[(size_t)(pix0 + nt * 16 + l15) * CIN + cc * 32 + quad * 8];
        #pragma unroll
        for (int mt = 0; mt < 4; ++mt)
            #pragma unroll
            for (int nt = 0; nt < 2; ++nt)
                acc[mt][nt] = __builtin_amdgcn_mfma_f32_16x16x32_bf16(
                    aw[mt], bp[nt], acc[mt][nt], 0, 0, 0);
    }

    const int bI = pix0 >> 12;
    const float a = BNACT ? al[0] : 0.f;

    if (OMODE == 0) {
        float* out = (float*)outv;
        #pragma unroll
        for (int mt = 0; mt < 4; ++mt)
            #pragma unroll
            for (int r = 0; r < 4; ++r) {
                const int co = co0 + mt * 16 + quad * 4 + r;
                float bb = bias[co];
                if (ebias) bb += ebias[bI * COUT + co];
                float scale = 1.f, shift = bb;
                if (BNACT) {
                    scale = bng[co] * rsqrtf(bnv[co] + EPSV);
                    shift = bb * scale + (bnb[co] - bnm[co] * scale);
                }
                #pragma unroll
                for (int nt = 0; nt < 2; ++nt) {
                    float t = acc[mt][nt][r] * scale + shift;
                    if (BNACT) t = t >= 0.f ? t : a * t;
                    out[((size_t)(bI * COUT + co)) * HW + (pix0 & 4095) + nt * 16 + l15] = t;
                }
            }
    } else {
        __shared__ ushort sT[4][32][68];
        #pragma unroll
        for (int mt = 0; mt < 4; ++mt)
            #pragma unroll
            for (int r = 0; r < 4; ++r) {
                const int co = co0 + mt * 16 + quad * 4 + r;
                float bb = bias[co];
                float scale = 1.f, shift = bb;
                if (BNACT) {
                    scale = bng[co] * rsqrtf(bnv[co] + EPSV);
                    shift = bb * scale + (bnb[co] - bnm[co] * scale);
                }
                #pragma unroll
                for (int nt = 0; nt < 2; ++nt) {
                    float t = acc[mt][nt][r] * scale + shift;
                    if (BNACT) t = t >= 0.f ? t : a * t;
                    sT[wave][nt * 16 + l15][mt * 16 + quad * 4 + r] = f2bf(t);
                }
            }
        __syncthreads();
        const int p = lane >> 1, half = lane & 1;
        ushort* out = (ushort*)outv;
        #pragma unroll
        for (int seg = 0; seg < 4; ++seg) {
            uint2 a0 = *(uint2*)&sT[wave][p][half * 32 + seg * 8];
            uint2 a1 = *(uint2*)&sT[wave][p][half * 32 + seg * 8 + 4];
            uint4 vv = {a0.x, a0.y, a1.x, a1.y};
            *(uint4*)&out[(size_t)(pix0 + p) * ostride + ocol + co0 + half * 32 + seg * 8] = vv;
        }
    }
}

// ---------------------------------------------------------------------------
// Generic fp32 1x1 conv (kept for v).  OUTBF16: write bf16.
// ---------------------------------------------------------------------------
template<int CIN, bool BNACT, bool OUTBF16>
__global__ __launch_bounds__(256) void conv1x1_kernel(
    const float* __restrict__ in0,
    const float* __restrict__ wgt, int wstride, int COUT,
    const float* __restrict__ bias, const float* __restrict__ al,
    void* __restrict__ outv)
{
    const int tid = threadIdx.x;
    const int b = blockIdx.z, co0 = blockIdx.y * 64, p0 = blockIdx.x * 64;
    const int cg = tid >> 4, pg = tid & 15;
    const int c0l = cg * 4, w0 = pg * 4;

    __shared__ __align__(16) float sIn[16 * 64];
    __shared__ __align__(16) float sW[16 * 68];

    float acc[4][4] = {};

    for (int cc = 0; cc < CIN; cc += 16) {
        {
            int i = tid;
            #pragma unroll
            for (int it = 0; it < 4; ++it, i += 256) {
                const int px = i & 63, ci = i >> 6;
                sIn[ci * 64 + px] = in0[(size_t)(b * CIN + cc + ci) * HW + p0 + px];
            }
            i = tid;
            #pragma unroll
            for (int it = 0; it < 4; ++it, i += 256) {
                const int ci = i & 15, co = i >> 4;
                sW[ci * 68 + co] = wgt[(co0 + co) * wstride + cc + ci];
            }
        }
        __syncthreads();
        #pragma unroll
        for (int ci = 0; ci < 16; ++ci) {
            const float4 iv = *(const float4*)&sIn[ci * 64 + w0];
            const float4 wv = *(const float4*)&sW[ci * 68 + c0l];
            const float ia[4] = {iv.x, iv.y, iv.z, iv.w};
            const float wa[4] = {wv.x, wv.y, wv.z, wv.w};
            #pragma unroll
            for (int i2 = 0; i2 < 4; ++i2)
                #pragma unroll
                for (int j = 0; j < 4; ++j)
                    acc[i2][j] = fmaf(wa[i2], ia[j], acc[i2][j]);
        }
        __syncthreads();
    }

    const float a = BNACT ? al[0] : 0.f;
    #pragma unroll
    for (int i2 = 0; i2 < 4; ++i2) {
        const int co = co0 + c0l + i2;
        const float shift = bias[co];
        float r[4];
        #pragma unroll
        for (int j = 0; j < 4; ++j) {
            float t = acc[i2][j] + shift;
            r[j] = (BNACT && t < 0.f) ? a * t : t;
        }
        const size_t base = (size_t)(b * COUT + co) * HW + p0 + w0;
        if (OUTBF16) {
            ushort* out = (ushort*)outv;
            #pragma unroll
            for (int j = 0; j < 4; ++j) out[base + j] = f2bf(r[j]);
        } else {
            float* out = (float*)outv;
            *(float4*)&out[base] = make_float4(r[0], r[1], r[2], r[3]);
        }
    }
}

// ---------------------------------------------------------------------------
// q & k 1x1 convs (128 -> 16 each) -> packed bf16 [b][4096][32] (16 ch + 16 zero)
// ---------------------------------------------------------------------------
__global__ __launch_bounds__(256) void qk_kernel(
    const float* __restrict__ c2g, const float* __restrict__ qw,
    const float* __restrict__ qb2, const float* __restrict__ kw,
    const float* __restrict__ kb2, ushort* __restrict__ qpack,
    ushort* __restrict__ kpack)
{
    const int b = blockIdx.y, p0 = blockIdx.x * 64, tid = threadIdx.x;
    __shared__ float sC[128][64];
    __shared__ float sWq[16][128];
    __shared__ float sWk[16][128];
    for (int i = tid; i < 8192; i += 256) {
        const int px = i & 63, ci = i >> 6;
        sC[ci][px] = c2g[(size_t)(b * 128 + ci) * HW + p0 + px];
    }
    for (int i = tid; i < 2048; i += 256) {
        const int ci = i & 127, co = i >> 7;
        sWq[co][ci] = qw[co * 128 + ci];
        sWk[co][ci] = kw[co * 128 + ci];
    }
    __syncthreads();
    const int px = tid & 63, grp = tid >> 6;
    const int co0 = (grp & 1) * 8;
    const bool isK = grp >= 2;
    const float* sWp = isK ? &sWk[0][0] : &sWq[0][0];
    float acc[8] = {};
    for (int ci = 0; ci < 128; ++ci) {
        const float xv = sC[ci][px];
        #pragma unroll
        for (int j = 0; j < 8; ++j)
            acc[j] = fmaf(sWp[(co0 + j) * 128 + ci], xv, acc[j]);
    }
    const float* bsrc = isK ? kb2 : qb2;
    ushort* osrc = isK ? kpack : qpack;
    const size_t base = (size_t)(b * 4096 + p0 + px) * 32;
    #pragma unroll
    for (int j = 0; j < 8; ++j) {
        osrc[base + co0 + j] = f2bf(acc[j] + bsrc[co0 + j]);
        osrc[base + 16 + co0 + j] = 0;
    }
}

// ---------------------------------------------------------------------------
// Two-pass flash attention.  Wave owns 32 queries (two Q B-frags).
// Grid: (32 nblk, 8 msplit, 4 batch) = 1024 blocks (4/CU for occupancy).
// ---------------------------------------------------------------------------
__global__ __launch_bounds__(256) void attn_flash(
    const ushort* __restrict__ qpack,
    const ushort* __restrict__ kpack,
    const ushort* __restrict__ vpackT,
    ushort* __restrict__ opart,       // [b][8j][4096n][128c] bf16
    float* __restrict__ Mpart,        // [b][8j][4096n]
    float* __restrict__ Spart)
{
    const int tid = threadIdx.x;
    const int wave = tid >> 6, lane = tid & 63;
    const int l15 = lane & 15, quad = lane >> 4;
    const int b = blockIdx.z, j = blockIdx.y;
    const int n0w = blockIdx.x * 128 + wave * 32;
    const int m_begin = j * 512;

    __shared__ __align__(16) ushort sP[4][2][16][72];   // wave-private [g][n][64m]+pad

    const bf16x8 bq0 = *(const bf16x8*)(qpack + ((size_t)(b * 4096 + n0w + l15) * 32 + quad * 8));
    const bf16x8 bq1 = *(const bf16x8*)(qpack + ((size_t)(b * 4096 + n0w + 16 + l15) * 32 + quad * 8));
    const f32x4 z = {0.f, 0.f, 0.f, 0.f};

    // ---- pass 1: exact row max, in-register only ----
    float runM0 = -3e30f, runM1 = -3e30f;
    #pragma unroll 2
    for (int t = 0; t < 8; ++t) {
        const int m0 = m_begin + t * 64;
        #pragma unroll
        for (int ms = 0; ms < 4; ++ms) {
            const bf16x8 ak = *(const bf16x8*)(
                kpack + ((size_t)(b * 4096 + m0 + ms * 16 + l15) * 32 + quad * 8));
            const f32x4 s0 = __builtin_amdgcn_mfma_f32_16x16x32_bf16(ak, bq0, z, 0, 0, 0);
            const f32x4 s1 = __builtin_amdgcn_mfma_f32_16x16x32_bf16(ak, bq1, z, 0, 0, 0);
            runM0 = fmaxf(runM0, fmaxf(fmaxf(s0[0], s0[1]), fmaxf(s0[2], s0[3])));
            runM1 = fmaxf(runM1, fmaxf(fmaxf(s1[0], s1[1]), fmaxf(s1[2], s1[3])));
        }
    }
    runM0 = fmaxf(runM0, __shfl_xor(runM0, 16));
    runM0 = fmaxf(runM0, __shfl_xor(runM0, 32));
    runM1 = fmaxf(runM1, __shfl_xor(runM1, 16));
    runM1 = fmaxf(runM1, __shfl_xor(runM1, 32));
    const float Ms0 = runM0 * 1.44269504f;
    const float Ms1 = runM1 * 1.44269504f;

    // ---- pass 2: p = exp2(s*log2e - Ms), PV accumulate ----
    float runS0 = 0.f, runS1 = 0.f;
    f32x4 oacc0[8], oacc1[8];
    #pragma unroll
    for (int cs = 0; cs < 8; ++cs) {
        oacc0[cs] = (f32x4){0.f, 0.f, 0.f, 0.f};
        oacc1[cs] = (f32x4){0.f, 0.f, 0.f, 0.f};
    }

    #pragma unroll 1
    for (int t = 0; t < 8; ++t) {
        const int m0 = m_begin + t * 64;
        f32x4 s0[4], s1[4];
        #pragma unroll
        for (int ms = 0; ms < 4; ++ms) {
            const bf16x8 ak = *(const bf16x8*)(
                kpack + ((size_t)(b * 4096 + m0 + ms * 16 + l15) * 32 + quad * 8));
            s0[ms] = __builtin_amdgcn_mfma_f32_16x16x32_bf16(ak, bq0, z, 0, 0, 0);
            s1[ms] = __builtin_amdgcn_mfma_f32_16x16x32_bf16(ak, bq1, z, 0, 0, 0);
        }
        #pragma unroll
        for (int ms = 0; ms < 4; ++ms) {
            float p0[4], p1[4];
            #pragma unroll
            for (int r = 0; r < 4; ++r) {
                p0[r] = __builtin_amdgcn_exp2f(fmaf(s0[ms][r], 1.44269504f, -Ms0));
                p1[r] = __builtin_amdgcn_exp2f(fmaf(s1[ms][r], 1.44269504f, -Ms1));
                runS0 += p0[r];
                runS1 += p1[r];
            }
            ushort4 u0, u1;
            u0.x = f2bf(p0[0]); u0.y = f2bf(p0[1]); u0.z = f2bf(p0[2]); u0.w = f2bf(p0[3]);
            u1.x = f2bf(p1[0]); u1.y = f2bf(p1[1]); u1.z = f2bf(p1[2]); u1.w = f2bf(p1[3]);
            *(uint2*)&sP[wave][0][l15][ms * 16 + quad * 4] = *(uint2*)&u0;
            *(uint2*)&sP[wave][1][l15][ms * 16 + quad * 4] = *(uint2*)&u1;
        }
        asm volatile("s_waitcnt lgkmcnt(0)" ::: "memory");   // LDS RAW only
        #pragma unroll
        for (int ks = 0; ks < 2; ++ks) {
            const bf16x8 ap0 = *(const bf16x8*)&sP[wave][0][l15][ks * 32 + quad * 8];
            const bf16x8 ap1 = *(const bf16x8*)&sP[wave][1][l15][ks * 32 + quad * 8];
            #pragma unroll
            for (int cs = 0; cs < 8; ++cs) {
                const bf16x8 bv = *(const bf16x8*)(
                    vpackT + ((size_t)(b * 128 + cs * 16 + l15) * HW + m0 + ks * 32 + quad * 8));
                oacc0[cs] = __builtin_amdgcn_mfma_f32_16x16x32_bf16(ap0, bv, oacc0[cs], 0, 0, 0);
                oacc1[cs] = __builtin_amdgcn_mfma_f32_16x16x32_bf16(ap1, bv, oacc1[cs], 0, 0, 0);
            }
        }
    }

    runS0 += __shfl_xor(runS0, 16);
    runS0 += __shfl_xor(runS0, 32);
    runS1 += __shfl_xor(runS1, 16);
    runS1 += __shfl_xor(runS1, 32);
    if (lane < 32) {
        const float Mv = (lane < 16) ? runM0 : runM1;
        const float Sv = (lane < 16) ? runS0 : runS1;
        const int n = n0w + ((lane < 16) ? 0 : 16) + l15;
        Mpart[((size_t)b * 8 + j) * 4096 + n] = Mv;
        Spart[((size_t)b * 8 + j) * 4096 + n] = Sv;
    }
    #pragma unroll
    for (int cs = 0; cs < 8; ++cs)
        #pragma unroll
        for (int r = 0; r < 4; ++r) {
            const int n = n0w + quad * 4 + r;
            opart[(((size_t)b * 8 + j) * 4096 + n) * 128 + cs * 16 + l15] = f2bf(oacc0[cs][r]);
            opart[(((size_t)b * 8 + j) * 4096 + n + 16) * 128 + cs * 16 + l15] = f2bf(oacc1[cs][r]);
        }
}

// ---------------------------------------------------------------------------
// Combine 8 m-split partials, normalize, fuse gamma2*O + c2 -> catb[:,128:256]
// ---------------------------------------------------------------------------
__global__ __launch_bounds__(256) void attn_combine(
    const ushort* __restrict__ opart, const float* __restrict__ Mpart,
    const float* __restrict__ Spart, const float* __restrict__ c2g,
    const float* __restrict__ gamma2, ushort* __restrict__ catb)
{
    const int b = blockIdx.y, n0 = blockIdx.x * 32, tid = threadIdx.x;
    __shared__ float sC2[128][33];
    __shared__ float sWj[8][32];
    if (tid < 32) {
        const int n = n0 + tid;
        float Mj[8], Sj[8];
        #pragma unroll
        for (int j = 0; j < 8; ++j) {
            Mj[j] = Mpart[((size_t)b * 8 + j) * 4096 + n];
            Sj[j] = Spart[((size_t)b * 8 + j) * 4096 + n];
        }
        float M = -3e30f;
        #pragma unroll
        for (int j = 0; j < 8; ++j) M = fmaxf(M, Mj[j]);
        float St = 0.f, e[8];
        #pragma unroll
        for (int j = 0; j < 8; ++j) { e[j] = __expf(Mj[j] - M); St += Sj[j] * e[j]; }
        const float inv = 1.0f / St;
        #pragma unroll
        for (int j = 0; j < 8; ++j) sWj[j][tid] = e[j] * inv;
    }
    #pragma unroll
    for (int e = 0; e < 16; ++e) {
        const int idx = tid + e * 256;
        const int c = idx >> 5, n = idx & 31;
        sC2[c][n] = c2g[(size_t)(b * 128 + c) * HW + n0 + n];
    }
    __syncthreads();
    const float g2 = gamma2[0];
    #pragma unroll
    for (int e = 0; e < 16; ++e) {
        const int idx = tid + e * 256;
        const int n = idx >> 7, c = idx & 127;
        float s = 0.f;
        #pragma unroll
        for (int j = 0; j < 8; ++j)
            s += bf2f(opart[(((size_t)b * 8 + j) * 4096 + n0 + n) * 128 + c]) * sWj[j][n];
        catb[(size_t)(b * 4096 + n0 + n) * 256 + 128 + c] = f2bf(fmaf(g2, s, sC2[c][n]));
    }
}

// ---------------------------------------------------------------------------
__global__ __launch_bounds__(256) void pool_kernel(
    const float* __restrict__ xp, float* __restrict__ pool)
{
    const int c = blockIdx.x, b = blockIdx.y, tid = threadIdx.x;
    const float4* row = (const float4*)(xp + (size_t)(b * 256 + c) * HW);
    float s = 0.f;
    #pragma unroll 4
    for (int i = tid; i < 1024; i += 256) {
        const float4 t = row[i];
        s += t.x + t.y + t.z + t.w;
    }
    __shared__ float red[256];
    red[tid] = s; __syncthreads();
    for (int st = 128; st > 0; st >>= 1) {
        if (tid < st) red[tid] += red[tid + st];
        __syncthreads();
    }
    if (tid == 0) pool[b * 256 + c] = red[0] * (1.0f / 4096.0f);
}

// ---------------------------------------------------------------------------
__global__ __launch_bounds__(256) void c3_fbias_kernel(
    const float* __restrict__ pool, const float* __restrict__ c3w,
    const float* __restrict__ c3b, const float* __restrict__ bng,
    const float* __restrict__ bnb, const float* __restrict__ bnm,
    const float* __restrict__ bnv, const float* __restrict__ al,
    const float* __restrict__ fw, float* __restrict__ fbias)
{
    const int b = blockIdx.x, tid = threadIdx.x;
    __shared__ float sp[256];
    __shared__ float sc3[128];
    sp[tid] = pool[b * 256 + tid];
    __syncthreads();
    if (tid < 128) {
        float acc = c3b[tid];
        for (int ci = 0; ci < 256; ++ci) acc = fmaf(c3w[tid * 256 + ci], sp[ci], acc);
        const float scale = bng[tid] * rsqrtf(bnv[tid] + EPSV);
        float t = (acc - bnm[tid]) * scale + bnb[tid];
        const float a = al[0];
        sc3[tid] = t >= 0.f ? t : a * t;
    }
    __syncthreads();
    float f = 0.f;
    for (int j = 0; j < 128; ++j) f = fmaf(fw[tid * 384 + 256 + j], sc3[j], f);
    fbias[b * 256 + tid] = f;
}

// ---------------------------------------------------------------------------
extern "C" void kernel_launch(void* const* d_in, const int* in_sizes, int n_in,
                              void* d_out, int out_size, void* d_ws, size_t ws_size,
                              hipStream_t stream)
{
    const float* x     = (const float*)d_in[0];
    const float* dc_w  = (const float*)d_in[1];
    const float* dc_b  = (const float*)d_in[2];
    const float* dc_g  = (const float*)d_in[3];
    const float* dc_bt = (const float*)d_in[4];
    const float* dc_m  = (const float*)d_in[5];
    const float* dc_v  = (const float*)d_in[6];
    const float* dc_a  = (const float*)d_in[7];
    const float* c1_w  = (const float*)d_in[8];
    const float* c1_b  = (const float*)d_in[9];
    const float* c1_g  = (const float*)d_in[10];
    const float* c1_bt = (const float*)d_in[11];
    const float* c1_m  = (const float*)d_in[12];
    const float* c1_v  = (const float*)d_in[13];
    const float* c1_a  = (const float*)d_in[14];
    const float* c2_w  = (const float*)d_in[15];
    const float* c2_b  = (const float*)d_in[16];
    const float* c2_g  = (const float*)d_in[17];
    const float* c2_bt = (const float*)d_in[18];
    const float* c2_m  = (const float*)d_in[19];
    const float* c2_v  = (const float*)d_in[20];
    const float* c2_a  = (const float*)d_in[21];
    const float* q_w   = (const float*)d_in[22];
    const float* q_b   = (const float*)d_in[23];
    const float* k_w   = (const float*)d_in[24];
    const float* k_b   = (const float*)d_in[25];
    const float* v_w   = (const float*)d_in[26];
    const float* v_b   = (const float*)d_in[27];
    const float* gamma2= (const float*)d_in[28];
    const float* c3_w  = (const float*)d_in[29];
    const float* c3_b  = (const float*)d_in[30];
    const float* c3_g  = (const float*)d_in[31];
    const float* c3_bt = (const float*)d_in[32];
    const float* c3_m  = (const float*)d_in[33];
    const float* c3_v  = (const float*)d_in[34];
    const float* c3_a  = (const float*)d_in[35];
    const float* f_w   = (const float*)d_in[36];
    const float* f_b   = (const float*)d_in[37];
    const float* f_g   = (const float*)d_in[38];
    const float* f_bt  = (const float*)d_in[39];
    const float* f_m   = (const float*)d_in[40];
    const float* f_v   = (const float*)d_in[41];
    const float* f_a   = (const float*)d_in[42];

    // ---- workspace layout (opart overlaps xp+xbf, both dead pre-attention) ----
    char* base = (char*)d_ws;
    ushort* opart = (ushort*)base;                       // [4,8,4096,128] = 33.5 MB
    float*  xp    = (float*)base;                        //  [4,256,4096] fp32 (early)
    ushort* xbf   = (ushort*)(base + 16777216);          //  [4,4096,512] bf16 (early)
    float*  c2b   = (float*)(base + 33554432);           // [4,128,4096] fp32
    ushort* catb  = (ushort*)(base + 41943040);          // [4,4096,256] bf16
    ushort* xpbf  = (ushort*)(base + 58720256);          // [4,4096,256] bf16
    ushort* qpk   = (ushort*)(base + 67108864);          // [4,4096,32]
    ushort* kpk   = (ushort*)(base + 68157440);
    ushort* vbh   = (ushort*)(base + 69206016);          // [4,128,4096]
    ushort* wdcp  = (ushort*)(base + 73400320);          // [9,16,256,32]
    ushort* wc2p  = (ushort*)(base + 75759616);          // [9,8,128,32]
    ushort* wc1b  = (ushort*)(base + 76349440);          // [128,256]
    ushort* wfb   = (ushort*)(base + 76414976);          // [256,256]
    float*  poolb = (float*)(base + 76546048);           // 1024
    float*  fbb   = (float*)(base + 76550144);           // 1024
    float*  Mpart = (float*)(base + 76554240);           // [4,8,4096]
    float*  Spart = (float*)(base + 77078528);           // [4,8,4096]

    // 0. packs + x -> channel-last bf16
    pack_w3x3<512, 256><<<dim3((9*16*256*32 + 255)/256), 256, 0, stream>>>(dc_w, wdcp);
    pack_w3x3<256, 128><<<dim3((9*8*128*32 + 255)/256), 256, 0, stream>>>(c2_w, wc2p);
    pack_w1x1<<<dim3((32768 + 255)/256), 256, 0, stream>>>(c1_w, wc1b, 256, 256, 32768);
    pack_w1x1<<<dim3((65536 + 255)/256), 256, 0, stream>>>(f_w, wfb, 256, 384, 65536);
    to_chlast_bf16<512><<<dim3(64, 8, 4), 256, 0, stream>>>(x, xbf);
    // 1. down_conv 3x3 512->256 (MFMA, 2 rows/block for occupancy)
    conv3x3_mfma<512, 256, 64, 1, 2><<<dim3(32, 4, 4), 256, 0, stream>>>(
        xbf, wdcp, dc_b, dc_g, dc_bt, dc_m, dc_v, dc_a, xp);
    // 1b. xp -> channel-last bf16; pool + c3 fbias (xp dies here)
    to_chlast_bf16<256><<<dim3(64, 4, 4), 256, 0, stream>>>(xp, xpbf);
    pool_kernel<<<dim3(256, 4), 256, 0, stream>>>(xp, poolb);
    c3_fbias_kernel<<<dim3(4), 256, 0, stream>>>(
        poolb, c3_w, c3_b, c3_g, c3_bt, c3_m, c3_v, c3_a, f_w, fbb);
    // 2. branch1 1x1 (MFMA) -> catb cols 0..127
    gemm1x1_cl<256, 128, true, 1><<<dim3(128, 2), 256, 0, stream>>>(
        xpbf, wc1b, c1_b, c1_g, c1_bt, c1_m, c1_v, c1_a, nullptr, catb, 256, 0);
    // 3. branch2 dilated 3x3 (MFMA, 2 rows/block)
    conv3x3_mfma<256, 128, 32, 2, 2><<<dim3(32, 4, 4), 256, 0, stream>>>(
        xpbf, wc2p, c2_b, c2_g, c2_bt, c2_m, c2_v, c2_a, c2b);
    // 4. q,k
    qk_kernel<<<dim3(64, 4), 256, 0, stream>>>(c2b, q_w, q_b, k_w, k_b, qpk, kpk);
    // 5. v -> bf16 [c][m]
    conv1x1_kernel<128, false, true><<<dim3(64, 2, 4), 256, 0, stream>>>(
        c2b, v_w, 128, 128, v_b, nullptr, vbh);
    // 6. flash attention (msplit 8 -> 1024 blocks) + combine
    attn_flash<<<dim3(32, 8, 4), 256, 0, stream>>>(qpk, kpk, vbh, opart, Mpart, Spart);
    attn_combine<<<dim3(128, 4), 256, 0, stream>>>(opart, Mpart, Spart, c2b, gamma2, catb);
    // 7. fuse conv (MFMA, K=256) -> d_out
    gemm1x1_cl<256, 256, true, 0><<<dim3(128, 4), 256, 0, stream>>>(
        catb, wfb, f_b, f_g, f_bt, f_m, f_v, f_a, fbb, (float*)d_out, 0, 0);
}

// Round 9
// 436.977 us; speedup vs baseline: 3.9628x; 1.1326x over previous
//
#include <hip/hip_runtime.h>
#include <hip/hip_bf16.h>
#include <math.h>

#define HW 4096
#define EPSV 1e-5f

typedef unsigned short ushort;
typedef __attribute__((ext_vector_type(8))) short bf16x8;
typedef __attribute__((ext_vector_type(4))) float f32x4;

__device__ inline ushort f2bf(float f) {
    __hip_bfloat16 h = __float2bfloat16(f);
    return *reinterpret_cast<ushort*>(&h);
}
__device__ inline float bf2f(ushort u) {
    unsigned int v = ((unsigned int)u) << 16;
    return __uint_as_float(v);
}

// ---------------------------------------------------------------------------
// fp32 [b][C][4096] -> bf16 channel-last [b][4096][C], LDS transpose.
// ---------------------------------------------------------------------------
template<int C>
__global__ __launch_bounds__(256) void to_chlast_bf16(
    const float* __restrict__ src, ushort* __restrict__ dst)
{
    const int b = blockIdx.z, c0 = blockIdx.y * 64, p0 = blockIdx.x * 64;
    const int tid = threadIdx.x;
    __shared__ float sT[64][65];
    for (int i = tid; i < 4096; i += 256) {
        const int ch = i >> 6, px = i & 63;
        sT[ch][px] = src[(size_t)(b * C + c0 + ch) * HW + p0 + px];
    }
    __syncthreads();
    const int px = tid >> 2, seg = tid & 3;
    ushort tmp[16];
    #pragma unroll
    for (int j = 0; j < 16; ++j) tmp[j] = f2bf(sT[seg * 16 + j][px]);
    ushort* d = dst + (size_t)(b * HW + p0 + px) * C + c0 + seg * 16;
    *(uint4*)d = *(uint4*)&tmp[0];
    *(uint4*)(d + 8) = *(uint4*)&tmp[8];
}

// ---------------------------------------------------------------------------
// Pack 3x3 weights [co][ci][3][3] fp32 -> [tap][ci/32][co][ci32] bf16.
// ---------------------------------------------------------------------------
template<int CIN, int COUT>
__global__ __launch_bounds__(256) void pack_w3x3(
    const float* __restrict__ w, ushort* __restrict__ wpk)
{
    const int idx = blockIdx.x * 256 + threadIdx.x;
    constexpr int total = 9 * (CIN / 32) * COUT * 32;
    if (idx >= total) return;
    const int ci_in = idx & 31;
    int rest = idx >> 5;
    const int co = rest % COUT; rest /= COUT;
    const int cc = rest % (CIN / 32);
    const int tap = rest / (CIN / 32);
    wpk[idx] = f2bf(w[((size_t)co * CIN + cc * 32 + ci_in) * 9 + tap]);
}

// ---------------------------------------------------------------------------
// Pack 1x1 weights [co][stride] fp32 -> [co][K] bf16 (first K columns).
// ---------------------------------------------------------------------------
__global__ __launch_bounds__(256) void pack_w1x1(
    const float* __restrict__ w, ushort* __restrict__ o,
    int K, int stride, int total)
{
    const int idx = blockIdx.x * 256 + threadIdx.x;
    if (idx >= total) return;
    const int co = idx / K, k = idx - co * K;
    o[idx] = f2bf(w[(size_t)co * stride + k]);
}

// ---------------------------------------------------------------------------
// MFMA implicit-GEMM 3x3 conv + BN + PReLU.  ROWS output rows per block.
// ---------------------------------------------------------------------------
template<int CIN, int COUT, int COTILE, int DIL, int ROWS>
__global__ __launch_bounds__(256) void conv3x3_mfma(
    const ushort* __restrict__ xin,   // [b][64][64][CIN] bf16
    const ushort* __restrict__ wpk,   // [9][CIN/32][COUT][32] bf16
    const float* __restrict__ bias, const float* __restrict__ bng,
    const float* __restrict__ bnb, const float* __restrict__ bnm,
    const float* __restrict__ bnv, const float* __restrict__ al,
    float* __restrict__ out)
{
    constexpr int HR = ROWS + 2 * DIL;
    constexpr int NC = 64 + 2 * DIL;
    constexpr int MT = COTILE / 16;
    constexpr int WPR = 4 / ROWS;
    constexpr int NT = ROWS;

    const int tid = threadIdx.x;
    const int wave = tid >> 6, lane = tid & 63;
    const int l15 = lane & 15, quad = lane >> 4;
    const int b = blockIdx.z;
    const int co0 = blockIdx.y * COTILE;
    const int h0 = blockIdx.x * ROWS;
    const int row = wave / WPR;
    const int ntbase = (wave % WPR) * NT;

    __shared__ __align__(16) ushort sA[HR * NC * 32];
    __shared__ __align__(16) ushort sB[9 * COTILE * 32];
    __shared__ float sScale[COTILE], sShift[COTILE];

    if (tid < COTILE) {
        const int co = co0 + tid;
        const float sc = bng[co] * rsqrtf(bnv[co] + EPSV);
        sScale[tid] = sc;
        sShift[tid] = (bias[co] - bnm[co]) * sc + bnb[co];
    }

    f32x4 acc[MT][NT];
    #pragma unroll
    for (int mt = 0; mt < MT; ++mt)
        #pragma unroll
        for (int nt = 0; nt < NT; ++nt) acc[mt][nt] = (f32x4){0.f, 0.f, 0.f, 0.f};

    #pragma unroll 1
    for (int cc = 0; cc < CIN / 32; ++cc) {
        __syncthreads();
        constexpr int NA = HR * NC * 4;
        for (int i = tid; i < NA; i += 256) {
            const int p = i >> 2, seg = i & 3;
            const int r = p / NC, c = p - r * NC;
            const int grow = h0 - DIL + r, gcol = c - DIL;
            uint4 val = {0u, 0u, 0u, 0u};
            if (grow >= 0 && grow < 64 && gcol >= 0 && gcol < 64)
                val = *(const uint4*)&xin[((size_t)(b * 64 + grow) * 64 + gcol) * CIN
                                          + cc * 32 + seg * 8];
            *(uint4*)&sA[p * 32 + seg * 8] = val;
        }
        constexpr int NB = 9 * COTILE * 4;
        for (int i = tid; i < NB; i += 256) {
            const int tap = i / (COTILE * 4);
            const int rem = i - tap * (COTILE * 4);
            const int co = rem >> 2, seg = rem & 3;
            *(uint4*)&sB[(tap * COTILE + co) * 32 + seg * 8] =
                *(const uint4*)&wpk[((size_t)(tap * (CIN / 32) + cc) * COUT
                                     + co0 + co) * 32 + seg * 8];
        }
        __syncthreads();

        #pragma unroll
        for (int ty = 0; ty < 3; ++ty)
            #pragma unroll
            for (int tx = 0; tx < 3; ++tx) {
                const int tap = ty * 3 + tx;
                bf16x8 aw[MT];
                #pragma unroll
                for (int mt = 0; mt < MT; ++mt)
                    aw[mt] = *(const bf16x8*)&sB[(tap * COTILE + mt * 16 + l15) * 32 + quad * 8];
                const int rl = row + ty * DIL;
                #pragma unroll
                for (int nt = 0; nt < NT; ++nt) {
                    const int cl = (ntbase + nt) * 16 + l15 + tx * DIL;
                    const bf16x8 bp = *(const bf16x8*)&sA[(rl * NC + cl) * 32 + quad * 8];
                    #pragma unroll
                    for (int mt = 0; mt < MT; ++mt)
                        acc[mt][nt] = __builtin_amdgcn_mfma_f32_16x16x32_bf16(
                            aw[mt], bp, acc[mt][nt], 0, 0, 0);
                }
            }
    }

    const float a = al[0];
    #pragma unroll
    for (int mt = 0; mt < MT; ++mt)
        #pragma unroll
        for (int rr = 0; rr < 4; ++rr) {
            const int col = mt * 16 + quad * 4 + rr;
            const float sc = sScale[col], sh = sShift[col];
            const int co = co0 + col;
            #pragma unroll
            for (int nt = 0; nt < NT; ++nt) {
                float t = acc[mt][nt][rr] * sc + sh;
                t = t >= 0.f ? t : a * t;
                out[((size_t)(b * COUT + co) * 64 + h0 + row) * 64
                    + (ntbase + nt) * 16 + l15] = t;
            }
        }
}

// ---------------------------------------------------------------------------
// MFMA 1x1 conv on channel-last bf16 input, frags straight from global.
// ---------------------------------------------------------------------------
template<int CIN, int COUT, bool BNACT, int OMODE>
__global__ __launch_bounds__(256) void gemm1x1_cl(
    const ushort* __restrict__ xin,   // [16384][CIN] bf16
    const ushort* __restrict__ wbf,   // [COUT][CIN] bf16
    const float* __restrict__ bias, const float* __restrict__ bng,
    const float* __restrict__ bnb, const float* __restrict__ bnm,
    const float* __restrict__ bnv, const float* __restrict__ al,
    const float* __restrict__ ebias, void* __restrict__ outv,
    int ostride, int ocol)
{
    const int tid = threadIdx.x;
    const int wave = tid >> 6, lane = tid & 63;
    const int l15 = lane & 15, quad = lane >> 4;
    const int pix0 = blockIdx.x * 128 + wave * 32;
    const int co0 = blockIdx.y * 64;

    f32x4 acc[4][2];
    #pragma unroll
    for (int mt = 0; mt < 4; ++mt)
        #pragma unroll
        for (int nt = 0; nt < 2; ++nt) acc[mt][nt] = (f32x4){0.f, 0.f, 0.f, 0.f};

    #pragma unroll 2
    for (int cc = 0; cc < CIN / 32; ++cc) {
        bf16x8 aw[4], bp[2];
        #pragma unroll
        for (int mt = 0; mt < 4; ++mt)
            aw[mt] = *(const bf16x8*)&wbf[(size_t)(co0 + mt * 16 + l15) * CIN + cc * 32 + quad * 8];
        #pragma unroll
        for (int nt = 0; nt < 2; ++nt)
            bp[nt] = *(const bf16x8*)&xin[(size_t)(pix0 + nt * 16 + l15) * CIN + cc * 32 + quad * 8];
        #pragma unroll
        for (int mt = 0; mt < 4; ++mt)
            #pragma unroll
            for (int nt = 0; nt < 2; ++nt)
                acc[mt][nt] = __builtin_amdgcn_mfma_f32_16x16x32_bf16(
                    aw[mt], bp[nt], acc[mt][nt], 0, 0, 0);
    }

    const int bI = pix0 >> 12;
    const float a = BNACT ? al[0] : 0.f;

    if (OMODE == 0) {
        float* out = (float*)outv;
        #pragma unroll
        for (int mt = 0; mt < 4; ++mt)
            #pragma unroll
            for (int r = 0; r < 4; ++r) {
                const int co = co0 + mt * 16 + quad * 4 + r;
                float bb = bias[co];
                if (ebias) bb += ebias[bI * COUT + co];
                float scale = 1.f, shift = bb;
                if (BNACT) {
                    scale = bng[co] * rsqrtf(bnv[co] + EPSV);
                    shift = bb * scale + (bnb[co] - bnm[co] * scale);
                }
                #pragma unroll
                for (int nt = 0; nt < 2; ++nt) {
                    float t = acc[mt][nt][r] * scale + shift;
                    if (BNACT) t = t >= 0.f ? t : a * t;
                    out[((size_t)(bI * COUT + co)) * HW + (pix0 & 4095) + nt * 16 + l15] = t;
                }
            }
    } else {
        __shared__ ushort sT[4][32][68];
        #pragma unroll
        for (int mt = 0; mt < 4; ++mt)
            #pragma unroll
            for (int r = 0; r < 4; ++r) {
                const int co = co0 + mt * 16 + quad * 4 + r;
                float bb = bias[co];
                float scale = 1.f, shift = bb;
                if (BNACT) {
                    scale = bng[co] * rsqrtf(bnv[co] + EPSV);
                    shift = bb * scale + (bnb[co] - bnm[co] * scale);
                }
                #pragma unroll
                for (int nt = 0; nt < 2; ++nt) {
                    float t = acc[mt][nt][r] * scale + shift;
                    if (BNACT) t = t >= 0.f ? t : a * t;
                    sT[wave][nt * 16 + l15][mt * 16 + quad * 4 + r] = f2bf(t);
                }
            }
        __syncthreads();
        const int p = lane >> 1, half = lane & 1;
        ushort* out = (ushort*)outv;
        #pragma unroll
        for (int seg = 0; seg < 4; ++seg) {
            uint2 a0 = *(uint2*)&sT[wave][p][half * 32 + seg * 8];
            uint2 a1 = *(uint2*)&sT[wave][p][half * 32 + seg * 8 + 4];
            uint4 vv = {a0.x, a0.y, a1.x, a1.y};
            *(uint4*)&out[(size_t)(pix0 + p) * ostride + ocol + co0 + half * 32 + seg * 8] = vv;
        }
    }
}

// ---------------------------------------------------------------------------
// Generic fp32 1x1 conv (kept for v).  OUTBF16: write bf16.
// ---------------------------------------------------------------------------
template<int CIN, bool BNACT, bool OUTBF16>
__global__ __launch_bounds__(256) void conv1x1_kernel(
    const float* __restrict__ in0,
    const float* __restrict__ wgt, int wstride, int COUT,
    const float* __restrict__ bias, const float* __restrict__ al,
    void* __restrict__ outv)
{
    const int tid = threadIdx.x;
    const int b = blockIdx.z, co0 = blockIdx.y * 64, p0 = blockIdx.x * 64;
    const int cg = tid >> 4, pg = tid & 15;
    const int c0l = cg * 4, w0 = pg * 4;

    __shared__ __align__(16) float sIn[16 * 64];
    __shared__ __align__(16) float sW[16 * 68];

    float acc[4][4] = {};

    for (int cc = 0; cc < CIN; cc += 16) {
        {
            int i = tid;
            #pragma unroll
            for (int it = 0; it < 4; ++it, i += 256) {
                const int px = i & 63, ci = i >> 6;
                sIn[ci * 64 + px] = in0[(size_t)(b * CIN + cc + ci) * HW + p0 + px];
            }
            i = tid;
            #pragma unroll
            for (int it = 0; it < 4; ++it, i += 256) {
                const int ci = i & 15, co = i >> 4;
                sW[ci * 68 + co] = wgt[(co0 + co) * wstride + cc + ci];
            }
        }
        __syncthreads();
        #pragma unroll
        for (int ci = 0; ci < 16; ++ci) {
            const float4 iv = *(const float4*)&sIn[ci * 64 + w0];
            const float4 wv = *(const float4*)&sW[ci * 68 + c0l];
            const float ia[4] = {iv.x, iv.y, iv.z, iv.w};
            const float wa[4] = {wv.x, wv.y, wv.z, wv.w};
            #pragma unroll
            for (int i2 = 0; i2 < 4; ++i2)
                #pragma unroll
                for (int j = 0; j < 4; ++j)
                    acc[i2][j] = fmaf(wa[i2], ia[j], acc[i2][j]);
        }
        __syncthreads();
    }

    const float a = BNACT ? al[0] : 0.f;
    #pragma unroll
    for (int i2 = 0; i2 < 4; ++i2) {
        const int co = co0 + c0l + i2;
        const float shift = bias[co];
        float r[4];
        #pragma unroll
        for (int j = 0; j < 4; ++j) {
            float t = acc[i2][j] + shift;
            r[j] = (BNACT && t < 0.f) ? a * t : t;
        }
        const size_t base = (size_t)(b * COUT + co) * HW + p0 + w0;
        if (OUTBF16) {
            ushort* out = (ushort*)outv;
            #pragma unroll
            for (int j = 0; j < 4; ++j) out[base + j] = f2bf(r[j]);
        } else {
            float* out = (float*)outv;
            *(float4*)&out[base] = make_float4(r[0], r[1], r[2], r[3]);
        }
    }
}

// ---------------------------------------------------------------------------
// q & k 1x1 convs (128 -> 16 each) -> packed bf16 [b][4096][32] (16 ch + 16 zero)
// ---------------------------------------------------------------------------
__global__ __launch_bounds__(256) void qk_kernel(
    const float* __restrict__ c2g, const float* __restrict__ qw,
    const float* __restrict__ qb2, const float* __restrict__ kw,
    const float* __restrict__ kb2, ushort* __restrict__ qpack,
    ushort* __restrict__ kpack)
{
    const int b = blockIdx.y, p0 = blockIdx.x * 64, tid = threadIdx.x;
    __shared__ float sC[128][64];
    __shared__ float sWq[16][128];
    __shared__ float sWk[16][128];
    for (int i = tid; i < 8192; i += 256) {
        const int px = i & 63, ci = i >> 6;
        sC[ci][px] = c2g[(size_t)(b * 128 + ci) * HW + p0 + px];
    }
    for (int i = tid; i < 2048; i += 256) {
        const int ci = i & 127, co = i >> 7;
        sWq[co][ci] = qw[co * 128 + ci];
        sWk[co][ci] = kw[co * 128 + ci];
    }
    __syncthreads();
    const int px = tid & 63, grp = tid >> 6;
    const int co0 = (grp & 1) * 8;
    const bool isK = grp >= 2;
    const float* sWp = isK ? &sWk[0][0] : &sWq[0][0];
    float acc[8] = {};
    for (int ci = 0; ci < 128; ++ci) {
        const float xv = sC[ci][px];
        #pragma unroll
        for (int j = 0; j < 8; ++j)
            acc[j] = fmaf(sWp[(co0 + j) * 128 + ci], xv, acc[j]);
    }
    const float* bsrc = isK ? kb2 : qb2;
    ushort* osrc = isK ? kpack : qpack;
    const size_t base = (size_t)(b * 4096 + p0 + px) * 32;
    #pragma unroll
    for (int j = 0; j < 8; ++j) {
        osrc[base + co0 + j] = f2bf(acc[j] + bsrc[co0 + j]);
        osrc[base + 16 + co0 + j] = 0;
    }
}

// ---------------------------------------------------------------------------
// Two-pass flash attention, V staged through block-shared LDS (fixes the
// 16-lines-per-instruction uncoalesced V reads).  Wave owns 32 queries.
// Pass 2: m-tile 32, sV double-buffered, software-pipelined (next tile's
// global loads land in regs before compute, LDS writes after, 1 barrier/t).
// Grid: (32 nblk, 8 msplit, 4 batch).
// ---------------------------------------------------------------------------
__global__ __launch_bounds__(256) void attn_flash(
    const ushort* __restrict__ qpack,
    const ushort* __restrict__ kpack,
    const ushort* __restrict__ vpackT,
    ushort* __restrict__ opart,       // [b][8j][4096n][128c] bf16
    float* __restrict__ Mpart,        // [b][8j][4096n]
    float* __restrict__ Spart)
{
    const int tid = threadIdx.x;
    const int wave = tid >> 6, lane = tid & 63;
    const int l15 = lane & 15, quad = lane >> 4;
    const int b = blockIdx.z, j = blockIdx.y;
    const int n0w = blockIdx.x * 128 + wave * 32;
    const int m_begin = j * 512;

    __shared__ __align__(16) ushort sV[2][128][40];     // [buf][c][32m + pad]
    __shared__ __align__(16) ushort sP[4][2][16][40];   // wave-private [g][n][32m + pad]

    const bf16x8 bq0 = *(const bf16x8*)(qpack + ((size_t)(b * 4096 + n0w + l15) * 32 + quad * 8));
    const bf16x8 bq1 = *(const bf16x8*)(qpack + ((size_t)(b * 4096 + n0w + 16 + l15) * 32 + quad * 8));
    const f32x4 z = {0.f, 0.f, 0.f, 0.f};

    // ---- pass 1: exact row max, in-register only (m-tile 64, no LDS) ----
    float runM0 = -3e30f, runM1 = -3e30f;
    #pragma unroll 2
    for (int t = 0; t < 8; ++t) {
        const int m0 = m_begin + t * 64;
        #pragma unroll
        for (int ms = 0; ms < 4; ++ms) {
            const bf16x8 ak = *(const bf16x8*)(
                kpack + ((size_t)(b * 4096 + m0 + ms * 16 + l15) * 32 + quad * 8));
            const f32x4 s0 = __builtin_amdgcn_mfma_f32_16x16x32_bf16(ak, bq0, z, 0, 0, 0);
            const f32x4 s1 = __builtin_amdgcn_mfma_f32_16x16x32_bf16(ak, bq1, z, 0, 0, 0);
            runM0 = fmaxf(runM0, fmaxf(fmaxf(s0[0], s0[1]), fmaxf(s0[2], s0[3])));
            runM1 = fmaxf(runM1, fmaxf(fmaxf(s1[0], s1[1]), fmaxf(s1[2], s1[3])));
        }
    }
    runM0 = fmaxf(runM0, __shfl_xor(runM0, 16));
    runM0 = fmaxf(runM0, __shfl_xor(runM0, 32));
    runM1 = fmaxf(runM1, __shfl_xor(runM1, 16));
    runM1 = fmaxf(runM1, __shfl_xor(runM1, 32));
    const float Ms0 = runM0 * 1.44269504f;
    const float Ms1 = runM1 * 1.44269504f;

    // ---- pass 2: m-tile 32, V via LDS ----
    float runS0 = 0.f, runS1 = 0.f;
    f32x4 oacc0[8], oacc1[8];
    #pragma unroll
    for (int cs = 0; cs < 8; ++cs) {
        oacc0[cs] = (f32x4){0.f, 0.f, 0.f, 0.f};
        oacc1[cs] = (f32x4){0.f, 0.f, 0.f, 0.f};
    }

    const int stc = tid >> 1, stseg = tid & 1;   // 128 c x 2 segs x 16B = 8 KB/tile

    // prologue: stage tile 0 into buf 0
    {
        uint4 v0 = *(const uint4*)&vpackT[(size_t)(b * 128 + stc) * HW + m_begin + stseg * 16];
        uint4 v1 = *(const uint4*)&vpackT[(size_t)(b * 128 + stc) * HW + m_begin + stseg * 16 + 8];
        *(uint4*)&sV[0][stc][stseg * 16] = v0;
        *(uint4*)&sV[0][stc][stseg * 16 + 8] = v1;
    }
    __syncthreads();

    #pragma unroll 1
    for (int t = 0; t < 16; ++t) {
        const int m0 = m_begin + t * 32;
        const int buf = t & 1;
        // issue next tile's global loads early (regs)
        uint4 nv0, nv1;
        const bool more = (t + 1 < 16);
        if (more) {
            const size_t nb = (size_t)(b * 128 + stc) * HW + m0 + 32 + stseg * 16;
            nv0 = *(const uint4*)&vpackT[nb];
            nv1 = *(const uint4*)&vpackT[nb + 8];
        }
        // scores (K coalesced from global)
        f32x4 s0[2], s1[2];
        #pragma unroll
        for (int ms = 0; ms < 2; ++ms) {
            const bf16x8 ak = *(const bf16x8*)(
                kpack + ((size_t)(b * 4096 + m0 + ms * 16 + l15) * 32 + quad * 8));
            s0[ms] = __builtin_amdgcn_mfma_f32_16x16x32_bf16(ak, bq0, z, 0, 0, 0);
            s1[ms] = __builtin_amdgcn_mfma_f32_16x16x32_bf16(ak, bq1, z, 0, 0, 0);
        }
        #pragma unroll
        for (int ms = 0; ms < 2; ++ms) {
            float p0[4], p1[4];
            #pragma unroll
            for (int r = 0; r < 4; ++r) {
                p0[r] = __builtin_amdgcn_exp2f(fmaf(s0[ms][r], 1.44269504f, -Ms0));
                p1[r] = __builtin_amdgcn_exp2f(fmaf(s1[ms][r], 1.44269504f, -Ms1));
                runS0 += p0[r];
                runS1 += p1[r];
            }
            ushort4 u0, u1;
            u0.x = f2bf(p0[0]); u0.y = f2bf(p0[1]); u0.z = f2bf(p0[2]); u0.w = f2bf(p0[3]);
            u1.x = f2bf(p1[0]); u1.y = f2bf(p1[1]); u1.z = f2bf(p1[2]); u1.w = f2bf(p1[3]);
            *(uint2*)&sP[wave][0][l15][ms * 16 + quad * 4] = *(uint2*)&u0;
            *(uint2*)&sP[wave][1][l15][ms * 16 + quad * 4] = *(uint2*)&u1;
        }
        asm volatile("s_waitcnt lgkmcnt(0)" ::: "memory");   // in-wave sP RAW
        const bf16x8 ap0 = *(const bf16x8*)&sP[wave][0][l15][quad * 8];
        const bf16x8 ap1 = *(const bf16x8*)&sP[wave][1][l15][quad * 8];
        #pragma unroll
        for (int cs = 0; cs < 8; ++cs) {
            const bf16x8 bv = *(const bf16x8*)&sV[buf][cs * 16 + l15][quad * 8];
            oacc0[cs] = __builtin_amdgcn_mfma_f32_16x16x32_bf16(ap0, bv, oacc0[cs], 0, 0, 0);
            oacc1[cs] = __builtin_amdgcn_mfma_f32_16x16x32_bf16(ap1, bv, oacc1[cs], 0, 0, 0);
        }
        if (more) {
            *(uint4*)&sV[buf ^ 1][stc][stseg * 16] = nv0;
            *(uint4*)&sV[buf ^ 1][stc][stseg * 16 + 8] = nv1;
            __syncthreads();
        }
    }

    runS0 += __shfl_xor(runS0, 16);
    runS0 += __shfl_xor(runS0, 32);
    runS1 += __shfl_xor(runS1, 16);
    runS1 += __shfl_xor(runS1, 32);
    if (lane < 32) {
        const float Mv = (lane < 16) ? runM0 : runM1;
        const float Sv = (lane < 16) ? runS0 : runS1;
        const int n = n0w + ((lane < 16) ? 0 : 16) + l15;
        Mpart[((size_t)b * 8 + j) * 4096 + n] = Mv;
        Spart[((size_t)b * 8 + j) * 4096 + n] = Sv;
    }
    #pragma unroll
    for (int cs = 0; cs < 8; ++cs)
        #pragma unroll
        for (int r = 0; r < 4; ++r) {
            const int n = n0w + quad * 4 + r;
            opart[(((size_t)b * 8 + j) * 4096 + n) * 128 + cs * 16 + l15] = f2bf(oacc0[cs][r]);
            opart[(((size_t)b * 8 + j) * 4096 + n + 16) * 128 + cs * 16 + l15] = f2bf(oacc1[cs][r]);
        }
}

// ---------------------------------------------------------------------------
// Combine 8 m-split partials, normalize, fuse gamma2*O + c2 -> catb[:,128:256]
// ---------------------------------------------------------------------------
__global__ __launch_bounds__(256) void attn_combine(
    const ushort* __restrict__ opart, const float* __restrict__ Mpart,
    const float* __restrict__ Spart, const float* __restrict__ c2g,
    const float* __restrict__ gamma2, ushort* __restrict__ catb)
{
    const int b = blockIdx.y, n0 = blockIdx.x * 32, tid = threadIdx.x;
    __shared__ float sC2[128][33];
    __shared__ float sWj[8][32];
    if (tid < 32) {
        const int n = n0 + tid;
        float Mj[8], Sj[8];
        #pragma unroll
        for (int j = 0; j < 8; ++j) {
            Mj[j] = Mpart[((size_t)b * 8 + j) * 4096 + n];
            Sj[j] = Spart[((size_t)b * 8 + j) * 4096 + n];
        }
        float M = -3e30f;
        #pragma unroll
        for (int j = 0; j < 8; ++j) M = fmaxf(M, Mj[j]);
        float St = 0.f, e[8];
        #pragma unroll
        for (int j = 0; j < 8; ++j) { e[j] = __expf(Mj[j] - M); St += Sj[j] * e[j]; }
        const float inv = 1.0f / St;
        #pragma unroll
        for (int j = 0; j < 8; ++j) sWj[j][tid] = e[j] * inv;
    }
    #pragma unroll
    for (int e = 0; e < 16; ++e) {
        const int idx = tid + e * 256;
        const int c = idx >> 5, n = idx & 31;
        sC2[c][n] = c2g[(size_t)(b * 128 + c) * HW + n0 + n];
    }
    __syncthreads();
    const float g2 = gamma2[0];
    #pragma unroll
    for (int e = 0; e < 16; ++e) {
        const int idx = tid + e * 256;
        const int n = idx >> 7, c = idx & 127;
        float s = 0.f;
        #pragma unroll
        for (int j = 0; j < 8; ++j)
            s += bf2f(opart[(((size_t)b * 8 + j) * 4096 + n0 + n) * 128 + c]) * sWj[j][n];
        catb[(size_t)(b * 4096 + n0 + n) * 256 + 128 + c] = f2bf(fmaf(g2, s, sC2[c][n]));
    }
}

// ---------------------------------------------------------------------------
__global__ __launch_bounds__(256) void pool_kernel(
    const float* __restrict__ xp, float* __restrict__ pool)
{
    const int c = blockIdx.x, b = blockIdx.y, tid = threadIdx.x;
    const float4* row = (const float4*)(xp + (size_t)(b * 256 + c) * HW);
    float s = 0.f;
    #pragma unroll 4
    for (int i = tid; i < 1024; i += 256) {
        const float4 t = row[i];
        s += t.x + t.y + t.z + t.w;
    }
    __shared__ float red[256];
    red[tid] = s; __syncthreads();
    for (int st = 128; st > 0; st >>= 1) {
        if (tid < st) red[tid] += red[tid + st];
        __syncthreads();
    }
    if (tid == 0) pool[b * 256 + c] = red[0] * (1.0f / 4096.0f);
}

// ---------------------------------------------------------------------------
__global__ __launch_bounds__(256) void c3_fbias_kernel(
    const float* __restrict__ pool, const float* __restrict__ c3w,
    const float* __restrict__ c3b, const float* __restrict__ bng,
    const float* __restrict__ bnb, const float* __restrict__ bnm,
    const float* __restrict__ bnv, const float* __restrict__ al,
    const float* __restrict__ fw, float* __restrict__ fbias)
{
    const int b = blockIdx.x, tid = threadIdx.x;
    __shared__ float sp[256];
    __shared__ float sc3[128];
    sp[tid] = pool[b * 256 + tid];
    __syncthreads();
    if (tid < 128) {
        float acc = c3b[tid];
        for (int ci = 0; ci < 256; ++ci) acc = fmaf(c3w[tid * 256 + ci], sp[ci], acc);
        const float scale = bng[tid] * rsqrtf(bnv[tid] + EPSV);
        float t = (acc - bnm[tid]) * scale + bnb[tid];
        const float a = al[0];
        sc3[tid] = t >= 0.f ? t : a * t;
    }
    __syncthreads();
    float f = 0.f;
    for (int j = 0; j < 128; ++j) f = fmaf(fw[tid * 384 + 256 + j], sc3[j], f);
    fbias[b * 256 + tid] = f;
}

// ---------------------------------------------------------------------------
extern "C" void kernel_launch(void* const* d_in, const int* in_sizes, int n_in,
                              void* d_out, int out_size, void* d_ws, size_t ws_size,
                              hipStream_t stream)
{
    const float* x     = (const float*)d_in[0];
    const float* dc_w  = (const float*)d_in[1];
    const float* dc_b  = (const float*)d_in[2];
    const float* dc_g  = (const float*)d_in[3];
    const float* dc_bt = (const float*)d_in[4];
    const float* dc_m  = (const float*)d_in[5];
    const float* dc_v  = (const float*)d_in[6];
    const float* dc_a  = (const float*)d_in[7];
    const float* c1_w  = (const float*)d_in[8];
    const float* c1_b  = (const float*)d_in[9];
    const float* c1_g  = (const float*)d_in[10];
    const float* c1_bt = (const float*)d_in[11];
    const float* c1_m  = (const float*)d_in[12];
    const float* c1_v  = (const float*)d_in[13];
    const float* c1_a  = (const float*)d_in[14];
    const float* c2_w  = (const float*)d_in[15];
    const float* c2_b  = (const float*)d_in[16];
    const float* c2_g  = (const float*)d_in[17];
    const float* c2_bt = (const float*)d_in[18];
    const float* c2_m  = (const float*)d_in[19];
    const float* c2_v  = (const float*)d_in[20];
    const float* c2_a  = (const float*)d_in[21];
    const float* q_w   = (const float*)d_in[22];
    const float* q_b   = (const float*)d_in[23];
    const float* k_w   = (const float*)d_in[24];
    const float* k_b   = (const float*)d_in[25];
    const float* v_w   = (const float*)d_in[26];
    const float* v_b   = (const float*)d_in[27];
    const float* gamma2= (const float*)d_in[28];
    const float* c3_w  = (const float*)d_in[29];
    const float* c3_b  = (const float*)d_in[30];
    const float* c3_g  = (const float*)d_in[31];
    const float* c3_bt = (const float*)d_in[32];
    const float* c3_m  = (const float*)d_in[33];
    const float* c3_v  = (const float*)d_in[34];
    const float* c3_a  = (const float*)d_in[35];
    const float* f_w   = (const float*)d_in[36];
    const float* f_b   = (const float*)d_in[37];
    const float* f_g   = (const float*)d_in[38];
    const float* f_bt  = (const float*)d_in[39];
    const float* f_m   = (const float*)d_in[40];
    const float* f_v   = (const float*)d_in[41];
    const float* f_a   = (const float*)d_in[42];

    // ---- workspace layout (opart overlaps xp+xbf, both dead pre-attention) ----
    char* base = (char*)d_ws;
    ushort* opart = (ushort*)base;                       // [4,8,4096,128] = 33.5 MB
    float*  xp    = (float*)base;                        //  [4,256,4096] fp32 (early)
    ushort* xbf   = (ushort*)(base + 16777216);          //  [4,4096,512] bf16 (early)
    float*  c2b   = (float*)(base + 33554432);           // [4,128,4096] fp32
    ushort* catb  = (ushort*)(base + 41943040);          // [4,4096,256] bf16
    ushort* xpbf  = (ushort*)(base + 58720256);          // [4,4096,256] bf16
    ushort* qpk   = (ushort*)(base + 67108864);          // [4,4096,32]
    ushort* kpk   = (ushort*)(base + 68157440);
    ushort* vbh   = (ushort*)(base + 69206016);          // [4,128,4096]
    ushort* wdcp  = (ushort*)(base + 73400320);          // [9,16,256,32]
    ushort* wc2p  = (ushort*)(base + 75759616);          // [9,8,128,32]
    ushort* wc1b  = (ushort*)(base + 76349440);          // [128,256]
    ushort* wfb   = (ushort*)(base + 76414976);          // [256,256]
    float*  poolb = (float*)(base + 76546048);           // 1024
    float*  fbb   = (float*)(base + 76550144);           // 1024
    float*  Mpart = (float*)(base + 76554240);           // [4,8,4096]
    float*  Spart = (float*)(base + 77078528);           // [4,8,4096]

    // 0. packs + x -> channel-last bf16
    pack_w3x3<512, 256><<<dim3((9*16*256*32 + 255)/256), 256, 0, stream>>>(dc_w, wdcp);
    pack_w3x3<256, 128><<<dim3((9*8*128*32 + 255)/256), 256, 0, stream>>>(c2_w, wc2p);
    pack_w1x1<<<dim3((32768 + 255)/256), 256, 0, stream>>>(c1_w, wc1b, 256, 256, 32768);
    pack_w1x1<<<dim3((65536 + 255)/256), 256, 0, stream>>>(f_w, wfb, 256, 384, 65536);
    to_chlast_bf16<512><<<dim3(64, 8, 4), 256, 0, stream>>>(x, xbf);
    // 1. down_conv 3x3 512->256 (MFMA, 2 rows/block)
    conv3x3_mfma<512, 256, 64, 1, 2><<<dim3(32, 4, 4), 256, 0, stream>>>(
        xbf, wdcp, dc_b, dc_g, dc_bt, dc_m, dc_v, dc_a, xp);
    // 1b. xp -> channel-last bf16; pool + c3 fbias (xp dies here)
    to_chlast_bf16<256><<<dim3(64, 4, 4), 256, 0, stream>>>(xp, xpbf);
    pool_kernel<<<dim3(256, 4), 256, 0, stream>>>(xp, poolb);
    c3_fbias_kernel<<<dim3(4), 256, 0, stream>>>(
        poolb, c3_w, c3_b, c3_g, c3_bt, c3_m, c3_v, c3_a, f_w, fbb);
    // 2. branch1 1x1 (MFMA) -> catb cols 0..127
    gemm1x1_cl<256, 128, true, 1><<<dim3(128, 2), 256, 0, stream>>>(
        xpbf, wc1b, c1_b, c1_g, c1_bt, c1_m, c1_v, c1_a, nullptr, catb, 256, 0);
    // 3. branch2 dilated 3x3 (MFMA, 2 rows/block)
    conv3x3_mfma<256, 128, 32, 2, 2><<<dim3(32, 4, 4), 256, 0, stream>>>(
        xpbf, wc2p, c2_b, c2_g, c2_bt, c2_m, c2_v, c2_a, c2b);
    // 4. q,k
    qk_kernel<<<dim3(64, 4), 256, 0, stream>>>(c2b, q_w, q_b, k_w, k_b, qpk, kpk);
    // 5. v -> bf16 [c][m]
    conv1x1_kernel<128, false, true><<<dim3(64, 2, 4), 256, 0, stream>>>(
        c2b, v_w, 128, 128, v_b, nullptr, vbh);
    // 6. flash attention (V via LDS) + combine
    attn_flash<<<dim3(32, 8, 4), 256, 0, stream>>>(qpk, kpk, vbh, opart, Mpart, Spart);
    attn_combine<<<dim3(128, 4), 256, 0, stream>>>(opart, Mpart, Spart, c2b, gamma2, catb);
    // 7. fuse conv (MFMA, K=256) -> d_out
    gemm1x1_cl<256, 256, true, 0><<<dim3(128, 4), 256, 0, stream>>>(
        catb, wfb, f_b, f_g, f_bt, f_m, f_v, f_a, fbb, (float*)d_out, 0, 0);
}